// Round 9
// baseline (1200.703 us; speedup 1.0000x reference)
//
#include <hip/hip_runtime.h>
#include <math.h>

constexpr int B_ = 16, C_ = 512, K_ = 64, N_ = 8192;
constexpr int BHALF = 8;
constexpr int BGRP = 8;       // EM batch group size (L3 residency)
constexpr int MCHUNK = 512;   // mstep n-chunk

typedef __bf16 bf16;
typedef __bf16 bf16x4 __attribute__((ext_vector_type(4)));
typedef __bf16 bf16x8 __attribute__((ext_vector_type(8)));
typedef float f32x4 __attribute__((ext_vector_type(4)));

#define GLDS16(gp, lp)                                              \
  __builtin_amdgcn_global_load_lds(                                 \
      (const __attribute__((address_space(1))) unsigned int*)(gp),  \
      (__attribute__((address_space(3))) unsigned int*)(lp), 16, 0, 0)

__device__ __forceinline__ bf16 lo_part(float v, bf16 h) {
  return (bf16)(v - (float)h);
}

// ---------------------------------------------------------------------------
// x (BHALF,C,N) fp32 -> XT hi/lo (BHALF,N,C) bf16 planes.
// ---------------------------------------------------------------------------
__global__ __launch_bounds__(256) void transpose_split_x(
    const float* __restrict__ X, bf16* __restrict__ XTH, bf16* __restrict__ XTL) {
  const int b = blockIdx.z, c0 = blockIdx.y * 64, n0 = blockIdx.x * 64;
  __shared__ float tile[64][65];
  const int tid = threadIdx.x;
  const int rr = tid >> 4, q4 = (tid & 15) << 2;
#pragma unroll
  for (int r = 0; r < 4; ++r) {
    const int c = r * 16 + rr;
    *reinterpret_cast<float4*>(&tile[c][q4]) = *reinterpret_cast<const float4*>(
        &X[((size_t)b * C_ + c0 + c) * N_ + n0 + q4]);
  }
  __syncthreads();
#pragma unroll
  for (int r = 0; r < 4; ++r) {
    const int n = r * 16 + rr;
    bf16x4 oh, ol;
#pragma unroll
    for (int e = 0; e < 4; ++e) {
      const float v = tile[q4 + e][n];
      const bf16 h = (bf16)v;
      oh[e] = h;
      ol[e] = lo_part(v, h);
    }
    const size_t off = ((size_t)b * N_ + n0 + n) * C_ + c0 + q4;
    *reinterpret_cast<bf16x4*>(&XTH[off]) = oh;
    *reinterpret_cast<bf16x4*>(&XTL[off]) = ol;
  }
}

__global__ void cast_w_split(const float* __restrict__ W, bf16* __restrict__ H,
                             bf16* __restrict__ L) {
  const int i = blockIdx.x * 256 + threadIdx.x;
  const float v = W[i];
  const bf16 h = (bf16)v;
  H[i] = h;
  L[i] = lo_part(v, h);
}

__global__ void cast_mu0T_split(const float* __restrict__ MU0,
                                bf16* __restrict__ H, bf16* __restrict__ L) {
  const int k = blockIdx.x;
  for (int c = threadIdx.x; c < C_; c += 256) {
    const float v = MU0[c * K_ + k];
    const bf16 h = (bf16)v;
    H[k * C_ + c] = h;
    L[k * C_ + c] = lo_part(v, h);
  }
}

// ---------------------------------------------------------------------------
// conv1: xs_NC = XT . w1^T + b1, split-bf16 3-pass MFMA. 128x128 tile, BK=64.
// Epilogue: LDS repack (reusing staging LDS) -> bf16x8 coalesced stores.
// ---------------------------------------------------------------------------
__global__ __launch_bounds__(256) void conv1_split(
    const bf16* __restrict__ XTH, const bf16* __restrict__ XTL,
    const bf16* __restrict__ W1H, const bf16* __restrict__ W1L,
    const float* __restrict__ bias, bf16* __restrict__ XSH,
    bf16* __restrict__ XSL) {
  const int bz = blockIdx.z;
  const int m0 = blockIdx.x * 128, n0 = blockIdx.y * 128;
  const bf16* __restrict__ AH = XTH + (size_t)bz * N_ * C_;
  const bf16* __restrict__ AL = XTL + (size_t)bz * N_ * C_;

  __shared__ bf16 SM[4 * 128 * 64];  // Ah|Al|Bh|Bl; first 32KB reused as EP
  bf16* Ah = SM;
  bf16* Al = SM + 8192;
  bf16* Bh = SM + 16384;
  bf16* Bl = SM + 24576;

  const int tid = threadIdx.x, wid = tid >> 6, lane = tid & 63;
  const int lc = lane & 15, hi = lane >> 4;
  const int wm = wid >> 1, wn = wid & 1;
  const int swz = lc & 7;

  f32x4 acc[4][4] = {};

  for (int k0 = 0; k0 < C_; k0 += 64) {
#pragma unroll
    for (int it = 0; it < 4; ++it) {
      const int chunk = it * 256 + tid;
      const int row = chunk >> 3;
      const int koff = (((chunk & 7) ^ (row & 7)) << 3);
      const size_t doff = (size_t)(it * 256 + wid * 64) * 8;
      GLDS16(AH + (size_t)(m0 + row) * C_ + k0 + koff, Ah + doff);
      GLDS16(AL + (size_t)(m0 + row) * C_ + k0 + koff, Al + doff);
      GLDS16(W1H + (size_t)(n0 + row) * C_ + k0 + koff, Bh + doff);
      GLDS16(W1L + (size_t)(n0 + row) * C_ + k0 + koff, Bl + doff);
    }
    __syncthreads();
#pragma unroll
    for (int ks = 0; ks < 2; ++ks) {
      bf16x8 ah[4], al4[4], bh[4], bl4[4];
      const int kc = (((ks << 2) + hi) ^ swz) << 3;
#pragma unroll
      for (int i = 0; i < 4; ++i) {
        ah[i] = *reinterpret_cast<const bf16x8*>(Ah + (wm * 64 + i * 16 + lc) * 64 + kc);
        al4[i] = *reinterpret_cast<const bf16x8*>(Al + (wm * 64 + i * 16 + lc) * 64 + kc);
      }
#pragma unroll
      for (int j = 0; j < 4; ++j) {
        bh[j] = *reinterpret_cast<const bf16x8*>(Bh + (wn * 64 + j * 16 + lc) * 64 + kc);
        bl4[j] = *reinterpret_cast<const bf16x8*>(Bl + (wn * 64 + j * 16 + lc) * 64 + kc);
      }
#pragma unroll
      for (int i = 0; i < 4; ++i)
#pragma unroll
        for (int j = 0; j < 4; ++j) {
          acc[i][j] = __builtin_amdgcn_mfma_f32_16x16x32_bf16(al4[i], bh[j], acc[i][j], 0, 0, 0);
          acc[i][j] = __builtin_amdgcn_mfma_f32_16x16x32_bf16(ah[i], bl4[j], acc[i][j], 0, 0, 0);
          acc[i][j] = __builtin_amdgcn_mfma_f32_16x16x32_bf16(ah[i], bh[j], acc[i][j], 0, 0, 0);
        }
    }
    __syncthreads();
  }

  // epilogue: repack via LDS (staging region dead), coalesced bf16x8 stores
  bf16 (*EP)[128] = reinterpret_cast<bf16(*)[128]>(SM);
  const int rr = tid >> 4, c8 = (tid & 15) << 3;
#pragma unroll
  for (int plane = 0; plane < 2; ++plane) {
    if (plane) __syncthreads();
#pragma unroll
    for (int j = 0; j < 4; ++j) {
      const int coll = wn * 64 + j * 16 + lc;
      const float bv = bias[n0 + coll];
#pragma unroll
      for (int i = 0; i < 4; ++i) {
        const int rowl = wm * 64 + i * 16 + hi * 4;
#pragma unroll
        for (int r = 0; r < 4; ++r) {
          const float v = acc[i][j][r] + bv;
          const bf16 h = (bf16)v;
          EP[rowl + r][coll] = plane ? lo_part(v, h) : h;
        }
      }
    }
    __syncthreads();
    bf16* DST = plane ? XSL : XSH;
#pragma unroll
    for (int rep = 0; rep < 8; ++rep) {
      const int row = rep * 16 + rr;
      *reinterpret_cast<bf16x8*>(&DST[((size_t)bz * N_ + m0 + row) * C_ + n0 + c8]) =
          *reinterpret_cast<const bf16x8*>(&EP[row][c8]);
    }
  }
}

// ---------------------------------------------------------------------------
// E-step: logits = xs . mu^T (split 3-pass), fp32 softmax over K=64.
// ---------------------------------------------------------------------------
__global__ __launch_bounds__(256) void estep_split(
    const bf16* __restrict__ XSH, const bf16* __restrict__ XSL,
    const bf16* __restrict__ MTH, const bf16* __restrict__ MTL,
    size_t mustride, bf16* __restrict__ ZH, bf16* __restrict__ ZL,
    float* __restrict__ colsum, int b_base) {
  const int b = b_base + blockIdx.y;
  const int m0 = blockIdx.x * 128;
  const bf16* __restrict__ AHp = XSH + (size_t)b * N_ * C_;
  const bf16* __restrict__ ALp = XSL + (size_t)b * N_ * C_;
  const bf16* __restrict__ BHp = MTH + (size_t)b * mustride;
  const bf16* __restrict__ BLp = MTL + (size_t)b * mustride;

  __shared__ bf16 Ah[128][64], Al[128][64], Bh[64][64], Bl[64][64];
  __shared__ float cs[64];

  const int tid = threadIdx.x, wid = tid >> 6, lane = tid & 63;
  const int lc = lane & 15, hi = lane >> 4;
  const int swz = lc & 7;
  if (tid < 64) cs[tid] = 0.0f;

  f32x4 acc[2][4] = {};
  for (int k0 = 0; k0 < C_; k0 += 64) {
#pragma unroll
    for (int it = 0; it < 4; ++it) {
      const int chunk = it * 256 + tid;
      const int row = chunk >> 3;
      const int koff = (((chunk & 7) ^ (row & 7)) << 3);
      const size_t doff = (size_t)(it * 256 + wid * 64) * 8;
      GLDS16(AHp + (size_t)(m0 + row) * C_ + k0 + koff, &Ah[0][0] + doff);
      GLDS16(ALp + (size_t)(m0 + row) * C_ + k0 + koff, &Al[0][0] + doff);
    }
#pragma unroll
    for (int it = 0; it < 2; ++it) {
      const int chunk = it * 256 + tid;
      const int row = chunk >> 3;
      const int koff = (((chunk & 7) ^ (row & 7)) << 3);
      const size_t doff = (size_t)(it * 256 + wid * 64) * 8;
      GLDS16(BHp + (size_t)row * C_ + k0 + koff, &Bh[0][0] + doff);
      GLDS16(BLp + (size_t)row * C_ + k0 + koff, &Bl[0][0] + doff);
    }
    __syncthreads();
#pragma unroll
    for (int ks = 0; ks < 2; ++ks) {
      const int kc = (((ks << 2) + hi) ^ swz) << 3;
      bf16x8 ah[2], al4[2], bh[4], bl4[4];
#pragma unroll
      for (int i = 0; i < 2; ++i) {
        ah[i] = *reinterpret_cast<const bf16x8*>(&Ah[wid * 32 + i * 16 + lc][kc]);
        al4[i] = *reinterpret_cast<const bf16x8*>(&Al[wid * 32 + i * 16 + lc][kc]);
      }
#pragma unroll
      for (int j = 0; j < 4; ++j) {
        bh[j] = *reinterpret_cast<const bf16x8*>(&Bh[j * 16 + lc][kc]);
        bl4[j] = *reinterpret_cast<const bf16x8*>(&Bl[j * 16 + lc][kc]);
      }
#pragma unroll
      for (int i = 0; i < 2; ++i)
#pragma unroll
        for (int j = 0; j < 4; ++j) {
          acc[i][j] = __builtin_amdgcn_mfma_f32_16x16x32_bf16(al4[i], bh[j], acc[i][j], 0, 0, 0);
          acc[i][j] = __builtin_amdgcn_mfma_f32_16x16x32_bf16(ah[i], bl4[j], acc[i][j], 0, 0, 0);
          acc[i][j] = __builtin_amdgcn_mfma_f32_16x16x32_bf16(ah[i], bh[j], acc[i][j], 0, 0, 0);
        }
    }
    __syncthreads();
  }

  float cp[4] = {0.f, 0.f, 0.f, 0.f};
#pragma unroll
  for (int i = 0; i < 2; ++i) {
#pragma unroll
    for (int r = 0; r < 4; ++r) {
      float v0 = acc[i][0][r], v1 = acc[i][1][r], v2 = acc[i][2][r], v3 = acc[i][3][r];
      float mx = fmaxf(fmaxf(v0, v1), fmaxf(v2, v3));
#pragma unroll
      for (int off = 1; off < 16; off <<= 1) mx = fmaxf(mx, __shfl_xor(mx, off));
      float p0 = __expf(v0 - mx), p1 = __expf(v1 - mx);
      float p2 = __expf(v2 - mx), p3 = __expf(v3 - mx);
      float s = p0 + p1 + p2 + p3;
#pragma unroll
      for (int off = 1; off < 16; off <<= 1) s += __shfl_xor(s, off);
      const float inv = 1.0f / s;
      p0 *= inv; p1 *= inv; p2 *= inv; p3 *= inv;
      const int n = m0 + wid * 32 + i * 16 + hi * 4 + r;
      bf16* zh = ZH + ((size_t)b * N_ + n) * K_;
      bf16* zl = ZL + ((size_t)b * N_ + n) * K_;
      const float pv[4] = {p0, p1, p2, p3};
#pragma unroll
      for (int j = 0; j < 4; ++j) {
        const bf16 h = (bf16)pv[j];
        zh[j * 16 + lc] = h;
        zl[j * 16 + lc] = lo_part(pv[j], h);
        cp[j] += pv[j];
      }
    }
  }
#pragma unroll
  for (int j = 0; j < 4; ++j) atomicAdd(&cs[j * 16 + lc], cp[j]);
  __syncthreads();
  if (tid < 64) atomicAdd(&colsum[b * K_ + tid], cs[tid]);
}

// ---------------------------------------------------------------------------
// M-step: muacc (C x K) += sum_n xs[n][c]*z[n][k], split 3-pass.
// ---------------------------------------------------------------------------
__global__ __launch_bounds__(128) void mstep_split(
    const bf16* __restrict__ XSH, const bf16* __restrict__ XSL,
    const bf16* __restrict__ ZHp, const bf16* __restrict__ ZLp,
    float* __restrict__ MUACC, int b_base) {
  const int b = b_base + blockIdx.z;
  const int c0 = blockIdx.y * 128;
  const int nbase = blockIdx.x * MCHUNK;
  const bf16* __restrict__ XbH = XSH + (size_t)b * N_ * C_;
  const bf16* __restrict__ XbL = XSL + (size_t)b * N_ * C_;
  const bf16* __restrict__ ZbH = ZHp + (size_t)b * N_ * K_;
  const bf16* __restrict__ ZbL = ZLp + (size_t)b * N_ * K_;

  __shared__ bf16 Ah[128][40], Al[128][40], Bh[64][40], Bl[64][40];

  const int tid = threadIdx.x, wid = tid >> 6, lane = tid & 63;
  const int lc = lane & 15, hi = lane >> 4;

  f32x4 acc[4][4] = {};
  for (int n0 = nbase; n0 < nbase + MCHUNK; n0 += 32) {
#pragma unroll
    for (int it = 0; it < 4; ++it) {
      const int chunk = it * 128 + tid;
      const int nn = chunk & 31, c8 = (chunk >> 5) * 8;
      const bf16x8 vh = *reinterpret_cast<const bf16x8*>(
          &XbH[(size_t)(n0 + nn) * C_ + c0 + c8]);
      const bf16x8 vl = *reinterpret_cast<const bf16x8*>(
          &XbL[(size_t)(n0 + nn) * C_ + c0 + c8]);
#pragma unroll
      for (int e = 0; e < 8; ++e) {
        Ah[c8 + e][nn] = vh[e];
        Al[c8 + e][nn] = vl[e];
      }
    }
#pragma unroll
    for (int it = 0; it < 2; ++it) {
      const int chunk = it * 128 + tid;
      const int nn = chunk & 31, k8 = (chunk >> 5) * 8;
      const bf16x8 vh = *reinterpret_cast<const bf16x8*>(
          &ZbH[(size_t)(n0 + nn) * K_ + k8]);
      const bf16x8 vl = *reinterpret_cast<const bf16x8*>(
          &ZbL[(size_t)(n0 + nn) * K_ + k8]);
#pragma unroll
      for (int e = 0; e < 8; ++e) {
        Bh[k8 + e][nn] = vh[e];
        Bl[k8 + e][nn] = vl[e];
      }
    }
    __syncthreads();
    bf16x8 ah[4], al4[4], bh[4], bl4[4];
#pragma unroll
    for (int i = 0; i < 4; ++i) {
      ah[i] = *reinterpret_cast<const bf16x8*>(&Ah[wid * 64 + i * 16 + lc][hi * 8]);
      al4[i] = *reinterpret_cast<const bf16x8*>(&Al[wid * 64 + i * 16 + lc][hi * 8]);
    }
#pragma unroll
    for (int j = 0; j < 4; ++j) {
      bh[j] = *reinterpret_cast<const bf16x8*>(&Bh[j * 16 + lc][hi * 8]);
      bl4[j] = *reinterpret_cast<const bf16x8*>(&Bl[j * 16 + lc][hi * 8]);
    }
#pragma unroll
    for (int i = 0; i < 4; ++i)
#pragma unroll
      for (int j = 0; j < 4; ++j) {
        acc[i][j] = __builtin_amdgcn_mfma_f32_16x16x32_bf16(al4[i], bh[j], acc[i][j], 0, 0, 0);
        acc[i][j] = __builtin_amdgcn_mfma_f32_16x16x32_bf16(ah[i], bl4[j], acc[i][j], 0, 0, 0);
        acc[i][j] = __builtin_amdgcn_mfma_f32_16x16x32_bf16(ah[i], bh[j], acc[i][j], 0, 0, 0);
      }
    __syncthreads();
  }
#pragma unroll
  for (int i = 0; i < 4; ++i) {
    const int c = c0 + wid * 64 + i * 16 + hi * 4;
#pragma unroll
    for (int r = 0; r < 4; ++r)
#pragma unroll
      for (int j = 0; j < 4; ++j)
        atomicAdd(&MUACC[((size_t)b * C_ + c + r) * K_ + j * 16 + lc], acc[i][j][r]);
  }
}

// ---------------------------------------------------------------------------
// finalize mu; also re-zeroes its MUACC slice for the next iteration.
// ---------------------------------------------------------------------------
__global__ void finalize_mu(float* __restrict__ MUACC,
                            const float* __restrict__ colsum,
                            bf16* __restrict__ MUTH, bf16* __restrict__ MUTL,
                            bf16* __restrict__ MUH, float* __restrict__ muout,
                            int idx_base) {
  const int idx = idx_base + blockIdx.x * 256 + threadIdx.x;
  const int k = idx & (K_ - 1);
  const int c = (idx >> 6) & (C_ - 1);
  const int b = idx >> 15;
  const float v = MUACC[idx] / (1e-6f + colsum[b * K_ + k]);
  MUACC[idx] = 0.0f;  // ready for next iteration (replaces per-iter memset)
  const bf16 h = (bf16)v;
  MUH[idx] = h;
  MUTH[((size_t)b * K_ + k) * C_ + c] = h;
  MUTL[((size_t)b * K_ + k) * C_ + c] = lo_part(v, h);
  if (muout) muout[idx] = v;
}

// ---------------------------------------------------------------------------
// x2_NC = relu(z . mu^T), plain bf16, single K=64 tile.
// Epilogue: LDS repack -> bf16x8 coalesced stores.
// ---------------------------------------------------------------------------
__global__ __launch_bounds__(256) void x2_plain(
    const bf16* __restrict__ ZHp, const bf16* __restrict__ MUHp,
    bf16* __restrict__ X2) {
  const int b = blockIdx.z;
  const int m0 = blockIdx.x * 128, n0 = blockIdx.y * 128;
  const bf16* __restrict__ Ab = ZHp + (size_t)b * N_ * K_;
  const bf16* __restrict__ Bb = MUHp + (size_t)b * C_ * K_;

  __shared__ bf16 SM[2 * 128 * 64];  // As|Bs; reused as EP[128][128]
  bf16* As = SM;
  bf16* Bs = SM + 8192;

  const int tid = threadIdx.x, wid = tid >> 6, lane = tid & 63;
  const int lc = lane & 15, hi = lane >> 4;
  const int wm = wid >> 1, wn = wid & 1;
  const int swz = lc & 7;

  f32x4 acc[4][4] = {};
#pragma unroll
  for (int it = 0; it < 4; ++it) {
    const int chunk = it * 256 + tid;
    const int row = chunk >> 3;
    const int koff = (((chunk & 7) ^ (row & 7)) << 3);
    const size_t doff = (size_t)(it * 256 + wid * 64) * 8;
    GLDS16(Ab + (size_t)(m0 + row) * K_ + koff, As + doff);
    GLDS16(Bb + (size_t)(n0 + row) * K_ + koff, Bs + doff);
  }
  __syncthreads();
#pragma unroll
  for (int ks = 0; ks < 2; ++ks) {
    const int kc = (((ks << 2) + hi) ^ swz) << 3;
    bf16x8 af[4], bg[4];
#pragma unroll
    for (int i = 0; i < 4; ++i)
      af[i] = *reinterpret_cast<const bf16x8*>(As + (wm * 64 + i * 16 + lc) * 64 + kc);
#pragma unroll
    for (int j = 0; j < 4; ++j)
      bg[j] = *reinterpret_cast<const bf16x8*>(Bs + (wn * 64 + j * 16 + lc) * 64 + kc);
#pragma unroll
    for (int i = 0; i < 4; ++i)
#pragma unroll
      for (int j = 0; j < 4; ++j)
        acc[i][j] = __builtin_amdgcn_mfma_f32_16x16x32_bf16(af[i], bg[j], acc[i][j], 0, 0, 0);
  }
  __syncthreads();  // staging reads done before EP overwrite

  bf16 (*EP)[128] = reinterpret_cast<bf16(*)[128]>(SM);
#pragma unroll
  for (int j = 0; j < 4; ++j) {
    const int coll = wn * 64 + j * 16 + lc;
#pragma unroll
    for (int i = 0; i < 4; ++i) {
      const int rowl = wm * 64 + i * 16 + hi * 4;
#pragma unroll
      for (int r = 0; r < 4; ++r)
        EP[rowl + r][coll] = (bf16)fmaxf(acc[i][j][r], 0.0f);
    }
  }
  __syncthreads();
  const int rr = tid >> 4, c8 = (tid & 15) << 3;
#pragma unroll
  for (int rep = 0; rep < 8; ++rep) {
    const int row = rep * 16 + rr;
    *reinterpret_cast<bf16x8*>(&X2[((size_t)b * N_ + m0 + row) * C_ + n0 + c8]) =
        *reinterpret_cast<const bf16x8*>(&EP[row][c8]);
  }
}

// ---------------------------------------------------------------------------
// conv2 (single GEMM): x3 tiles -> per-channel sum/sumsq partials AND
// x3 fp32 stored into OUT (xs planes there are dead). EPF repack, coalesced.
// ---------------------------------------------------------------------------
__global__ __launch_bounds__(256) void conv2_full(
    const bf16* __restrict__ W2H, const bf16* __restrict__ X2,
    float* __restrict__ psumP, float* __restrict__ psqP,
    float* __restrict__ X3out) {
  const int b = blockIdx.z;
  const int m0 = blockIdx.x * 128, n0 = blockIdx.y * 128;
  const bf16* __restrict__ Bb = X2 + (size_t)b * N_ * C_;

  __shared__ bf16 SM[2 * 128 * 64];  // As|Bs; reused as EPF[32][132]
  bf16* As = SM;
  bf16* Bs = SM + 8192;
  __shared__ float s_sum[128], s_sq[128];

  const int tid = threadIdx.x, wid = tid >> 6, lane = tid & 63;
  const int lc = lane & 15, hi = lane >> 4;
  const int wm = wid >> 1, wn = wid & 1;
  const int swz = lc & 7;
  if (tid < 128) { s_sum[tid] = 0.0f; s_sq[tid] = 0.0f; }

  f32x4 acc[4][4] = {};
  for (int k0 = 0; k0 < C_; k0 += 64) {
#pragma unroll
    for (int it = 0; it < 4; ++it) {
      const int chunk = it * 256 + tid;
      const int row = chunk >> 3;
      const int koff = (((chunk & 7) ^ (row & 7)) << 3);
      const size_t doff = (size_t)(it * 256 + wid * 64) * 8;
      GLDS16(W2H + (size_t)(m0 + row) * C_ + k0 + koff, As + doff);
      GLDS16(Bb + (size_t)(n0 + row) * C_ + k0 + koff, Bs + doff);
    }
    __syncthreads();
#pragma unroll
    for (int ks = 0; ks < 2; ++ks) {
      const int kc = (((ks << 2) + hi) ^ swz) << 3;
      bf16x8 af[4], bg[4];
#pragma unroll
      for (int i = 0; i < 4; ++i)
        af[i] = *reinterpret_cast<const bf16x8*>(As + (wm * 64 + i * 16 + lc) * 64 + kc);
#pragma unroll
      for (int j = 0; j < 4; ++j)
        bg[j] = *reinterpret_cast<const bf16x8*>(Bs + (wn * 64 + j * 16 + lc) * 64 + kc);
#pragma unroll
      for (int i = 0; i < 4; ++i)
#pragma unroll
        for (int j = 0; j < 4; ++j)
          acc[i][j] = __builtin_amdgcn_mfma_f32_16x16x32_bf16(af[i], bg[j], acc[i][j], 0, 0, 0);
    }
    __syncthreads();
  }

  // stats: reduce over the 16 lc-lanes, LDS atomics into s_sum/s_sq
  float ps[4][4] = {};
  float pq[4][4] = {};
#pragma unroll
  for (int j = 0; j < 4; ++j)
#pragma unroll
    for (int i = 0; i < 4; ++i)
#pragma unroll
      for (int r = 0; r < 4; ++r) {
        const float v = acc[i][j][r];
        ps[i][r] += v;
        pq[i][r] += v * v;
      }
#pragma unroll
  for (int off = 1; off < 16; off <<= 1)
#pragma unroll
    for (int i = 0; i < 4; ++i)
#pragma unroll
      for (int r = 0; r < 4; ++r) {
        ps[i][r] += __shfl_xor(ps[i][r], off);
        pq[i][r] += __shfl_xor(pq[i][r], off);
      }
  if (lc == 0) {
#pragma unroll
    for (int i = 0; i < 4; ++i) {
      const int chl = wm * 64 + i * 16 + hi * 4;
#pragma unroll
      for (int r = 0; r < 4; ++r) {
        atomicAdd(&s_sum[chl + r], ps[i][r]);
        atomicAdd(&s_sq[chl + r], pq[i][r]);
      }
    }
  }

  // x3 fp32 via EPF repack (staging LDS dead since last barrier) -> OUT
  float (*EPF)[132] = reinterpret_cast<float(*)[132]>(SM);  // 16.9 KB
  const int rr = tid >> 3, c4 = (tid & 7) << 2;
#pragma unroll
  for (int i = 0; i < 4; ++i) {
    __syncthreads();  // prev slice's reads (or staging/atomics) done
#pragma unroll
    for (int j = 0; j < 4; ++j) {
      const int coll = wn * 64 + j * 16 + lc;
#pragma unroll
      for (int r = 0; r < 4; ++r)
        EPF[wm * 16 + hi * 4 + r][coll] = acc[i][j][r];
    }
    __syncthreads();
    const int m = m0 + (rr >> 4) * 64 + i * 16 + (rr & 15);
#pragma unroll
    for (int rep = 0; rep < 4; ++rep) {
      const int col = rep * 32 + c4;
      const size_t off = ((size_t)b * C_ + m) * N_ + n0 + col;
      float4 ov;
      ov.x = EPF[rr][col + 0];
      ov.y = EPF[rr][col + 1];
      ov.z = EPF[rr][col + 2];
      ov.w = EPF[rr][col + 3];
      *reinterpret_cast<float4*>(&X3out[off]) = ov;
    }
  }

  const int p = b * 64 + blockIdx.y;
  if (tid < 128) {
    psumP[(size_t)p * C_ + m0 + tid] = s_sum[tid];
    psqP[(size_t)p * C_ + m0 + tid] = s_sq[tid];
  }
}

// ---------------------------------------------------------------------------
__global__ __launch_bounds__(256) void bn_finalize2(
    const float* __restrict__ psumP, const float* __restrict__ psqP,
    const float* __restrict__ gamma, const float* __restrict__ beta,
    float* __restrict__ gc, float* __restrict__ oc) {
  const int c = blockIdx.x;
  const int tid = threadIdx.x;
  float s = 0.0f, q = 0.0f;
  for (int p = tid; p < B_ * 64; p += 256) {
    s += psumP[(size_t)p * C_ + c];
    q += psqP[(size_t)p * C_ + c];
  }
  __shared__ float ls[256], lq[256];
  ls[tid] = s;
  lq[tid] = q;
  __syncthreads();
  for (int off = 128; off > 0; off >>= 1) {
    if (tid < off) { ls[tid] += ls[tid + off]; lq[tid] += lq[tid + off]; }
    __syncthreads();
  }
  if (tid == 0) {
    const float inv = 1.0f / ((float)B_ * N_);
    const float mean = ls[0] * inv;
    const float var = lq[0] * inv - mean * mean;
    const float rstd = rsqrtf(var + 1e-5f);
    const float g = gamma[c] * rstd;
    gc[c] = g;
    oc[c] = beta[c] - mean * g;
  }
}

// ---------------------------------------------------------------------------
// In-place BN + residual: OUT[i] = OUT[i]*g + o + x[i]. Same-thread RMW only.
// ---------------------------------------------------------------------------
__global__ __launch_bounds__(256) void bn_inplace(
    float* __restrict__ OUT, const float* __restrict__ Xin,
    const float* __restrict__ gc, const float* __restrict__ oc) {
  const size_t total4 = (size_t)B_ * C_ * N_ / 4;
  for (size_t i = (size_t)blockIdx.x * 256 + threadIdx.x; i < total4;
       i += (size_t)gridDim.x * 256) {
    const int c = (int)((i >> 11) & (C_ - 1));  // N/4 = 2048
    const float g = gc[c];
    const float o = oc[c];
    float4 v = reinterpret_cast<const float4*>(OUT)[i];
    const float4 xi = reinterpret_cast<const float4*>(Xin)[i];
    v.x = v.x * g + o + xi.x;
    v.y = v.y * g + o + xi.y;
    v.z = v.z * g + o + xi.z;
    v.w = v.w * g + o + xi.w;
    reinterpret_cast<float4*>(OUT)[i] = v;
  }
}

// ---------------------------------------------------------------------------
extern "C" void kernel_launch(void* const* d_in, const int* in_sizes, int n_in,
                              void* d_out, int out_size, void* d_ws,
                              size_t ws_size, hipStream_t stream) {
  (void)in_sizes; (void)n_in; (void)out_size; (void)ws_size;
  const float* x     = (const float*)d_in[0];
  const float* w1    = (const float*)d_in[1];
  const float* b1    = (const float*)d_in[2];
  const float* mu0   = (const float*)d_in[3];
  const float* w2    = (const float*)d_in[4];
  const float* gamma = (const float*)d_in[5];
  const float* beta  = (const float*)d_in[6];

  // d_out: xs hi/lo planes live here until conv2_full overwrites with x3 fp32.
  bf16* XSH = (bf16*)d_out;
  bf16* XSL = XSH + (size_t)B_ * N_ * C_;
  float* OUT = (float*)d_out;
  float* MUOUT = OUT + (size_t)B_ * C_ * N_;

  // d_ws layout (identical to round 7)
  bf16* XTH = (bf16*)d_ws;                          // BHALF*N*C
  bf16* XTL = XTH + (size_t)BHALF * N_ * C_;        // BHALF*N*C
  bf16* X2b = XTH;                                  // alias after conv1 (B*N*C)
  bf16* ZH  = XTH + (size_t)B_ * N_ * C_;           // B*N*K
  bf16* ZL  = ZH + (size_t)B_ * N_ * K_;
  bf16* W1H = ZL + (size_t)B_ * N_ * K_;
  bf16* W1L = W1H + C_ * C_;
  bf16* W2H = W1L + C_ * C_;
  bf16* W2L = W2H + C_ * C_;
  bf16* MT0H = W2L + C_ * C_;                       // K*C
  bf16* MT0L = MT0H + K_ * C_;
  bf16* MUTH = MT0L + K_ * C_;                      // B*K*C
  bf16* MUTL = MUTH + (size_t)B_ * K_ * C_;
  bf16* MUH  = MUTL + (size_t)B_ * K_ * C_;         // B*C*K
  float* MUACC = (float*)(MUH + (size_t)B_ * C_ * K_);
  float* colsum = MUACC + (size_t)B_ * C_ * K_;     // B*K
  float* gcp = colsum + B_ * K_;                    // C
  float* ocp = gcp + C_;                            // C
  float* psumP = ocp + C_;                          // 1024*C
  float* psqP  = psumP + (size_t)B_ * 64 * C_;      // 1024*C

  const dim3 blk(256);

  cast_w_split<<<dim3(C_ * C_ / 256), blk, 0, stream>>>(w1, W1H, W1L);
  cast_w_split<<<dim3(C_ * C_ / 256), blk, 0, stream>>>(w2, W2H, W2L);
  cast_mu0T_split<<<dim3(K_), blk, 0, stream>>>(mu0, MT0H, MT0L);
  hipMemsetAsync(MUACC, 0, (size_t)B_ * C_ * K_ * sizeof(float), stream);

  for (int half = 0; half < 2; ++half) {
    const float* xh = x + (size_t)half * BHALF * C_ * N_;
    transpose_split_x<<<dim3(N_ / 64, C_ / 64, BHALF), blk, 0, stream>>>(xh, XTH, XTL);
    conv1_split<<<dim3(N_ / 128, C_ / 128, BHALF), blk, 0, stream>>>(
        XTH, XTL, W1H, W1L, b1,
        XSH + (size_t)half * BHALF * N_ * C_, XSL + (size_t)half * BHALF * N_ * C_);
  }

  // EM: grouped by batches so xs hi/lo (134 MB/group) stays L3-resident
  for (int g = 0; g < B_ / BGRP; ++g) {
    const int boff = g * BGRP;
    for (int it = 0; it < 3; ++it) {
      hipMemsetAsync(colsum + boff * K_, 0, BGRP * K_ * sizeof(float), stream);
      estep_split<<<dim3(N_ / 128, BGRP), blk, 0, stream>>>(
          XSH, XSL, it == 0 ? MT0H : MUTH, it == 0 ? MT0L : MUTL,
          it == 0 ? 0 : (size_t)K_ * C_, ZH, ZL, colsum, boff);
      mstep_split<<<dim3(N_ / MCHUNK, C_ / 128, BGRP), dim3(128), 0, stream>>>(
          XSH, XSL, ZH, ZL, MUACC, boff);
      finalize_mu<<<dim3(BGRP * C_ * K_ / 256), blk, 0, stream>>>(
          MUACC, colsum, MUTH, MUTL, MUH, it == 2 ? MUOUT : nullptr,
          boff * C_ * K_);
    }
  }

  x2_plain<<<dim3(N_ / 128, C_ / 128, B_), blk, 0, stream>>>(ZH, MUH, X2b);
  // single conv2 GEMM: stats partials + x3 fp32 into OUT (xs planes dead)
  conv2_full<<<dim3(C_ / 128, N_ / 128, B_), blk, 0, stream>>>(
      W2H, X2b, psumP, psqP, OUT);
  bn_finalize2<<<dim3(C_), blk, 0, stream>>>(psumP, psqP, gamma, beta, gcp, ocp);
  // in-place BN + residual
  bn_inplace<<<dim3(2048), blk, 0, stream>>>(OUT, x, gcp, ocp);
}

// Round 10
// 1153.111 us; speedup vs baseline: 1.0413x; 1.0413x over previous
//
#include <hip/hip_runtime.h>
#include <math.h>

constexpr int B_ = 16, C_ = 512, K_ = 64, N_ = 8192;
constexpr int BGRP = 8;       // EM batch group size (L3 residency)
constexpr int MCHUNK = 512;   // mstep n-chunk

typedef __bf16 bf16;
typedef __bf16 bf16x4 __attribute__((ext_vector_type(4)));
typedef __bf16 bf16x8 __attribute__((ext_vector_type(8)));
typedef float f32x4 __attribute__((ext_vector_type(4)));

#define GLDS16(gp, lp)                                              \
  __builtin_amdgcn_global_load_lds(                                 \
      (const __attribute__((address_space(1))) unsigned int*)(gp),  \
      (__attribute__((address_space(3))) unsigned int*)(lp), 16, 0, 0)

__device__ __forceinline__ bf16 lo_part(float v, bf16 h) {
  return (bf16)(v - (float)h);
}

__global__ void cast_w_split(const float* __restrict__ W, bf16* __restrict__ H,
                             bf16* __restrict__ L) {
  const int i = blockIdx.x * 256 + threadIdx.x;
  const float v = W[i];
  const bf16 h = (bf16)v;
  H[i] = h;
  L[i] = lo_part(v, h);
}

__global__ void cast_mu0T_split(const float* __restrict__ MU0,
                                bf16* __restrict__ H, bf16* __restrict__ L) {
  const int k = blockIdx.x;
  for (int c = threadIdx.x; c < C_; c += 256) {
    const float v = MU0[c * K_ + k];
    const bf16 h = (bf16)v;
    H[k * C_ + c] = h;
    L[k * C_ + c] = lo_part(v, h);
  }
}

// ---------------------------------------------------------------------------
// conv1 FUSED transpose: xs_NC = x^T . w1^T + b1, split-bf16 3-pass MFMA.
// A operand staged fp32 directly from x (C,N) in 32-c sub-tiles [32][130];
// hi/lo split done in registers (bitwise-identical to the old XT path).
// B (w1 hi/lo) via GLDS16 + granule swizzle. Epilogue: EP repack -> bf16x8.
// ---------------------------------------------------------------------------
__global__ __launch_bounds__(256) void conv1_fused(
    const float* __restrict__ X, const bf16* __restrict__ W1H,
    const bf16* __restrict__ W1L, const float* __restrict__ bias,
    bf16* __restrict__ XSH, bf16* __restrict__ XSL) {
  const int bz = blockIdx.z;
  const int m0 = blockIdx.x * 128;  // n rows
  const int n0 = blockIdx.y * 128;  // o cols
  const float* __restrict__ Xb = X + (size_t)bz * C_ * N_;

  __shared__ float Xs32[32 * 130];     // 16.6 KB (ld=130: free frag reads)
  __shared__ bf16 Bbuf[2 * 128 * 64];  // 32 KB: Bh | Bl ; reused as EP
  bf16* Bh = Bbuf;
  bf16* Bl = Bbuf + 8192;

  const int tid = threadIdx.x, wid = tid >> 6, lane = tid & 63;
  const int lc = lane & 15, hi = lane >> 4;
  const int wm = wid >> 1, wn = wid & 1;
  const int swz = lc & 7;
  const int srow = tid >> 3, scolg = (tid & 7) << 4;  // A-staging map

  f32x4 acc[4][4] = {};

  for (int k0 = 0; k0 < C_; k0 += 64) {
    // stage B (w1 hi/lo) for this 64-c chunk
#pragma unroll
    for (int it = 0; it < 4; ++it) {
      const int chunk = it * 256 + tid;
      const int row = chunk >> 3;
      const int koff = (((chunk & 7) ^ (row & 7)) << 3);
      const size_t doff = (size_t)(it * 256 + wid * 64) * 8;
      GLDS16(W1H + (size_t)(n0 + row) * C_ + k0 + koff, Bh + doff);
      GLDS16(W1L + (size_t)(n0 + row) * C_ + k0 + koff, Bl + doff);
    }
#pragma unroll
    for (int sub = 0; sub < 2; ++sub) {
      // stage A fp32 sub-tile: rows c = k0+sub*32+srow, cols m0+scolg..+15
      {
        const float* src = &Xb[(size_t)(k0 + sub * 32 + srow) * N_ + m0 + scolg];
        float* dstb = &Xs32[srow * 130 + scolg];
#pragma unroll
        for (int q = 0; q < 4; ++q) {
          const float4 v = *reinterpret_cast<const float4*>(src + q * 4);
          *reinterpret_cast<float2*>(dstb + q * 4) = make_float2(v.x, v.y);
          *reinterpret_cast<float2*>(dstb + q * 4 + 2) = make_float2(v.z, v.w);
        }
      }
      __syncthreads();  // B (sub==0) + A staged
      {
        bf16x8 ah[4], al4[4], bh[4], bl4[4];
        const int kc = (((sub << 2) + hi) ^ swz) << 3;
#pragma unroll
        for (int i = 0; i < 4; ++i) {
          const int arow = wm * 64 + i * 16 + lc;
#pragma unroll
          for (int e = 0; e < 8; ++e) {
            const float v = Xs32[(hi * 8 + e) * 130 + arow];
            const bf16 h = (bf16)v;
            ah[i][e] = h;
            al4[i][e] = lo_part(v, h);
          }
        }
#pragma unroll
        for (int j = 0; j < 4; ++j) {
          bh[j] = *reinterpret_cast<const bf16x8*>(Bh + (wn * 64 + j * 16 + lc) * 64 + kc);
          bl4[j] = *reinterpret_cast<const bf16x8*>(Bl + (wn * 64 + j * 16 + lc) * 64 + kc);
        }
#pragma unroll
        for (int i = 0; i < 4; ++i)
#pragma unroll
          for (int j = 0; j < 4; ++j) {
            acc[i][j] = __builtin_amdgcn_mfma_f32_16x16x32_bf16(al4[i], bh[j], acc[i][j], 0, 0, 0);
            acc[i][j] = __builtin_amdgcn_mfma_f32_16x16x32_bf16(ah[i], bl4[j], acc[i][j], 0, 0, 0);
            acc[i][j] = __builtin_amdgcn_mfma_f32_16x16x32_bf16(ah[i], bh[j], acc[i][j], 0, 0, 0);
          }
      }
      __syncthreads();  // frag reads done before next staging overwrites
    }
  }

  // epilogue: EP repack (B region dead), coalesced bf16x8 stores
  bf16 (*EP)[128] = reinterpret_cast<bf16(*)[128]>(Bbuf);
  const int rr = tid >> 4, c8 = (tid & 15) << 3;
#pragma unroll
  for (int plane = 0; plane < 2; ++plane) {
    if (plane) __syncthreads();
#pragma unroll
    for (int j = 0; j < 4; ++j) {
      const int coll = wn * 64 + j * 16 + lc;
      const float bv = bias[n0 + coll];
#pragma unroll
      for (int i = 0; i < 4; ++i) {
        const int rowl = wm * 64 + i * 16 + hi * 4;
#pragma unroll
        for (int r = 0; r < 4; ++r) {
          const float v = acc[i][j][r] + bv;
          const bf16 h = (bf16)v;
          EP[rowl + r][coll] = plane ? lo_part(v, h) : h;
        }
      }
    }
    __syncthreads();
    bf16* DST = plane ? XSL : XSH;
#pragma unroll
    for (int rep = 0; rep < 8; ++rep) {
      const int row = rep * 16 + rr;
      *reinterpret_cast<bf16x8*>(&DST[((size_t)bz * N_ + m0 + row) * C_ + n0 + c8]) =
          *reinterpret_cast<const bf16x8*>(&EP[row][c8]);
    }
  }
}

// ---------------------------------------------------------------------------
// E-step: logits = xs . mu^T (split 3-pass), fp32 softmax over K=64.
// ---------------------------------------------------------------------------
__global__ __launch_bounds__(256) void estep_split(
    const bf16* __restrict__ XSH, const bf16* __restrict__ XSL,
    const bf16* __restrict__ MTH, const bf16* __restrict__ MTL,
    size_t mustride, bf16* __restrict__ ZH, bf16* __restrict__ ZL,
    float* __restrict__ colsum, int b_base) {
  const int b = b_base + blockIdx.y;
  const int m0 = blockIdx.x * 128;
  const bf16* __restrict__ AHp = XSH + (size_t)b * N_ * C_;
  const bf16* __restrict__ ALp = XSL + (size_t)b * N_ * C_;
  const bf16* __restrict__ BHp = MTH + (size_t)b * mustride;
  const bf16* __restrict__ BLp = MTL + (size_t)b * mustride;

  __shared__ bf16 Ah[128][64], Al[128][64], Bh[64][64], Bl[64][64];
  __shared__ float cs[64];

  const int tid = threadIdx.x, wid = tid >> 6, lane = tid & 63;
  const int lc = lane & 15, hi = lane >> 4;
  const int swz = lc & 7;
  if (tid < 64) cs[tid] = 0.0f;

  f32x4 acc[2][4] = {};
  for (int k0 = 0; k0 < C_; k0 += 64) {
#pragma unroll
    for (int it = 0; it < 4; ++it) {
      const int chunk = it * 256 + tid;
      const int row = chunk >> 3;
      const int koff = (((chunk & 7) ^ (row & 7)) << 3);
      const size_t doff = (size_t)(it * 256 + wid * 64) * 8;
      GLDS16(AHp + (size_t)(m0 + row) * C_ + k0 + koff, &Ah[0][0] + doff);
      GLDS16(ALp + (size_t)(m0 + row) * C_ + k0 + koff, &Al[0][0] + doff);
    }
#pragma unroll
    for (int it = 0; it < 2; ++it) {
      const int chunk = it * 256 + tid;
      const int row = chunk >> 3;
      const int koff = (((chunk & 7) ^ (row & 7)) << 3);
      const size_t doff = (size_t)(it * 256 + wid * 64) * 8;
      GLDS16(BHp + (size_t)row * C_ + k0 + koff, &Bh[0][0] + doff);
      GLDS16(BLp + (size_t)row * C_ + k0 + koff, &Bl[0][0] + doff);
    }
    __syncthreads();
#pragma unroll
    for (int ks = 0; ks < 2; ++ks) {
      const int kc = (((ks << 2) + hi) ^ swz) << 3;
      bf16x8 ah[2], al4[2], bh[4], bl4[4];
#pragma unroll
      for (int i = 0; i < 2; ++i) {
        ah[i] = *reinterpret_cast<const bf16x8*>(&Ah[wid * 32 + i * 16 + lc][kc]);
        al4[i] = *reinterpret_cast<const bf16x8*>(&Al[wid * 32 + i * 16 + lc][kc]);
      }
#pragma unroll
      for (int j = 0; j < 4; ++j) {
        bh[j] = *reinterpret_cast<const bf16x8*>(&Bh[j * 16 + lc][kc]);
        bl4[j] = *reinterpret_cast<const bf16x8*>(&Bl[j * 16 + lc][kc]);
      }
#pragma unroll
      for (int i = 0; i < 2; ++i)
#pragma unroll
        for (int j = 0; j < 4; ++j) {
          acc[i][j] = __builtin_amdgcn_mfma_f32_16x16x32_bf16(al4[i], bh[j], acc[i][j], 0, 0, 0);
          acc[i][j] = __builtin_amdgcn_mfma_f32_16x16x32_bf16(ah[i], bl4[j], acc[i][j], 0, 0, 0);
          acc[i][j] = __builtin_amdgcn_mfma_f32_16x16x32_bf16(ah[i], bh[j], acc[i][j], 0, 0, 0);
        }
    }
    __syncthreads();
  }

  float cp[4] = {0.f, 0.f, 0.f, 0.f};
#pragma unroll
  for (int i = 0; i < 2; ++i) {
#pragma unroll
    for (int r = 0; r < 4; ++r) {
      float v0 = acc[i][0][r], v1 = acc[i][1][r], v2 = acc[i][2][r], v3 = acc[i][3][r];
      float mx = fmaxf(fmaxf(v0, v1), fmaxf(v2, v3));
#pragma unroll
      for (int off = 1; off < 16; off <<= 1) mx = fmaxf(mx, __shfl_xor(mx, off));
      float p0 = __expf(v0 - mx), p1 = __expf(v1 - mx);
      float p2 = __expf(v2 - mx), p3 = __expf(v3 - mx);
      float s = p0 + p1 + p2 + p3;
#pragma unroll
      for (int off = 1; off < 16; off <<= 1) s += __shfl_xor(s, off);
      const float inv = 1.0f / s;
      p0 *= inv; p1 *= inv; p2 *= inv; p3 *= inv;
      const int n = m0 + wid * 32 + i * 16 + hi * 4 + r;
      bf16* zh = ZH + ((size_t)b * N_ + n) * K_;
      bf16* zl = ZL + ((size_t)b * N_ + n) * K_;
      const float pv[4] = {p0, p1, p2, p3};
#pragma unroll
      for (int j = 0; j < 4; ++j) {
        const bf16 h = (bf16)pv[j];
        zh[j * 16 + lc] = h;
        zl[j * 16 + lc] = lo_part(pv[j], h);
        cp[j] += pv[j];
      }
    }
  }
#pragma unroll
  for (int j = 0; j < 4; ++j) atomicAdd(&cs[j * 16 + lc], cp[j]);
  __syncthreads();
  if (tid < 64) atomicAdd(&colsum[b * K_ + tid], cs[tid]);
}

// ---------------------------------------------------------------------------
// M-step: muacc (C x K) += sum_n xs[n][c]*z[n][k], split 3-pass.
// ---------------------------------------------------------------------------
__global__ __launch_bounds__(128) void mstep_split(
    const bf16* __restrict__ XSH, const bf16* __restrict__ XSL,
    const bf16* __restrict__ ZHp, const bf16* __restrict__ ZLp,
    float* __restrict__ MUACC, int b_base) {
  const int b = b_base + blockIdx.z;
  const int c0 = blockIdx.y * 128;
  const int nbase = blockIdx.x * MCHUNK;
  const bf16* __restrict__ XbH = XSH + (size_t)b * N_ * C_;
  const bf16* __restrict__ XbL = XSL + (size_t)b * N_ * C_;
  const bf16* __restrict__ ZbH = ZHp + (size_t)b * N_ * K_;
  const bf16* __restrict__ ZbL = ZLp + (size_t)b * N_ * K_;

  __shared__ bf16 Ah[128][40], Al[128][40], Bh[64][40], Bl[64][40];

  const int tid = threadIdx.x, wid = tid >> 6, lane = tid & 63;
  const int lc = lane & 15, hi = lane >> 4;

  f32x4 acc[4][4] = {};
  for (int n0 = nbase; n0 < nbase + MCHUNK; n0 += 32) {
#pragma unroll
    for (int it = 0; it < 4; ++it) {
      const int chunk = it * 128 + tid;
      const int nn = chunk & 31, c8 = (chunk >> 5) * 8;
      const bf16x8 vh = *reinterpret_cast<const bf16x8*>(
          &XbH[(size_t)(n0 + nn) * C_ + c0 + c8]);
      const bf16x8 vl = *reinterpret_cast<const bf16x8*>(
          &XbL[(size_t)(n0 + nn) * C_ + c0 + c8]);
#pragma unroll
      for (int e = 0; e < 8; ++e) {
        Ah[c8 + e][nn] = vh[e];
        Al[c8 + e][nn] = vl[e];
      }
    }
#pragma unroll
    for (int it = 0; it < 2; ++it) {
      const int chunk = it * 128 + tid;
      const int nn = chunk & 31, k8 = (chunk >> 5) * 8;
      const bf16x8 vh = *reinterpret_cast<const bf16x8*>(
          &ZbH[(size_t)(n0 + nn) * K_ + k8]);
      const bf16x8 vl = *reinterpret_cast<const bf16x8*>(
          &ZbL[(size_t)(n0 + nn) * K_ + k8]);
#pragma unroll
      for (int e = 0; e < 8; ++e) {
        Bh[k8 + e][nn] = vh[e];
        Bl[k8 + e][nn] = vl[e];
      }
    }
    __syncthreads();
    bf16x8 ah[4], al4[4], bh[4], bl4[4];
#pragma unroll
    for (int i = 0; i < 4; ++i) {
      ah[i] = *reinterpret_cast<const bf16x8*>(&Ah[wid * 64 + i * 16 + lc][hi * 8]);
      al4[i] = *reinterpret_cast<const bf16x8*>(&Al[wid * 64 + i * 16 + lc][hi * 8]);
    }
#pragma unroll
    for (int j = 0; j < 4; ++j) {
      bh[j] = *reinterpret_cast<const bf16x8*>(&Bh[j * 16 + lc][hi * 8]);
      bl4[j] = *reinterpret_cast<const bf16x8*>(&Bl[j * 16 + lc][hi * 8]);
    }
#pragma unroll
    for (int i = 0; i < 4; ++i)
#pragma unroll
      for (int j = 0; j < 4; ++j) {
        acc[i][j] = __builtin_amdgcn_mfma_f32_16x16x32_bf16(al4[i], bh[j], acc[i][j], 0, 0, 0);
        acc[i][j] = __builtin_amdgcn_mfma_f32_16x16x32_bf16(ah[i], bl4[j], acc[i][j], 0, 0, 0);
        acc[i][j] = __builtin_amdgcn_mfma_f32_16x16x32_bf16(ah[i], bh[j], acc[i][j], 0, 0, 0);
      }
    __syncthreads();
  }
#pragma unroll
  for (int i = 0; i < 4; ++i) {
    const int c = c0 + wid * 64 + i * 16 + hi * 4;
#pragma unroll
    for (int r = 0; r < 4; ++r)
#pragma unroll
      for (int j = 0; j < 4; ++j)
        atomicAdd(&MUACC[((size_t)b * C_ + c + r) * K_ + j * 16 + lc], acc[i][j][r]);
  }
}

// ---------------------------------------------------------------------------
// finalize mu; also re-zeroes its MUACC slice for the next iteration.
// ---------------------------------------------------------------------------
__global__ void finalize_mu(float* __restrict__ MUACC,
                            const float* __restrict__ colsum,
                            bf16* __restrict__ MUTH, bf16* __restrict__ MUTL,
                            bf16* __restrict__ MUH, float* __restrict__ muout,
                            int idx_base) {
  const int idx = idx_base + blockIdx.x * 256 + threadIdx.x;
  const int k = idx & (K_ - 1);
  const int c = (idx >> 6) & (C_ - 1);
  const int b = idx >> 15;
  const float v = MUACC[idx] / (1e-6f + colsum[b * K_ + k]);
  MUACC[idx] = 0.0f;
  const bf16 h = (bf16)v;
  MUH[idx] = h;
  MUTH[((size_t)b * K_ + k) * C_ + c] = h;
  MUTL[((size_t)b * K_ + k) * C_ + c] = lo_part(v, h);
  if (muout) muout[idx] = v;
}

// ---------------------------------------------------------------------------
// x2_NC = relu(z . mu^T), plain bf16, single K=64 tile. EP repack epilogue.
// ---------------------------------------------------------------------------
__global__ __launch_bounds__(256) void x2_plain(
    const bf16* __restrict__ ZHp, const bf16* __restrict__ MUHp,
    bf16* __restrict__ X2) {
  const int b = blockIdx.z;
  const int m0 = blockIdx.x * 128, n0 = blockIdx.y * 128;
  const bf16* __restrict__ Ab = ZHp + (size_t)b * N_ * K_;
  const bf16* __restrict__ Bb = MUHp + (size_t)b * C_ * K_;

  __shared__ bf16 SM[2 * 128 * 64];
  bf16* As = SM;
  bf16* Bs = SM + 8192;

  const int tid = threadIdx.x, wid = tid >> 6, lane = tid & 63;
  const int lc = lane & 15, hi = lane >> 4;
  const int wm = wid >> 1, wn = wid & 1;
  const int swz = lc & 7;

  f32x4 acc[4][4] = {};
#pragma unroll
  for (int it = 0; it < 4; ++it) {
    const int chunk = it * 256 + tid;
    const int row = chunk >> 3;
    const int koff = (((chunk & 7) ^ (row & 7)) << 3);
    const size_t doff = (size_t)(it * 256 + wid * 64) * 8;
    GLDS16(Ab + (size_t)(m0 + row) * K_ + koff, As + doff);
    GLDS16(Bb + (size_t)(n0 + row) * K_ + koff, Bs + doff);
  }
  __syncthreads();
#pragma unroll
  for (int ks = 0; ks < 2; ++ks) {
    const int kc = (((ks << 2) + hi) ^ swz) << 3;
    bf16x8 af[4], bg[4];
#pragma unroll
    for (int i = 0; i < 4; ++i)
      af[i] = *reinterpret_cast<const bf16x8*>(As + (wm * 64 + i * 16 + lc) * 64 + kc);
#pragma unroll
    for (int j = 0; j < 4; ++j)
      bg[j] = *reinterpret_cast<const bf16x8*>(Bs + (wn * 64 + j * 16 + lc) * 64 + kc);
#pragma unroll
    for (int i = 0; i < 4; ++i)
#pragma unroll
      for (int j = 0; j < 4; ++j)
        acc[i][j] = __builtin_amdgcn_mfma_f32_16x16x32_bf16(af[i], bg[j], acc[i][j], 0, 0, 0);
  }
  __syncthreads();

  bf16 (*EP)[128] = reinterpret_cast<bf16(*)[128]>(SM);
#pragma unroll
  for (int j = 0; j < 4; ++j) {
    const int coll = wn * 64 + j * 16 + lc;
#pragma unroll
    for (int i = 0; i < 4; ++i) {
      const int rowl = wm * 64 + i * 16 + hi * 4;
#pragma unroll
      for (int r = 0; r < 4; ++r)
        EP[rowl + r][coll] = (bf16)fmaxf(acc[i][j][r], 0.0f);
    }
  }
  __syncthreads();
  const int rr = tid >> 4, c8 = (tid & 15) << 3;
#pragma unroll
  for (int rep = 0; rep < 8; ++rep) {
    const int row = rep * 16 + rr;
    *reinterpret_cast<bf16x8*>(&X2[((size_t)b * N_ + m0 + row) * C_ + n0 + c8]) =
        *reinterpret_cast<const bf16x8*>(&EP[row][c8]);
  }
}

// ---------------------------------------------------------------------------
// conv2 pass 1: x3 tiles -> per-channel sum/sumsq non-atomic partials.
// ---------------------------------------------------------------------------
__global__ __launch_bounds__(256) void conv2_stats(
    const bf16* __restrict__ W2H, const bf16* __restrict__ X2,
    float* __restrict__ psumP, float* __restrict__ psqP) {
  const int b = blockIdx.z;
  const int m0 = blockIdx.x * 128, n0 = blockIdx.y * 128;
  const bf16* __restrict__ Bb = X2 + (size_t)b * N_ * C_;

  __shared__ bf16 As[128][64], Bs[128][64];
  __shared__ float s_sum[128], s_sq[128];

  const int tid = threadIdx.x, wid = tid >> 6, lane = tid & 63;
  const int lc = lane & 15, hi = lane >> 4;
  const int wm = wid >> 1, wn = wid & 1;
  const int swz = lc & 7;
  if (tid < 128) { s_sum[tid] = 0.0f; s_sq[tid] = 0.0f; }

  f32x4 acc[4][4] = {};
  for (int k0 = 0; k0 < C_; k0 += 64) {
#pragma unroll
    for (int it = 0; it < 4; ++it) {
      const int chunk = it * 256 + tid;
      const int row = chunk >> 3;
      const int koff = (((chunk & 7) ^ (row & 7)) << 3);
      const size_t doff = (size_t)(it * 256 + wid * 64) * 8;
      GLDS16(W2H + (size_t)(m0 + row) * C_ + k0 + koff, &As[0][0] + doff);
      GLDS16(Bb + (size_t)(n0 + row) * C_ + k0 + koff, &Bs[0][0] + doff);
    }
    __syncthreads();
#pragma unroll
    for (int ks = 0; ks < 2; ++ks) {
      const int kc = (((ks << 2) + hi) ^ swz) << 3;
      bf16x8 af[4], bg[4];
#pragma unroll
      for (int i = 0; i < 4; ++i)
        af[i] = *reinterpret_cast<const bf16x8*>(&As[wm * 64 + i * 16 + lc][kc]);
#pragma unroll
      for (int j = 0; j < 4; ++j)
        bg[j] = *reinterpret_cast<const bf16x8*>(&Bs[wn * 64 + j * 16 + lc][kc]);
#pragma unroll
      for (int i = 0; i < 4; ++i)
#pragma unroll
        for (int j = 0; j < 4; ++j)
          acc[i][j] = __builtin_amdgcn_mfma_f32_16x16x32_bf16(af[i], bg[j], acc[i][j], 0, 0, 0);
    }
    __syncthreads();
  }

  float ps[4][4] = {};
  float pq[4][4] = {};
#pragma unroll
  for (int j = 0; j < 4; ++j)
#pragma unroll
    for (int i = 0; i < 4; ++i)
#pragma unroll
      for (int r = 0; r < 4; ++r) {
        const float v = acc[i][j][r];
        ps[i][r] += v;
        pq[i][r] += v * v;
      }
#pragma unroll
  for (int off = 1; off < 16; off <<= 1)
#pragma unroll
    for (int i = 0; i < 4; ++i)
#pragma unroll
      for (int r = 0; r < 4; ++r) {
        ps[i][r] += __shfl_xor(ps[i][r], off);
        pq[i][r] += __shfl_xor(pq[i][r], off);
      }
  if (lc == 0) {
#pragma unroll
    for (int i = 0; i < 4; ++i) {
      const int chl = wm * 64 + i * 16 + hi * 4;
#pragma unroll
      for (int r = 0; r < 4; ++r) {
        atomicAdd(&s_sum[chl + r], ps[i][r]);
        atomicAdd(&s_sq[chl + r], pq[i][r]);
      }
    }
  }
  __syncthreads();
  const int p = b * 64 + blockIdx.y;
  if (tid < 128) {
    psumP[(size_t)p * C_ + m0 + tid] = s_sum[tid];
    psqP[(size_t)p * C_ + m0 + tid] = s_sq[tid];
  }
}

// ---------------------------------------------------------------------------
__global__ __launch_bounds__(256) void bn_finalize2(
    const float* __restrict__ psumP, const float* __restrict__ psqP,
    const float* __restrict__ gamma, const float* __restrict__ beta,
    float* __restrict__ gc, float* __restrict__ oc) {
  const int c = blockIdx.x;
  const int tid = threadIdx.x;
  float s = 0.0f, q = 0.0f;
  for (int p = tid; p < B_ * 64; p += 256) {
    s += psumP[(size_t)p * C_ + c];
    q += psqP[(size_t)p * C_ + c];
  }
  __shared__ float ls[256], lq[256];
  ls[tid] = s;
  lq[tid] = q;
  __syncthreads();
  for (int off = 128; off > 0; off >>= 1) {
    if (tid < off) { ls[tid] += ls[tid + off]; lq[tid] += lq[tid + off]; }
    __syncthreads();
  }
  if (tid == 0) {
    const float inv = 1.0f / ((float)B_ * N_);
    const float mean = ls[0] * inv;
    const float var = lq[0] * inv - mean * mean;
    const float rstd = rsqrtf(var + 1e-5f);
    const float g = gamma[c] * rstd;
    gc[c] = g;
    oc[c] = beta[c] - mean * g;
  }
}

// ---------------------------------------------------------------------------
// conv2 pass 2: x3 + BN + residual -> OUT fp32 (EPF repack, coalesced).
// ---------------------------------------------------------------------------
__global__ __launch_bounds__(256) void conv2_bn(
    const bf16* __restrict__ W2H, const bf16* __restrict__ X2,
    const float* __restrict__ gc, const float* __restrict__ oc,
    const float* __restrict__ Xin, float* __restrict__ OUT) {
  const int b = blockIdx.z;
  const int m0 = blockIdx.x * 128, n0 = blockIdx.y * 128;
  const bf16* __restrict__ Bb = X2 + (size_t)b * N_ * C_;

  __shared__ bf16 SM[2 * 128 * 64];
  bf16* As = SM;
  bf16* Bs = SM + 8192;

  const int tid = threadIdx.x, wid = tid >> 6, lane = tid & 63;
  const int lc = lane & 15, hi = lane >> 4;
  const int wm = wid >> 1, wn = wid & 1;
  const int swz = lc & 7;

  f32x4 acc[4][4] = {};
  for (int k0 = 0; k0 < C_; k0 += 64) {
#pragma unroll
    for (int it = 0; it < 4; ++it) {
      const int chunk = it * 256 + tid;
      const int row = chunk >> 3;
      const int koff = (((chunk & 7) ^ (row & 7)) << 3);
      const size_t doff = (size_t)(it * 256 + wid * 64) * 8;
      GLDS16(W2H + (size_t)(m0 + row) * C_ + k0 + koff, As + doff);
      GLDS16(Bb + (size_t)(n0 + row) * C_ + k0 + koff, Bs + doff);
    }
    __syncthreads();
#pragma unroll
    for (int ks = 0; ks < 2; ++ks) {
      const int kc = (((ks << 2) + hi) ^ swz) << 3;
      bf16x8 af[4], bg[4];
#pragma unroll
      for (int i = 0; i < 4; ++i)
        af[i] = *reinterpret_cast<const bf16x8*>(As + (wm * 64 + i * 16 + lc) * 64 + kc);
#pragma unroll
      for (int j = 0; j < 4; ++j)
        bg[j] = *reinterpret_cast<const bf16x8*>(Bs + (wn * 64 + j * 16 + lc) * 64 + kc);
#pragma unroll
      for (int i = 0; i < 4; ++i)
#pragma unroll
        for (int j = 0; j < 4; ++j)
          acc[i][j] = __builtin_amdgcn_mfma_f32_16x16x32_bf16(af[i], bg[j], acc[i][j], 0, 0, 0);
    }
    __syncthreads();
  }

  float (*EPF)[132] = reinterpret_cast<float(*)[132]>(SM);
  const int rr = tid >> 3, c4 = (tid & 7) << 2;
#pragma unroll
  for (int i = 0; i < 4; ++i) {
    if (i) __syncthreads();
    const int row0 = m0 + wm * 64 + i * 16 + hi * 4;
    const float4 g4 = *reinterpret_cast<const float4*>(&gc[row0]);
    const float4 o4 = *reinterpret_cast<const float4*>(&oc[row0]);
    const float ga[4] = {g4.x, g4.y, g4.z, g4.w};
    const float oa[4] = {o4.x, o4.y, o4.z, o4.w};
#pragma unroll
    for (int j = 0; j < 4; ++j) {
      const int coll = wn * 64 + j * 16 + lc;
#pragma unroll
      for (int r = 0; r < 4; ++r)
        EPF[wm * 16 + hi * 4 + r][coll] = acc[i][j][r] * ga[r] + oa[r];
    }
    __syncthreads();
    const int m = m0 + (rr >> 4) * 64 + i * 16 + (rr & 15);
#pragma unroll
    for (int rep = 0; rep < 4; ++rep) {
      const int col = rep * 32 + c4;
      const size_t off = ((size_t)b * C_ + m) * N_ + n0 + col;
      const float4 xi = *reinterpret_cast<const float4*>(&Xin[off]);
      float4 ov;
      ov.x = EPF[rr][col + 0] + xi.x;
      ov.y = EPF[rr][col + 1] + xi.y;
      ov.z = EPF[rr][col + 2] + xi.z;
      ov.w = EPF[rr][col + 3] + xi.w;
      *reinterpret_cast<float4*>(&OUT[off]) = ov;
    }
  }
}

// ---------------------------------------------------------------------------
extern "C" void kernel_launch(void* const* d_in, const int* in_sizes, int n_in,
                              void* d_out, int out_size, void* d_ws,
                              size_t ws_size, hipStream_t stream) {
  (void)in_sizes; (void)n_in; (void)out_size; (void)ws_size;
  const float* x     = (const float*)d_in[0];
  const float* w1    = (const float*)d_in[1];
  const float* b1    = (const float*)d_in[2];
  const float* mu0   = (const float*)d_in[3];
  const float* w2    = (const float*)d_in[4];
  const float* gamma = (const float*)d_in[5];
  const float* beta  = (const float*)d_in[6];

  // d_out: xs hi/lo planes live here until conv2_bn overwrites with fp32 out.
  bf16* XSH = (bf16*)d_out;
  bf16* XSL = XSH + (size_t)B_ * N_ * C_;
  float* OUT = (float*)d_out;
  float* MUOUT = OUT + (size_t)B_ * C_ * N_;

  // d_ws layout (XT gone; x2 owns the front region)
  bf16* X2b = (bf16*)d_ws;                          // B*N*C
  bf16* ZH  = X2b + (size_t)B_ * N_ * C_;           // B*N*K
  bf16* ZL  = ZH + (size_t)B_ * N_ * K_;
  bf16* W1H = ZL + (size_t)B_ * N_ * K_;
  bf16* W1L = W1H + C_ * C_;
  bf16* W2H = W1L + C_ * C_;
  bf16* W2L = W2H + C_ * C_;
  bf16* MT0H = W2L + C_ * C_;                       // K*C
  bf16* MT0L = MT0H + K_ * C_;
  bf16* MUTH = MT0L + K_ * C_;                      // B*K*C
  bf16* MUTL = MUTH + (size_t)B_ * K_ * C_;
  bf16* MUH  = MUTL + (size_t)B_ * K_ * C_;         // B*C*K
  float* MUACC = (float*)(MUH + (size_t)B_ * C_ * K_);
  float* colsum = MUACC + (size_t)B_ * C_ * K_;     // B*K
  float* gcp = colsum + B_ * K_;                    // C
  float* ocp = gcp + C_;                            // C
  float* psumP = ocp + C_;                          // 1024*C
  float* psqP  = psumP + (size_t)B_ * 64 * C_;      // 1024*C

  const dim3 blk(256);

  cast_w_split<<<dim3(C_ * C_ / 256), blk, 0, stream>>>(w1, W1H, W1L);
  cast_w_split<<<dim3(C_ * C_ / 256), blk, 0, stream>>>(w2, W2H, W2L);
  cast_mu0T_split<<<dim3(K_), blk, 0, stream>>>(mu0, MT0H, MT0L);
  hipMemsetAsync(MUACC, 0, (size_t)B_ * C_ * K_ * sizeof(float), stream);

  // conv1 with fused transpose (reads x fp32 directly), all 16 batches
  conv1_fused<<<dim3(N_ / 128, C_ / 128, B_), blk, 0, stream>>>(
      x, W1H, W1L, b1, XSH, XSL);

  // EM: grouped by batches so xs hi/lo (134 MB/group) stays L3-resident
  for (int g = 0; g < B_ / BGRP; ++g) {
    const int boff = g * BGRP;
    for (int it = 0; it < 3; ++it) {
      hipMemsetAsync(colsum + boff * K_, 0, BGRP * K_ * sizeof(float), stream);
      estep_split<<<dim3(N_ / 128, BGRP), blk, 0, stream>>>(
          XSH, XSL, it == 0 ? MT0H : MUTH, it == 0 ? MT0L : MUTL,
          it == 0 ? 0 : (size_t)K_ * C_, ZH, ZL, colsum, boff);
      mstep_split<<<dim3(N_ / MCHUNK, C_ / 128, BGRP), dim3(128), 0, stream>>>(
          XSH, XSL, ZH, ZL, MUACC, boff);
      finalize_mu<<<dim3(BGRP * C_ * K_ / 256), blk, 0, stream>>>(
          MUACC, colsum, MUTH, MUTL, MUH, it == 2 ? MUOUT : nullptr,
          boff * C_ * K_);
    }
  }

  x2_plain<<<dim3(N_ / 128, C_ / 128, B_), blk, 0, stream>>>(ZH, MUH, X2b);
  conv2_stats<<<dim3(C_ / 128, N_ / 128, B_), blk, 0, stream>>>(
      W2H, X2b, psumP, psqP);
  bn_finalize2<<<dim3(C_), blk, 0, stream>>>(psumP, psqP, gamma, beta, gcp, ocp);
  conv2_bn<<<dim3(C_ / 128, N_ / 128, B_), blk, 0, stream>>>(
      W2H, X2b, gcp, ocp, x, OUT);
}

// Round 11
// 1127.345 us; speedup vs baseline: 1.0651x; 1.0229x over previous
//
#include <hip/hip_runtime.h>
#include <math.h>

constexpr int B_ = 16, C_ = 512, K_ = 64, N_ = 8192;
constexpr int BGRP = 8;       // EM batch group size (L3 residency)
constexpr int MCHUNK = 512;   // mstep n-chunk

typedef __bf16 bf16;
typedef __bf16 bf16x4 __attribute__((ext_vector_type(4)));
typedef __bf16 bf16x8 __attribute__((ext_vector_type(8)));
typedef float f32x4 __attribute__((ext_vector_type(4)));

#define GLDS16(gp, lp)                                              \
  __builtin_amdgcn_global_load_lds(                                 \
      (const __attribute__((address_space(1))) unsigned int*)(gp),  \
      (__attribute__((address_space(3))) unsigned int*)(lp), 16, 0, 0)

__device__ __forceinline__ bf16 lo_part(float v, bf16 h) {
  return (bf16)(v - (float)h);
}

__global__ void cast_w_split(const float* __restrict__ W, bf16* __restrict__ H,
                             bf16* __restrict__ L) {
  const int i = blockIdx.x * 256 + threadIdx.x;
  const float v = W[i];
  const bf16 h = (bf16)v;
  H[i] = h;
  L[i] = lo_part(v, h);
}

__global__ void cast_mu0T_split(const float* __restrict__ MU0,
                                bf16* __restrict__ H, bf16* __restrict__ L) {
  const int k = blockIdx.x;
  for (int c = threadIdx.x; c < C_; c += 256) {
    const float v = MU0[c * K_ + k];
    const bf16 h = (bf16)v;
    H[k * C_ + c] = h;
    L[k * C_ + c] = lo_part(v, h);
  }
}

// ---------------------------------------------------------------------------
// conv1 FUSED transpose v2: xs_NC = x^T . w1^T + b1, split-bf16 3-pass MFMA.
// A: cooperative transposed-gather from global (coalesced across lanes),
// hi/lo conversion ONCE per element, written bf16x8 into [128][40] tiles
// (mstep-proven conflict-free layout). B via GLDS16 + granule swizzle.
// ---------------------------------------------------------------------------
__global__ __launch_bounds__(256) void conv1_fused(
    const float* __restrict__ X, const bf16* __restrict__ W1H,
    const bf16* __restrict__ W1L, const float* __restrict__ bias,
    bf16* __restrict__ XSH, bf16* __restrict__ XSL) {
  const int bz = blockIdx.z;
  const int m0 = blockIdx.x * 128;  // n rows
  const int n0 = blockIdx.y * 128;  // o cols
  const float* __restrict__ Xb = X + (size_t)bz * C_ * N_;

  __shared__ bf16 Ah[128][40], Al[128][40];  // 10.25 KB each (ld=40: 2-way)
  __shared__ bf16 Bbuf[2 * 128 * 64];        // 32 KB: Bh | Bl ; reused as EP
  bf16* Bh = Bbuf;
  bf16* Bl = Bbuf + 8192;

  const int tid = threadIdx.x, wid = tid >> 6, lane = tid & 63;
  const int lc = lane & 15, hi = lane >> 4;
  const int wm = wid >> 1, wn = wid & 1;
  const int swz = lc & 7;
  const int cvn = tid & 127;   // conversion: n row
  const int cvg = tid >> 7;    // conversion: c-granule base (0..1; +2 via g)

  f32x4 acc[4][4] = {};

  for (int k0 = 0; k0 < C_; k0 += 64) {
    // stage B (w1 hi/lo) for this 64-c chunk (in flight during A conversion)
#pragma unroll
    for (int it = 0; it < 4; ++it) {
      const int chunk = it * 256 + tid;
      const int row = chunk >> 3;
      const int koff = (((chunk & 7) ^ (row & 7)) << 3);
      const size_t doff = (size_t)(it * 256 + wid * 64) * 8;
      GLDS16(W1H + (size_t)(n0 + row) * C_ + k0 + koff, Bh + doff);
      GLDS16(W1L + (size_t)(n0 + row) * C_ + k0 + koff, Bl + doff);
    }
#pragma unroll
    for (int sub = 0; sub < 2; ++sub) {
      // cooperative A convert-stage: 32 c-rows x 128 n, each elem once.
      // lanes read consecutive n at fixed c -> coalesced global loads.
#pragma unroll
      for (int g = 0; g < 2; ++g) {
        const int cg = cvg + g * 2;  // 0..3
        const int cbase = k0 + sub * 32 + cg * 8;
        bf16x8 vh, vl;
#pragma unroll
        for (int e = 0; e < 8; ++e) {
          const float v = Xb[(size_t)(cbase + e) * N_ + m0 + cvn];
          const bf16 h = (bf16)v;
          vh[e] = h;
          vl[e] = lo_part(v, h);
        }
        *reinterpret_cast<bf16x8*>(&Ah[cvn][cg * 8]) = vh;
        *reinterpret_cast<bf16x8*>(&Al[cvn][cg * 8]) = vl;
      }
      __syncthreads();  // A staged (+ B drained on sub==0)
      {
        bf16x8 ah[4], al4[4], bh[4], bl4[4];
        const int kc = (((sub << 2) + hi) ^ swz) << 3;
#pragma unroll
        for (int i = 0; i < 4; ++i) {
          const int arow = wm * 64 + i * 16 + lc;
          ah[i] = *reinterpret_cast<const bf16x8*>(&Ah[arow][hi * 8]);
          al4[i] = *reinterpret_cast<const bf16x8*>(&Al[arow][hi * 8]);
        }
#pragma unroll
        for (int j = 0; j < 4; ++j) {
          bh[j] = *reinterpret_cast<const bf16x8*>(Bh + (wn * 64 + j * 16 + lc) * 64 + kc);
          bl4[j] = *reinterpret_cast<const bf16x8*>(Bl + (wn * 64 + j * 16 + lc) * 64 + kc);
        }
#pragma unroll
        for (int i = 0; i < 4; ++i)
#pragma unroll
          for (int j = 0; j < 4; ++j) {
            acc[i][j] = __builtin_amdgcn_mfma_f32_16x16x32_bf16(al4[i], bh[j], acc[i][j], 0, 0, 0);
            acc[i][j] = __builtin_amdgcn_mfma_f32_16x16x32_bf16(ah[i], bl4[j], acc[i][j], 0, 0, 0);
            acc[i][j] = __builtin_amdgcn_mfma_f32_16x16x32_bf16(ah[i], bh[j], acc[i][j], 0, 0, 0);
          }
      }
      __syncthreads();  // frag reads done before next staging overwrites
    }
  }

  // epilogue: EP repack (B region dead), coalesced bf16x8 stores
  bf16 (*EP)[128] = reinterpret_cast<bf16(*)[128]>(Bbuf);
  const int rr = tid >> 4, c8 = (tid & 15) << 3;
#pragma unroll
  for (int plane = 0; plane < 2; ++plane) {
    if (plane) __syncthreads();
#pragma unroll
    for (int j = 0; j < 4; ++j) {
      const int coll = wn * 64 + j * 16 + lc;
      const float bv = bias[n0 + coll];
#pragma unroll
      for (int i = 0; i < 4; ++i) {
        const int rowl = wm * 64 + i * 16 + hi * 4;
#pragma unroll
        for (int r = 0; r < 4; ++r) {
          const float v = acc[i][j][r] + bv;
          const bf16 h = (bf16)v;
          EP[rowl + r][coll] = plane ? lo_part(v, h) : h;
        }
      }
    }
    __syncthreads();
    bf16* DST = plane ? XSL : XSH;
#pragma unroll
    for (int rep = 0; rep < 8; ++rep) {
      const int row = rep * 16 + rr;
      *reinterpret_cast<bf16x8*>(&DST[((size_t)bz * N_ + m0 + row) * C_ + n0 + c8]) =
          *reinterpret_cast<const bf16x8*>(&EP[row][c8]);
    }
  }
}

// ---------------------------------------------------------------------------
// E-step: logits = xs . mu^T (split 3-pass), fp32 softmax over K=64.
// ---------------------------------------------------------------------------
__global__ __launch_bounds__(256) void estep_split(
    const bf16* __restrict__ XSH, const bf16* __restrict__ XSL,
    const bf16* __restrict__ MTH, const bf16* __restrict__ MTL,
    size_t mustride, bf16* __restrict__ ZH, bf16* __restrict__ ZL,
    float* __restrict__ colsum, int b_base) {
  const int b = b_base + blockIdx.y;
  const int m0 = blockIdx.x * 128;
  const bf16* __restrict__ AHp = XSH + (size_t)b * N_ * C_;
  const bf16* __restrict__ ALp = XSL + (size_t)b * N_ * C_;
  const bf16* __restrict__ BHp = MTH + (size_t)b * mustride;
  const bf16* __restrict__ BLp = MTL + (size_t)b * mustride;

  __shared__ bf16 Ah[128][64], Al[128][64], Bh[64][64], Bl[64][64];
  __shared__ float cs[64];

  const int tid = threadIdx.x, wid = tid >> 6, lane = tid & 63;
  const int lc = lane & 15, hi = lane >> 4;
  const int swz = lc & 7;
  if (tid < 64) cs[tid] = 0.0f;

  f32x4 acc[2][4] = {};
  for (int k0 = 0; k0 < C_; k0 += 64) {
#pragma unroll
    for (int it = 0; it < 4; ++it) {
      const int chunk = it * 256 + tid;
      const int row = chunk >> 3;
      const int koff = (((chunk & 7) ^ (row & 7)) << 3);
      const size_t doff = (size_t)(it * 256 + wid * 64) * 8;
      GLDS16(AHp + (size_t)(m0 + row) * C_ + k0 + koff, &Ah[0][0] + doff);
      GLDS16(ALp + (size_t)(m0 + row) * C_ + k0 + koff, &Al[0][0] + doff);
    }
#pragma unroll
    for (int it = 0; it < 2; ++it) {
      const int chunk = it * 256 + tid;
      const int row = chunk >> 3;
      const int koff = (((chunk & 7) ^ (row & 7)) << 3);
      const size_t doff = (size_t)(it * 256 + wid * 64) * 8;
      GLDS16(BHp + (size_t)row * C_ + k0 + koff, &Bh[0][0] + doff);
      GLDS16(BLp + (size_t)row * C_ + k0 + koff, &Bl[0][0] + doff);
    }
    __syncthreads();
#pragma unroll
    for (int ks = 0; ks < 2; ++ks) {
      const int kc = (((ks << 2) + hi) ^ swz) << 3;
      bf16x8 ah[2], al4[2], bh[4], bl4[4];
#pragma unroll
      for (int i = 0; i < 2; ++i) {
        ah[i] = *reinterpret_cast<const bf16x8*>(&Ah[wid * 32 + i * 16 + lc][kc]);
        al4[i] = *reinterpret_cast<const bf16x8*>(&Al[wid * 32 + i * 16 + lc][kc]);
      }
#pragma unroll
      for (int j = 0; j < 4; ++j) {
        bh[j] = *reinterpret_cast<const bf16x8*>(&Bh[j * 16 + lc][kc]);
        bl4[j] = *reinterpret_cast<const bf16x8*>(&Bl[j * 16 + lc][kc]);
      }
#pragma unroll
      for (int i = 0; i < 2; ++i)
#pragma unroll
        for (int j = 0; j < 4; ++j) {
          acc[i][j] = __builtin_amdgcn_mfma_f32_16x16x32_bf16(al4[i], bh[j], acc[i][j], 0, 0, 0);
          acc[i][j] = __builtin_amdgcn_mfma_f32_16x16x32_bf16(ah[i], bl4[j], acc[i][j], 0, 0, 0);
          acc[i][j] = __builtin_amdgcn_mfma_f32_16x16x32_bf16(ah[i], bh[j], acc[i][j], 0, 0, 0);
        }
    }
    __syncthreads();
  }

  float cp[4] = {0.f, 0.f, 0.f, 0.f};
#pragma unroll
  for (int i = 0; i < 2; ++i) {
#pragma unroll
    for (int r = 0; r < 4; ++r) {
      float v0 = acc[i][0][r], v1 = acc[i][1][r], v2 = acc[i][2][r], v3 = acc[i][3][r];
      float mx = fmaxf(fmaxf(v0, v1), fmaxf(v2, v3));
#pragma unroll
      for (int off = 1; off < 16; off <<= 1) mx = fmaxf(mx, __shfl_xor(mx, off));
      float p0 = __expf(v0 - mx), p1 = __expf(v1 - mx);
      float p2 = __expf(v2 - mx), p3 = __expf(v3 - mx);
      float s = p0 + p1 + p2 + p3;
#pragma unroll
      for (int off = 1; off < 16; off <<= 1) s += __shfl_xor(s, off);
      const float inv = 1.0f / s;
      p0 *= inv; p1 *= inv; p2 *= inv; p3 *= inv;
      const int n = m0 + wid * 32 + i * 16 + hi * 4 + r;
      bf16* zh = ZH + ((size_t)b * N_ + n) * K_;
      bf16* zl = ZL + ((size_t)b * N_ + n) * K_;
      const float pv[4] = {p0, p1, p2, p3};
#pragma unroll
      for (int j = 0; j < 4; ++j) {
        const bf16 h = (bf16)pv[j];
        zh[j * 16 + lc] = h;
        zl[j * 16 + lc] = lo_part(pv[j], h);
        cp[j] += pv[j];
      }
    }
  }
#pragma unroll
  for (int j = 0; j < 4; ++j) atomicAdd(&cs[j * 16 + lc], cp[j]);
  __syncthreads();
  if (tid < 64) atomicAdd(&colsum[b * K_ + tid], cs[tid]);
}

// ---------------------------------------------------------------------------
// M-step: muacc (C x K) += sum_n xs[n][c]*z[n][k], split 3-pass.
// ---------------------------------------------------------------------------
__global__ __launch_bounds__(128) void mstep_split(
    const bf16* __restrict__ XSH, const bf16* __restrict__ XSL,
    const bf16* __restrict__ ZHp, const bf16* __restrict__ ZLp,
    float* __restrict__ MUACC, int b_base) {
  const int b = b_base + blockIdx.z;
  const int c0 = blockIdx.y * 128;
  const int nbase = blockIdx.x * MCHUNK;
  const bf16* __restrict__ XbH = XSH + (size_t)b * N_ * C_;
  const bf16* __restrict__ XbL = XSL + (size_t)b * N_ * C_;
  const bf16* __restrict__ ZbH = ZHp + (size_t)b * N_ * K_;
  const bf16* __restrict__ ZbL = ZLp + (size_t)b * N_ * K_;

  __shared__ bf16 Ah[128][40], Al[128][40], Bh[64][40], Bl[64][40];

  const int tid = threadIdx.x, wid = tid >> 6, lane = tid & 63;
  const int lc = lane & 15, hi = lane >> 4;

  f32x4 acc[4][4] = {};
  for (int n0 = nbase; n0 < nbase + MCHUNK; n0 += 32) {
#pragma unroll
    for (int it = 0; it < 4; ++it) {
      const int chunk = it * 128 + tid;
      const int nn = chunk & 31, c8 = (chunk >> 5) * 8;
      const bf16x8 vh = *reinterpret_cast<const bf16x8*>(
          &XbH[(size_t)(n0 + nn) * C_ + c0 + c8]);
      const bf16x8 vl = *reinterpret_cast<const bf16x8*>(
          &XbL[(size_t)(n0 + nn) * C_ + c0 + c8]);
#pragma unroll
      for (int e = 0; e < 8; ++e) {
        Ah[c8 + e][nn] = vh[e];
        Al[c8 + e][nn] = vl[e];
      }
    }
#pragma unroll
    for (int it = 0; it < 2; ++it) {
      const int chunk = it * 128 + tid;
      const int nn = chunk & 31, k8 = (chunk >> 5) * 8;
      const bf16x8 vh = *reinterpret_cast<const bf16x8*>(
          &ZbH[(size_t)(n0 + nn) * K_ + k8]);
      const bf16x8 vl = *reinterpret_cast<const bf16x8*>(
          &ZbL[(size_t)(n0 + nn) * K_ + k8]);
#pragma unroll
      for (int e = 0; e < 8; ++e) {
        Bh[k8 + e][nn] = vh[e];
        Bl[k8 + e][nn] = vl[e];
      }
    }
    __syncthreads();
    bf16x8 ah[4], al4[4], bh[4], bl4[4];
#pragma unroll
    for (int i = 0; i < 4; ++i) {
      ah[i] = *reinterpret_cast<const bf16x8*>(&Ah[wid * 64 + i * 16 + lc][hi * 8]);
      al4[i] = *reinterpret_cast<const bf16x8*>(&Al[wid * 64 + i * 16 + lc][hi * 8]);
    }
#pragma unroll
    for (int j = 0; j < 4; ++j) {
      bh[j] = *reinterpret_cast<const bf16x8*>(&Bh[j * 16 + lc][hi * 8]);
      bl4[j] = *reinterpret_cast<const bf16x8*>(&Bl[j * 16 + lc][hi * 8]);
    }
#pragma unroll
    for (int i = 0; i < 4; ++i)
#pragma unroll
      for (int j = 0; j < 4; ++j) {
        acc[i][j] = __builtin_amdgcn_mfma_f32_16x16x32_bf16(al4[i], bh[j], acc[i][j], 0, 0, 0);
        acc[i][j] = __builtin_amdgcn_mfma_f32_16x16x32_bf16(ah[i], bl4[j], acc[i][j], 0, 0, 0);
        acc[i][j] = __builtin_amdgcn_mfma_f32_16x16x32_bf16(ah[i], bh[j], acc[i][j], 0, 0, 0);
      }
    __syncthreads();
  }
#pragma unroll
  for (int i = 0; i < 4; ++i) {
    const int c = c0 + wid * 64 + i * 16 + hi * 4;
#pragma unroll
    for (int r = 0; r < 4; ++r)
#pragma unroll
      for (int j = 0; j < 4; ++j)
        atomicAdd(&MUACC[((size_t)b * C_ + c + r) * K_ + j * 16 + lc], acc[i][j][r]);
  }
}

// ---------------------------------------------------------------------------
// finalize mu; also re-zeroes its MUACC slice for the next iteration.
// ---------------------------------------------------------------------------
__global__ void finalize_mu(float* __restrict__ MUACC,
                            const float* __restrict__ colsum,
                            bf16* __restrict__ MUTH, bf16* __restrict__ MUTL,
                            bf16* __restrict__ MUH, float* __restrict__ muout,
                            int idx_base) {
  const int idx = idx_base + blockIdx.x * 256 + threadIdx.x;
  const int k = idx & (K_ - 1);
  const int c = (idx >> 6) & (C_ - 1);
  const int b = idx >> 15;
  const float v = MUACC[idx] / (1e-6f + colsum[b * K_ + k]);
  MUACC[idx] = 0.0f;
  const bf16 h = (bf16)v;
  MUH[idx] = h;
  MUTH[((size_t)b * K_ + k) * C_ + c] = h;
  MUTL[((size_t)b * K_ + k) * C_ + c] = lo_part(v, h);
  if (muout) muout[idx] = v;
}

// ---------------------------------------------------------------------------
// x2_NC = relu(z . mu^T), plain bf16, single K=64 tile. EP repack epilogue.
// ---------------------------------------------------------------------------
__global__ __launch_bounds__(256) void x2_plain(
    const bf16* __restrict__ ZHp, const bf16* __restrict__ MUHp,
    bf16* __restrict__ X2) {
  const int b = blockIdx.z;
  const int m0 = blockIdx.x * 128, n0 = blockIdx.y * 128;
  const bf16* __restrict__ Ab = ZHp + (size_t)b * N_ * K_;
  const bf16* __restrict__ Bb = MUHp + (size_t)b * C_ * K_;

  __shared__ bf16 SM[2 * 128 * 64];
  bf16* As = SM;
  bf16* Bs = SM + 8192;

  const int tid = threadIdx.x, wid = tid >> 6, lane = tid & 63;
  const int lc = lane & 15, hi = lane >> 4;
  const int wm = wid >> 1, wn = wid & 1;
  const int swz = lc & 7;

  f32x4 acc[4][4] = {};
#pragma unroll
  for (int it = 0; it < 4; ++it) {
    const int chunk = it * 256 + tid;
    const int row = chunk >> 3;
    const int koff = (((chunk & 7) ^ (row & 7)) << 3);
    const size_t doff = (size_t)(it * 256 + wid * 64) * 8;
    GLDS16(Ab + (size_t)(m0 + row) * K_ + koff, As + doff);
    GLDS16(Bb + (size_t)(n0 + row) * K_ + koff, Bs + doff);
  }
  __syncthreads();
#pragma unroll
  for (int ks = 0; ks < 2; ++ks) {
    const int kc = (((ks << 2) + hi) ^ swz) << 3;
    bf16x8 af[4], bg[4];
#pragma unroll
    for (int i = 0; i < 4; ++i)
      af[i] = *reinterpret_cast<const bf16x8*>(As + (wm * 64 + i * 16 + lc) * 64 + kc);
#pragma unroll
    for (int j = 0; j < 4; ++j)
      bg[j] = *reinterpret_cast<const bf16x8*>(Bs + (wn * 64 + j * 16 + lc) * 64 + kc);
#pragma unroll
    for (int i = 0; i < 4; ++i)
#pragma unroll
      for (int j = 0; j < 4; ++j)
        acc[i][j] = __builtin_amdgcn_mfma_f32_16x16x32_bf16(af[i], bg[j], acc[i][j], 0, 0, 0);
  }
  __syncthreads();

  bf16 (*EP)[128] = reinterpret_cast<bf16(*)[128]>(SM);
#pragma unroll
  for (int j = 0; j < 4; ++j) {
    const int coll = wn * 64 + j * 16 + lc;
#pragma unroll
    for (int i = 0; i < 4; ++i) {
      const int rowl = wm * 64 + i * 16 + hi * 4;
#pragma unroll
      for (int r = 0; r < 4; ++r)
        EP[rowl + r][coll] = (bf16)fmaxf(acc[i][j][r], 0.0f);
    }
  }
  __syncthreads();
  const int rr = tid >> 4, c8 = (tid & 15) << 3;
#pragma unroll
  for (int rep = 0; rep < 8; ++rep) {
    const int row = rep * 16 + rr;
    *reinterpret_cast<bf16x8*>(&X2[((size_t)b * N_ + m0 + row) * C_ + n0 + c8]) =
        *reinterpret_cast<const bf16x8*>(&EP[row][c8]);
  }
}

// ---------------------------------------------------------------------------
// conv2 pass 1: x3 tiles -> per-channel sum/sumsq non-atomic partials.
// ---------------------------------------------------------------------------
__global__ __launch_bounds__(256) void conv2_stats(
    const bf16* __restrict__ W2H, const bf16* __restrict__ X2,
    float* __restrict__ psumP, float* __restrict__ psqP) {
  const int b = blockIdx.z;
  const int m0 = blockIdx.x * 128, n0 = blockIdx.y * 128;
  const bf16* __restrict__ Bb = X2 + (size_t)b * N_ * C_;

  __shared__ bf16 As[128][64], Bs[128][64];
  __shared__ float s_sum[128], s_sq[128];

  const int tid = threadIdx.x, wid = tid >> 6, lane = tid & 63;
  const int lc = lane & 15, hi = lane >> 4;
  const int wm = wid >> 1, wn = wid & 1;
  const int swz = lc & 7;
  if (tid < 128) { s_sum[tid] = 0.0f; s_sq[tid] = 0.0f; }

  f32x4 acc[4][4] = {};
  for (int k0 = 0; k0 < C_; k0 += 64) {
#pragma unroll
    for (int it = 0; it < 4; ++it) {
      const int chunk = it * 256 + tid;
      const int row = chunk >> 3;
      const int koff = (((chunk & 7) ^ (row & 7)) << 3);
      const size_t doff = (size_t)(it * 256 + wid * 64) * 8;
      GLDS16(W2H + (size_t)(m0 + row) * C_ + k0 + koff, &As[0][0] + doff);
      GLDS16(Bb + (size_t)(n0 + row) * C_ + k0 + koff, &Bs[0][0] + doff);
    }
    __syncthreads();
#pragma unroll
    for (int ks = 0; ks < 2; ++ks) {
      const int kc = (((ks << 2) + hi) ^ swz) << 3;
      bf16x8 af[4], bg[4];
#pragma unroll
      for (int i = 0; i < 4; ++i)
        af[i] = *reinterpret_cast<const bf16x8*>(&As[wm * 64 + i * 16 + lc][kc]);
#pragma unroll
      for (int j = 0; j < 4; ++j)
        bg[j] = *reinterpret_cast<const bf16x8*>(&Bs[wn * 64 + j * 16 + lc][kc]);
#pragma unroll
      for (int i = 0; i < 4; ++i)
#pragma unroll
        for (int j = 0; j < 4; ++j)
          acc[i][j] = __builtin_amdgcn_mfma_f32_16x16x32_bf16(af[i], bg[j], acc[i][j], 0, 0, 0);
    }
    __syncthreads();
  }

  float ps[4][4] = {};
  float pq[4][4] = {};
#pragma unroll
  for (int j = 0; j < 4; ++j)
#pragma unroll
    for (int i = 0; i < 4; ++i)
#pragma unroll
      for (int r = 0; r < 4; ++r) {
        const float v = acc[i][j][r];
        ps[i][r] += v;
        pq[i][r] += v * v;
      }
#pragma unroll
  for (int off = 1; off < 16; off <<= 1)
#pragma unroll
    for (int i = 0; i < 4; ++i)
#pragma unroll
      for (int r = 0; r < 4; ++r) {
        ps[i][r] += __shfl_xor(ps[i][r], off);
        pq[i][r] += __shfl_xor(pq[i][r], off);
      }
  if (lc == 0) {
#pragma unroll
    for (int i = 0; i < 4; ++i) {
      const int chl = wm * 64 + i * 16 + hi * 4;
#pragma unroll
      for (int r = 0; r < 4; ++r) {
        atomicAdd(&s_sum[chl + r], ps[i][r]);
        atomicAdd(&s_sq[chl + r], pq[i][r]);
      }
    }
  }
  __syncthreads();
  const int p = b * 64 + blockIdx.y;
  if (tid < 128) {
    psumP[(size_t)p * C_ + m0 + tid] = s_sum[tid];
    psqP[(size_t)p * C_ + m0 + tid] = s_sq[tid];
  }
}

// ---------------------------------------------------------------------------
__global__ __launch_bounds__(256) void bn_finalize2(
    const float* __restrict__ psumP, const float* __restrict__ psqP,
    const float* __restrict__ gamma, const float* __restrict__ beta,
    float* __restrict__ gc, float* __restrict__ oc) {
  const int c = blockIdx.x;
  const int tid = threadIdx.x;
  float s = 0.0f, q = 0.0f;
  for (int p = tid; p < B_ * 64; p += 256) {
    s += psumP[(size_t)p * C_ + c];
    q += psqP[(size_t)p * C_ + c];
  }
  __shared__ float ls[256], lq[256];
  ls[tid] = s;
  lq[tid] = q;
  __syncthreads();
  for (int off = 128; off > 0; off >>= 1) {
    if (tid < off) { ls[tid] += ls[tid + off]; lq[tid] += lq[tid + off]; }
    __syncthreads();
  }
  if (tid == 0) {
    const float inv = 1.0f / ((float)B_ * N_);
    const float mean = ls[0] * inv;
    const float var = lq[0] * inv - mean * mean;
    const float rstd = rsqrtf(var + 1e-5f);
    const float g = gamma[c] * rstd;
    gc[c] = g;
    oc[c] = beta[c] - mean * g;
  }
}

// ---------------------------------------------------------------------------
// conv2 pass 2: x3 + BN + residual -> OUT fp32 (EPF repack, coalesced).
// ---------------------------------------------------------------------------
__global__ __launch_bounds__(256) void conv2_bn(
    const bf16* __restrict__ W2H, const bf16* __restrict__ X2,
    const float* __restrict__ gc, const float* __restrict__ oc,
    const float* __restrict__ Xin, float* __restrict__ OUT) {
  const int b = blockIdx.z;
  const int m0 = blockIdx.x * 128, n0 = blockIdx.y * 128;
  const bf16* __restrict__ Bb = X2 + (size_t)b * N_ * C_;

  __shared__ bf16 SM[2 * 128 * 64];
  bf16* As = SM;
  bf16* Bs = SM + 8192;

  const int tid = threadIdx.x, wid = tid >> 6, lane = tid & 63;
  const int lc = lane & 15, hi = lane >> 4;
  const int wm = wid >> 1, wn = wid & 1;
  const int swz = lc & 7;

  f32x4 acc[4][4] = {};
  for (int k0 = 0; k0 < C_; k0 += 64) {
#pragma unroll
    for (int it = 0; it < 4; ++it) {
      const int chunk = it * 256 + tid;
      const int row = chunk >> 3;
      const int koff = (((chunk & 7) ^ (row & 7)) << 3);
      const size_t doff = (size_t)(it * 256 + wid * 64) * 8;
      GLDS16(W2H + (size_t)(m0 + row) * C_ + k0 + koff, As + doff);
      GLDS16(Bb + (size_t)(n0 + row) * C_ + k0 + koff, Bs + doff);
    }
    __syncthreads();
#pragma unroll
    for (int ks = 0; ks < 2; ++ks) {
      const int kc = (((ks << 2) + hi) ^ swz) << 3;
      bf16x8 af[4], bg[4];
#pragma unroll
      for (int i = 0; i < 4; ++i)
        af[i] = *reinterpret_cast<const bf16x8*>(As + (wm * 64 + i * 16 + lc) * 64 + kc);
#pragma unroll
      for (int j = 0; j < 4; ++j)
        bg[j] = *reinterpret_cast<const bf16x8*>(Bs + (wn * 64 + j * 16 + lc) * 64 + kc);
#pragma unroll
      for (int i = 0; i < 4; ++i)
#pragma unroll
        for (int j = 0; j < 4; ++j)
          acc[i][j] = __builtin_amdgcn_mfma_f32_16x16x32_bf16(af[i], bg[j], acc[i][j], 0, 0, 0);
    }
    __syncthreads();
  }

  float (*EPF)[132] = reinterpret_cast<float(*)[132]>(SM);
  const int rr = tid >> 3, c4 = (tid & 7) << 2;
#pragma unroll
  for (int i = 0; i < 4; ++i) {
    if (i) __syncthreads();
    const int row0 = m0 + wm * 64 + i * 16 + hi * 4;
    const float4 g4 = *reinterpret_cast<const float4*>(&gc[row0]);
    const float4 o4 = *reinterpret_cast<const float4*>(&oc[row0]);
    const float ga[4] = {g4.x, g4.y, g4.z, g4.w};
    const float oa[4] = {o4.x, o4.y, o4.z, o4.w};
#pragma unroll
    for (int j = 0; j < 4; ++j) {
      const int coll = wn * 64 + j * 16 + lc;
#pragma unroll
      for (int r = 0; r < 4; ++r)
        EPF[wm * 16 + hi * 4 + r][coll] = acc[i][j][r] * ga[r] + oa[r];
    }
    __syncthreads();
    const int m = m0 + (rr >> 4) * 64 + i * 16 + (rr & 15);
#pragma unroll
    for (int rep = 0; rep < 4; ++rep) {
      const int col = rep * 32 + c4;
      const size_t off = ((size_t)b * C_ + m) * N_ + n0 + col;
      const float4 xi = *reinterpret_cast<const float4*>(&Xin[off]);
      float4 ov;
      ov.x = EPF[rr][col + 0] + xi.x;
      ov.y = EPF[rr][col + 1] + xi.y;
      ov.z = EPF[rr][col + 2] + xi.z;
      ov.w = EPF[rr][col + 3] + xi.w;
      *reinterpret_cast<float4*>(&OUT[off]) = ov;
    }
  }
}

// ---------------------------------------------------------------------------
extern "C" void kernel_launch(void* const* d_in, const int* in_sizes, int n_in,
                              void* d_out, int out_size, void* d_ws,
                              size_t ws_size, hipStream_t stream) {
  (void)in_sizes; (void)n_in; (void)out_size; (void)ws_size;
  const float* x     = (const float*)d_in[0];
  const float* w1    = (const float*)d_in[1];
  const float* b1    = (const float*)d_in[2];
  const float* mu0   = (const float*)d_in[3];
  const float* w2    = (const float*)d_in[4];
  const float* gamma = (const float*)d_in[5];
  const float* beta  = (const float*)d_in[6];

  // d_out: xs hi/lo planes live here until conv2_bn overwrites with fp32 out.
  bf16* XSH = (bf16*)d_out;
  bf16* XSL = XSH + (size_t)B_ * N_ * C_;
  float* OUT = (float*)d_out;
  float* MUOUT = OUT + (size_t)B_ * C_ * N_;

  // d_ws layout
  bf16* X2b = (bf16*)d_ws;                          // B*N*C
  bf16* ZH  = X2b + (size_t)B_ * N_ * C_;           // B*N*K
  bf16* ZL  = ZH + (size_t)B_ * N_ * K_;
  bf16* W1H = ZL + (size_t)B_ * N_ * K_;
  bf16* W1L = W1H + C_ * C_;
  bf16* W2H = W1L + C_ * C_;
  bf16* W2L = W2H + C_ * C_;
  bf16* MT0H = W2L + C_ * C_;                       // K*C
  bf16* MT0L = MT0H + K_ * C_;
  bf16* MUTH = MT0L + K_ * C_;                      // B*K*C
  bf16* MUTL = MUTH + (size_t)B_ * K_ * C_;
  bf16* MUH  = MUTL + (size_t)B_ * K_ * C_;         // B*C*K
  float* MUACC = (float*)(MUH + (size_t)B_ * C_ * K_);
  float* colsum = MUACC + (size_t)B_ * C_ * K_;     // B*K
  float* gcp = colsum + B_ * K_;                    // C
  float* ocp = gcp + C_;                            // C
  float* psumP = ocp + C_;                          // 1024*C
  float* psqP  = psumP + (size_t)B_ * 64 * C_;      // 1024*C

  const dim3 blk(256);

  cast_w_split<<<dim3(C_ * C_ / 256), blk, 0, stream>>>(w1, W1H, W1L);
  cast_w_split<<<dim3(C_ * C_ / 256), blk, 0, stream>>>(w2, W2H, W2L);
  cast_mu0T_split<<<dim3(K_), blk, 0, stream>>>(mu0, MT0H, MT0L);
  hipMemsetAsync(MUACC, 0, (size_t)B_ * C_ * K_ * sizeof(float), stream);

  // conv1 with fused transpose (reads x fp32 directly), all 16 batches
  conv1_fused<<<dim3(N_ / 128, C_ / 128, B_), blk, 0, stream>>>(
      x, W1H, W1L, b1, XSH, XSL);

  // EM: grouped by batches so xs hi/lo (134 MB/group) stays L3-resident
  for (int g = 0; g < B_ / BGRP; ++g) {
    const int boff = g * BGRP;
    for (int it = 0; it < 3; ++it) {
      hipMemsetAsync(colsum + boff * K_, 0, BGRP * K_ * sizeof(float), stream);
      estep_split<<<dim3(N_ / 128, BGRP), blk, 0, stream>>>(
          XSH, XSL, it == 0 ? MT0H : MUTH, it == 0 ? MT0L : MUTL,
          it == 0 ? 0 : (size_t)K_ * C_, ZH, ZL, colsum, boff);
      mstep_split<<<dim3(N_ / MCHUNK, C_ / 128, BGRP), dim3(128), 0, stream>>>(
          XSH, XSL, ZH, ZL, MUACC, boff);
      finalize_mu<<<dim3(BGRP * C_ * K_ / 256), blk, 0, stream>>>(
          MUACC, colsum, MUTH, MUTL, MUH, it == 2 ? MUOUT : nullptr,
          boff * C_ * K_);
    }
  }

  x2_plain<<<dim3(N_ / 128, C_ / 128, B_), blk, 0, stream>>>(ZH, MUH, X2b);
  conv2_stats<<<dim3(C_ / 128, N_ / 128, B_), blk, 0, stream>>>(
      W2H, X2b, psumP, psqP);
  bn_finalize2<<<dim3(C_), blk, 0, stream>>>(psumP, psqP, gamma, beta, gcp, ocp);
  conv2_bn<<<dim3(C_ / 128, N_ / 128, B_), blk, 0, stream>>>(
      W2H, X2b, gcp, ocp, x, OUT);
}

// Round 13
// 1107.343 us; speedup vs baseline: 1.0843x; 1.0181x over previous
//
#include <hip/hip_runtime.h>
#include <math.h>

constexpr int B_ = 16, C_ = 512, K_ = 64, N_ = 8192;
constexpr int BGRP = 8;       // EM batch group size (L3 residency)
constexpr int MCHUNK = 512;   // mstep n-chunk

typedef __bf16 bf16;
typedef __bf16 bf16x4 __attribute__((ext_vector_type(4)));
typedef __bf16 bf16x8 __attribute__((ext_vector_type(8)));
typedef float f32x4 __attribute__((ext_vector_type(4)));

#define GLDS16(gp, lp)                                              \
  __builtin_amdgcn_global_load_lds(                                 \
      (const __attribute__((address_space(1))) unsigned int*)(gp),  \
      (__attribute__((address_space(3))) unsigned int*)(lp), 16, 0, 0)

__device__ __forceinline__ bf16 lo_part(float v, bf16 h) {
  return (bf16)(v - (float)h);
}

__global__ void cast_w_split(const float* __restrict__ W, bf16* __restrict__ H,
                             bf16* __restrict__ L) {
  const int i = blockIdx.x * 256 + threadIdx.x;
  const float v = W[i];
  const bf16 h = (bf16)v;
  H[i] = h;
  L[i] = lo_part(v, h);
}

__global__ void cast_mu0T_split(const float* __restrict__ MU0,
                                bf16* __restrict__ H, bf16* __restrict__ L) {
  const int k = blockIdx.x;
  for (int c = threadIdx.x; c < C_; c += 256) {
    const float v = MU0[c * K_ + k];
    const bf16 h = (bf16)v;
    H[k * C_ + c] = h;
    L[k * C_ + c] = lo_part(v, h);
  }
}

// ---------------------------------------------------------------------------
// conv1 FUSED transpose v3: xs_NC = x^T . w1^T + b1, split-bf16 3-pass MFMA.
// A: transposed-gather -> registers, issued EARLY (between staging barrier
// and MFMA cluster) so HBM latency hides under MFMA (T14). Convert once,
// write bf16x8 into [128][40]. B via GLDS16 + granule swizzle.
// ---------------------------------------------------------------------------
#define LOADREGS(cb32, xr)                                              \
  {                                                                     \
    _Pragma("unroll") for (int g = 0; g < 2; ++g) {                     \
      const int cg = cvg + g * 2;                                       \
      const int cbase = (cb32) + cg * 8;                                \
      _Pragma("unroll") for (int e = 0; e < 8; ++e)                     \
          xr[g * 8 + e] = Xb[(size_t)(cbase + e) * N_ + m0 + cvn];      \
    }                                                                   \
  }

#define STAGEREGS(xr)                                                   \
  {                                                                     \
    _Pragma("unroll") for (int g = 0; g < 2; ++g) {                     \
      const int cg = cvg + g * 2;                                       \
      bf16x8 vh, vl;                                                    \
      _Pragma("unroll") for (int e = 0; e < 8; ++e) {                   \
        const float v = xr[g * 8 + e];                                  \
        const bf16 h = (bf16)v;                                         \
        vh[e] = h;                                                      \
        vl[e] = lo_part(v, h);                                          \
      }                                                                 \
      *reinterpret_cast<bf16x8*>(&Ah[cvn][cg * 8]) = vh;                \
      *reinterpret_cast<bf16x8*>(&Al[cvn][cg * 8]) = vl;                \
    }                                                                   \
  }

#define MFMASUB(sub)                                                        \
  {                                                                         \
    bf16x8 ah[4], al4[4], bh[4], bl4[4];                                    \
    const int kc = ((((sub) << 2) + hi) ^ swz) << 3;                        \
    _Pragma("unroll") for (int i = 0; i < 4; ++i) {                         \
      const int arow = wm * 64 + i * 16 + lc;                               \
      ah[i] = *reinterpret_cast<const bf16x8*>(&Ah[arow][hi * 8]);          \
      al4[i] = *reinterpret_cast<const bf16x8*>(&Al[arow][hi * 8]);         \
    }                                                                       \
    _Pragma("unroll") for (int j = 0; j < 4; ++j) {                         \
      bh[j] = *reinterpret_cast<const bf16x8*>(                             \
          Bh + (wn * 64 + j * 16 + lc) * 64 + kc);                          \
      bl4[j] = *reinterpret_cast<const bf16x8*>(                            \
          Bl + (wn * 64 + j * 16 + lc) * 64 + kc);                          \
    }                                                                       \
    _Pragma("unroll") for (int i = 0; i < 4; ++i)                           \
        _Pragma("unroll") for (int j = 0; j < 4; ++j) {                     \
      acc[i][j] =                                                           \
          __builtin_amdgcn_mfma_f32_16x16x32_bf16(al4[i], bh[j], acc[i][j], 0, 0, 0); \
      acc[i][j] =                                                           \
          __builtin_amdgcn_mfma_f32_16x16x32_bf16(ah[i], bl4[j], acc[i][j], 0, 0, 0); \
      acc[i][j] =                                                           \
          __builtin_amdgcn_mfma_f32_16x16x32_bf16(ah[i], bh[j], acc[i][j], 0, 0, 0); \
    }                                                                       \
  }

__global__ __launch_bounds__(256) void conv1_fused(
    const float* __restrict__ X, const bf16* __restrict__ W1H,
    const bf16* __restrict__ W1L, const float* __restrict__ bias,
    bf16* __restrict__ XSH, bf16* __restrict__ XSL) {
  const int bz = blockIdx.z;
  const int m0 = blockIdx.x * 128;  // n rows
  const int n0 = blockIdx.y * 128;  // o cols
  const float* __restrict__ Xb = X + (size_t)bz * C_ * N_;

  __shared__ bf16 Ah[128][40], Al[128][40];  // 10.25 KB each (ld=40: 2-way)
  __shared__ bf16 Bbuf[2 * 128 * 64];        // 32 KB: Bh | Bl ; reused as EP
  bf16* Bh = Bbuf;
  bf16* Bl = Bbuf + 8192;

  const int tid = threadIdx.x, wid = tid >> 6, lane = tid & 63;
  const int lc = lane & 15, hi = lane >> 4;
  const int wm = wid >> 1, wn = wid & 1;
  const int swz = lc & 7;
  const int cvn = tid & 127;   // conversion: n row
  const int cvg = tid >> 7;    // conversion: c-granule base (0..1; +2 via g)

  f32x4 acc[4][4] = {};
  float xa[16], xb[16];

  LOADREGS(0, xa);  // prologue: regs for (k0=0, sub=0)

  for (int k0 = 0; k0 < C_; k0 += 64) {
    // stage B (w1 hi/lo) for this 64-c chunk
#pragma unroll
    for (int it = 0; it < 4; ++it) {
      const int chunk = it * 256 + tid;
      const int row = chunk >> 3;
      const int koff = (((chunk & 7) ^ (row & 7)) << 3);
      const size_t doff = (size_t)(it * 256 + wid * 64) * 8;
      GLDS16(W1H + (size_t)(n0 + row) * C_ + k0 + koff, Bh + doff);
      GLDS16(W1L + (size_t)(n0 + row) * C_ + k0 + koff, Bl + doff);
    }
    // sub 0
    STAGEREGS(xa);
    __syncthreads();           // A(sub0) + B staged
    LOADREGS(k0 + 32, xb);     // issue sub1 loads; latency hides under MFMA
    MFMASUB(0);
    __syncthreads();
    // sub 1
    STAGEREGS(xb);
    __syncthreads();           // A(sub1) staged
    if (k0 < C_ - 64) LOADREGS(k0 + 64, xa);  // prefetch next k0 sub0
    MFMASUB(1);
    __syncthreads();
  }

  // epilogue: EP repack (B region dead), coalesced bf16x8 stores
  bf16 (*EP)[128] = reinterpret_cast<bf16(*)[128]>(Bbuf);
  const int rr = tid >> 4, c8 = (tid & 15) << 3;
#pragma unroll
  for (int plane = 0; plane < 2; ++plane) {
    if (plane) __syncthreads();
#pragma unroll
    for (int j = 0; j < 4; ++j) {
      const int coll = wn * 64 + j * 16 + lc;
      const float bv = bias[n0 + coll];
#pragma unroll
      for (int i = 0; i < 4; ++i) {
        const int rowl = wm * 64 + i * 16 + hi * 4;
#pragma unroll
        for (int r = 0; r < 4; ++r) {
          const float v = acc[i][j][r] + bv;
          const bf16 h = (bf16)v;
          EP[rowl + r][coll] = plane ? lo_part(v, h) : h;
        }
      }
    }
    __syncthreads();
    bf16* DST = plane ? XSL : XSH;
#pragma unroll
    for (int rep = 0; rep < 8; ++rep) {
      const int row = rep * 16 + rr;
      *reinterpret_cast<bf16x8*>(&DST[((size_t)bz * N_ + m0 + row) * C_ + n0 + c8]) =
          *reinterpret_cast<const bf16x8*>(&EP[row][c8]);
    }
  }
}

// ---------------------------------------------------------------------------
// E-step: logits = xs . mu^T (split 3-pass), fp32 softmax over K=64.
// z written as hi/lo bf16 pair (precision-critical: r12 showed hi-only fails).
// ---------------------------------------------------------------------------
__global__ __launch_bounds__(256) void estep_split(
    const bf16* __restrict__ XSH, const bf16* __restrict__ XSL,
    const bf16* __restrict__ MTH, const bf16* __restrict__ MTL,
    size_t mustride, bf16* __restrict__ ZH, bf16* __restrict__ ZL,
    float* __restrict__ colsum, int b_base) {
  const int b = b_base + blockIdx.y;
  const int m0 = blockIdx.x * 128;
  const bf16* __restrict__ AHp = XSH + (size_t)b * N_ * C_;
  const bf16* __restrict__ ALp = XSL + (size_t)b * N_ * C_;
  const bf16* __restrict__ BHp = MTH + (size_t)b * mustride;
  const bf16* __restrict__ BLp = MTL + (size_t)b * mustride;

  __shared__ bf16 Ah[128][64], Al[128][64], Bh[64][64], Bl[64][64];
  __shared__ float cs[64];

  const int tid = threadIdx.x, wid = tid >> 6, lane = tid & 63;
  const int lc = lane & 15, hi = lane >> 4;
  const int swz = lc & 7;
  if (tid < 64) cs[tid] = 0.0f;

  f32x4 acc[2][4] = {};
  for (int k0 = 0; k0 < C_; k0 += 64) {
#pragma unroll
    for (int it = 0; it < 4; ++it) {
      const int chunk = it * 256 + tid;
      const int row = chunk >> 3;
      const int koff = (((chunk & 7) ^ (row & 7)) << 3);
      const size_t doff = (size_t)(it * 256 + wid * 64) * 8;
      GLDS16(AHp + (size_t)(m0 + row) * C_ + k0 + koff, &Ah[0][0] + doff);
      GLDS16(ALp + (size_t)(m0 + row) * C_ + k0 + koff, &Al[0][0] + doff);
    }
#pragma unroll
    for (int it = 0; it < 2; ++it) {
      const int chunk = it * 256 + tid;
      const int row = chunk >> 3;
      const int koff = (((chunk & 7) ^ (row & 7)) << 3);
      const size_t doff = (size_t)(it * 256 + wid * 64) * 8;
      GLDS16(BHp + (size_t)row * C_ + k0 + koff, &Bh[0][0] + doff);
      GLDS16(BLp + (size_t)row * C_ + k0 + koff, &Bl[0][0] + doff);
    }
    __syncthreads();
#pragma unroll
    for (int ks = 0; ks < 2; ++ks) {
      const int kc = (((ks << 2) + hi) ^ swz) << 3;
      bf16x8 ah[2], al4[2], bh[4], bl4[4];
#pragma unroll
      for (int i = 0; i < 2; ++i) {
        ah[i] = *reinterpret_cast<const bf16x8*>(&Ah[wid * 32 + i * 16 + lc][kc]);
        al4[i] = *reinterpret_cast<const bf16x8*>(&Al[wid * 32 + i * 16 + lc][kc]);
      }
#pragma unroll
      for (int j = 0; j < 4; ++j) {
        bh[j] = *reinterpret_cast<const bf16x8*>(&Bh[j * 16 + lc][kc]);
        bl4[j] = *reinterpret_cast<const bf16x8*>(&Bl[j * 16 + lc][kc]);
      }
#pragma unroll
      for (int i = 0; i < 2; ++i)
#pragma unroll
        for (int j = 0; j < 4; ++j) {
          acc[i][j] = __builtin_amdgcn_mfma_f32_16x16x32_bf16(al4[i], bh[j], acc[i][j], 0, 0, 0);
          acc[i][j] = __builtin_amdgcn_mfma_f32_16x16x32_bf16(ah[i], bl4[j], acc[i][j], 0, 0, 0);
          acc[i][j] = __builtin_amdgcn_mfma_f32_16x16x32_bf16(ah[i], bh[j], acc[i][j], 0, 0, 0);
        }
    }
    __syncthreads();
  }

  float cp[4] = {0.f, 0.f, 0.f, 0.f};
#pragma unroll
  for (int i = 0; i < 2; ++i) {
#pragma unroll
    for (int r = 0; r < 4; ++r) {
      float v0 = acc[i][0][r], v1 = acc[i][1][r], v2 = acc[i][2][r], v3 = acc[i][3][r];
      float mx = fmaxf(fmaxf(v0, v1), fmaxf(v2, v3));
#pragma unroll
      for (int off = 1; off < 16; off <<= 1) mx = fmaxf(mx, __shfl_xor(mx, off));
      float p0 = __expf(v0 - mx), p1 = __expf(v1 - mx);
      float p2 = __expf(v2 - mx), p3 = __expf(v3 - mx);
      float s = p0 + p1 + p2 + p3;
#pragma unroll
      for (int off = 1; off < 16; off <<= 1) s += __shfl_xor(s, off);
      const float inv = 1.0f / s;
      p0 *= inv; p1 *= inv; p2 *= inv; p3 *= inv;
      const int n = m0 + wid * 32 + i * 16 + hi * 4 + r;
      bf16* zh = ZH + ((size_t)b * N_ + n) * K_;
      bf16* zl = ZL + ((size_t)b * N_ + n) * K_;
      const float pv[4] = {p0, p1, p2, p3};
#pragma unroll
      for (int j = 0; j < 4; ++j) {
        const bf16 h = (bf16)pv[j];
        zh[j * 16 + lc] = h;
        zl[j * 16 + lc] = lo_part(pv[j], h);
        cp[j] += pv[j];
      }
    }
  }
#pragma unroll
  for (int j = 0; j < 4; ++j) atomicAdd(&cs[j * 16 + lc], cp[j]);
  __syncthreads();
  if (tid < 64) atomicAdd(&colsum[b * K_ + tid], cs[tid]);
}

// ---------------------------------------------------------------------------
// M-step: muacc (C x K) += sum_n xs[n][c]*z[n][k], split 3-pass.
// ---------------------------------------------------------------------------
__global__ __launch_bounds__(128) void mstep_split(
    const bf16* __restrict__ XSH, const bf16* __restrict__ XSL,
    const bf16* __restrict__ ZHp, const bf16* __restrict__ ZLp,
    float* __restrict__ MUACC, int b_base) {
  const int b = b_base + blockIdx.z;
  const int c0 = blockIdx.y * 128;
  const int nbase = blockIdx.x * MCHUNK;
  const bf16* __restrict__ XbH = XSH + (size_t)b * N_ * C_;
  const bf16* __restrict__ XbL = XSL + (size_t)b * N_ * C_;
  const bf16* __restrict__ ZbH = ZHp + (size_t)b * N_ * K_;
  const bf16* __restrict__ ZbL = ZLp + (size_t)b * N_ * K_;

  __shared__ bf16 Ah[128][40], Al[128][40], Bh[64][40], Bl[64][40];

  const int tid = threadIdx.x, wid = tid >> 6, lane = tid & 63;
  const int lc = lane & 15, hi = lane >> 4;

  f32x4 acc[4][4] = {};
  for (int n0 = nbase; n0 < nbase + MCHUNK; n0 += 32) {
#pragma unroll
    for (int it = 0; it < 4; ++it) {
      const int chunk = it * 128 + tid;
      const int nn = chunk & 31, c8 = (chunk >> 5) * 8;
      const bf16x8 vh = *reinterpret_cast<const bf16x8*>(
          &XbH[(size_t)(n0 + nn) * C_ + c0 + c8]);
      const bf16x8 vl = *reinterpret_cast<const bf16x8*>(
          &XbL[(size_t)(n0 + nn) * C_ + c0 + c8]);
#pragma unroll
      for (int e = 0; e < 8; ++e) {
        Ah[c8 + e][nn] = vh[e];
        Al[c8 + e][nn] = vl[e];
      }
    }
#pragma unroll
    for (int it = 0; it < 2; ++it) {
      const int chunk = it * 128 + tid;
      const int nn = chunk & 31, k8 = (chunk >> 5) * 8;
      const bf16x8 vh = *reinterpret_cast<const bf16x8*>(
          &ZbH[(size_t)(n0 + nn) * K_ + k8]);
      const bf16x8 vl = *reinterpret_cast<const bf16x8*>(
          &ZbL[(size_t)(n0 + nn) * K_ + k8]);
#pragma unroll
      for (int e = 0; e < 8; ++e) {
        Bh[k8 + e][nn] = vh[e];
        Bl[k8 + e][nn] = vl[e];
      }
    }
    __syncthreads();
    bf16x8 ah[4], al4[4], bh[4], bl4[4];
#pragma unroll
    for (int i = 0; i < 4; ++i) {
      ah[i] = *reinterpret_cast<const bf16x8*>(&Ah[wid * 64 + i * 16 + lc][hi * 8]);
      al4[i] = *reinterpret_cast<const bf16x8*>(&Al[wid * 64 + i * 16 + lc][hi * 8]);
    }
#pragma unroll
    for (int j = 0; j < 4; ++j) {
      bh[j] = *reinterpret_cast<const bf16x8*>(&Bh[j * 16 + lc][hi * 8]);
      bl4[j] = *reinterpret_cast<const bf16x8*>(&Bl[j * 16 + lc][hi * 8]);
    }
#pragma unroll
    for (int i = 0; i < 4; ++i)
#pragma unroll
      for (int j = 0; j < 4; ++j) {
        acc[i][j] = __builtin_amdgcn_mfma_f32_16x16x32_bf16(al4[i], bh[j], acc[i][j], 0, 0, 0);
        acc[i][j] = __builtin_amdgcn_mfma_f32_16x16x32_bf16(ah[i], bl4[j], acc[i][j], 0, 0, 0);
        acc[i][j] = __builtin_amdgcn_mfma_f32_16x16x32_bf16(ah[i], bh[j], acc[i][j], 0, 0, 0);
      }
    __syncthreads();
  }
#pragma unroll
  for (int i = 0; i < 4; ++i) {
    const int c = c0 + wid * 64 + i * 16 + hi * 4;
#pragma unroll
    for (int r = 0; r < 4; ++r)
#pragma unroll
      for (int j = 0; j < 4; ++j)
        atomicAdd(&MUACC[((size_t)b * C_ + c + r) * K_ + j * 16 + lc], acc[i][j][r]);
  }
}

// ---------------------------------------------------------------------------
// finalize mu; also re-zeroes its MUACC slice for the next iteration.
// ---------------------------------------------------------------------------
__global__ void finalize_mu(float* __restrict__ MUACC,
                            const float* __restrict__ colsum,
                            bf16* __restrict__ MUTH, bf16* __restrict__ MUTL,
                            bf16* __restrict__ MUH, float* __restrict__ muout,
                            int idx_base) {
  const int idx = idx_base + blockIdx.x * 256 + threadIdx.x;
  const int k = idx & (K_ - 1);
  const int c = (idx >> 6) & (C_ - 1);
  const int b = idx >> 15;
  const float v = MUACC[idx] / (1e-6f + colsum[b * K_ + k]);
  MUACC[idx] = 0.0f;
  const bf16 h = (bf16)v;
  MUH[idx] = h;
  MUTH[((size_t)b * K_ + k) * C_ + c] = h;
  MUTL[((size_t)b * K_ + k) * C_ + c] = lo_part(v, h);
  if (muout) muout[idx] = v;
}

// ---------------------------------------------------------------------------
// x2_NC = relu(z . mu^T), plain bf16, single K=64 tile. EP repack epilogue.
// ---------------------------------------------------------------------------
__global__ __launch_bounds__(256) void x2_plain(
    const bf16* __restrict__ ZHp, const bf16* __restrict__ MUHp,
    bf16* __restrict__ X2) {
  const int b = blockIdx.z;
  const int m0 = blockIdx.x * 128, n0 = blockIdx.y * 128;
  const bf16* __restrict__ Ab = ZHp + (size_t)b * N_ * K_;
  const bf16* __restrict__ Bb = MUHp + (size_t)b * C_ * K_;

  __shared__ bf16 SM[2 * 128 * 64];
  bf16* As = SM;
  bf16* Bs = SM + 8192;

  const int tid = threadIdx.x, wid = tid >> 6, lane = tid & 63;
  const int lc = lane & 15, hi = lane >> 4;
  const int wm = wid >> 1, wn = wid & 1;
  const int swz = lc & 7;

  f32x4 acc[4][4] = {};
#pragma unroll
  for (int it = 0; it < 4; ++it) {
    const int chunk = it * 256 + tid;
    const int row = chunk >> 3;
    const int koff = (((chunk & 7) ^ (row & 7)) << 3);
    const size_t doff = (size_t)(it * 256 + wid * 64) * 8;
    GLDS16(Ab + (size_t)(m0 + row) * K_ + koff, As + doff);
    GLDS16(Bb + (size_t)(n0 + row) * K_ + koff, Bs + doff);
  }
  __syncthreads();
#pragma unroll
  for (int ks = 0; ks < 2; ++ks) {
    const int kc = (((ks << 2) + hi) ^ swz) << 3;
    bf16x8 af[4], bg[4];
#pragma unroll
    for (int i = 0; i < 4; ++i)
      af[i] = *reinterpret_cast<const bf16x8*>(As + (wm * 64 + i * 16 + lc) * 64 + kc);
#pragma unroll
    for (int j = 0; j < 4; ++j)
      bg[j] = *reinterpret_cast<const bf16x8*>(Bs + (wn * 64 + j * 16 + lc) * 64 + kc);
#pragma unroll
    for (int i = 0; i < 4; ++i)
#pragma unroll
      for (int j = 0; j < 4; ++j)
        acc[i][j] = __builtin_amdgcn_mfma_f32_16x16x32_bf16(af[i], bg[j], acc[i][j], 0, 0, 0);
  }
  __syncthreads();

  bf16 (*EP)[128] = reinterpret_cast<bf16(*)[128]>(SM);
#pragma unroll
  for (int j = 0; j < 4; ++j) {
    const int coll = wn * 64 + j * 16 + lc;
#pragma unroll
    for (int i = 0; i < 4; ++i) {
      const int rowl = wm * 64 + i * 16 + hi * 4;
#pragma unroll
      for (int r = 0; r < 4; ++r)
        EP[rowl + r][coll] = (bf16)fmaxf(acc[i][j][r], 0.0f);
    }
  }
  __syncthreads();
  const int rr = tid >> 4, c8 = (tid & 15) << 3;
#pragma unroll
  for (int rep = 0; rep < 8; ++rep) {
    const int row = rep * 16 + rr;
    *reinterpret_cast<bf16x8*>(&X2[((size_t)b * N_ + m0 + row) * C_ + n0 + c8]) =
        *reinterpret_cast<const bf16x8*>(&EP[row][c8]);
  }
}

// ---------------------------------------------------------------------------
// conv2 pass 1: x3 tiles -> per-channel sum/sumsq non-atomic partials.
// ---------------------------------------------------------------------------
__global__ __launch_bounds__(256) void conv2_stats(
    const bf16* __restrict__ W2H, const bf16* __restrict__ X2,
    float* __restrict__ psumP, float* __restrict__ psqP) {
  const int b = blockIdx.z;
  const int m0 = blockIdx.x * 128, n0 = blockIdx.y * 128;
  const bf16* __restrict__ Bb = X2 + (size_t)b * N_ * C_;

  __shared__ bf16 As[128][64], Bs[128][64];
  __shared__ float s_sum[128], s_sq[128];

  const int tid = threadIdx.x, wid = tid >> 6, lane = tid & 63;
  const int lc = lane & 15, hi = lane >> 4;
  const int wm = wid >> 1, wn = wid & 1;
  const int swz = lc & 7;
  if (tid < 128) { s_sum[tid] = 0.0f; s_sq[tid] = 0.0f; }

  f32x4 acc[4][4] = {};
  for (int k0 = 0; k0 < C_; k0 += 64) {
#pragma unroll
    for (int it = 0; it < 4; ++it) {
      const int chunk = it * 256 + tid;
      const int row = chunk >> 3;
      const int koff = (((chunk & 7) ^ (row & 7)) << 3);
      const size_t doff = (size_t)(it * 256 + wid * 64) * 8;
      GLDS16(W2H + (size_t)(m0 + row) * C_ + k0 + koff, &As[0][0] + doff);
      GLDS16(Bb + (size_t)(n0 + row) * C_ + k0 + koff, &Bs[0][0] + doff);
    }
    __syncthreads();
#pragma unroll
    for (int ks = 0; ks < 2; ++ks) {
      const int kc = (((ks << 2) + hi) ^ swz) << 3;
      bf16x8 af[4], bg[4];
#pragma unroll
      for (int i = 0; i < 4; ++i)
        af[i] = *reinterpret_cast<const bf16x8*>(&As[wm * 64 + i * 16 + lc][kc]);
#pragma unroll
      for (int j = 0; j < 4; ++j)
        bg[j] = *reinterpret_cast<const bf16x8*>(&Bs[wn * 64 + j * 16 + lc][kc]);
#pragma unroll
      for (int i = 0; i < 4; ++i)
#pragma unroll
        for (int j = 0; j < 4; ++j)
          acc[i][j] = __builtin_amdgcn_mfma_f32_16x16x32_bf16(af[i], bg[j], acc[i][j], 0, 0, 0);
    }
    __syncthreads();
  }

  float ps[4][4] = {};
  float pq[4][4] = {};
#pragma unroll
  for (int j = 0; j < 4; ++j)
#pragma unroll
    for (int i = 0; i < 4; ++i)
#pragma unroll
      for (int r = 0; r < 4; ++r) {
        const float v = acc[i][j][r];
        ps[i][r] += v;
        pq[i][r] += v * v;
      }
#pragma unroll
  for (int off = 1; off < 16; off <<= 1)
#pragma unroll
    for (int i = 0; i < 4; ++i)
#pragma unroll
      for (int r = 0; r < 4; ++r) {
        ps[i][r] += __shfl_xor(ps[i][r], off);
        pq[i][r] += __shfl_xor(pq[i][r], off);
      }
  if (lc == 0) {
#pragma unroll
    for (int i = 0; i < 4; ++i) {
      const int chl = wm * 64 + i * 16 + hi * 4;
#pragma unroll
      for (int r = 0; r < 4; ++r) {
        atomicAdd(&s_sum[chl + r], ps[i][r]);
        atomicAdd(&s_sq[chl + r], pq[i][r]);
      }
    }
  }
  __syncthreads();
  const int p = b * 64 + blockIdx.y;
  if (tid < 128) {
    psumP[(size_t)p * C_ + m0 + tid] = s_sum[tid];
    psqP[(size_t)p * C_ + m0 + tid] = s_sq[tid];
  }
}

// ---------------------------------------------------------------------------
__global__ __launch_bounds__(256) void bn_finalize2(
    const float* __restrict__ psumP, const float* __restrict__ psqP,
    const float* __restrict__ gamma, const float* __restrict__ beta,
    float* __restrict__ gc, float* __restrict__ oc) {
  const int c = blockIdx.x;
  const int tid = threadIdx.x;
  float s = 0.0f, q = 0.0f;
  for (int p = tid; p < B_ * 64; p += 256) {
    s += psumP[(size_t)p * C_ + c];
    q += psqP[(size_t)p * C_ + c];
  }
  __shared__ float ls[256], lq[256];
  ls[tid] = s;
  lq[tid] = q;
  __syncthreads();
  for (int off = 128; off > 0; off >>= 1) {
    if (tid < off) { ls[tid] += ls[tid + off]; lq[tid] += lq[tid + off]; }
    __syncthreads();
  }
  if (tid == 0) {
    const float inv = 1.0f / ((float)B_ * N_);
    const float mean = ls[0] * inv;
    const float var = lq[0] * inv - mean * mean;
    const float rstd = rsqrtf(var + 1e-5f);
    const float g = gamma[c] * rstd;
    gc[c] = g;
    oc[c] = beta[c] - mean * g;
  }
}

// ---------------------------------------------------------------------------
// conv2 pass 2: x3 + BN + residual -> OUT fp32 (EPF repack, coalesced).
// ---------------------------------------------------------------------------
__global__ __launch_bounds__(256) void conv2_bn(
    const bf16* __restrict__ W2H, const bf16* __restrict__ X2,
    const float* __restrict__ gc, const float* __restrict__ oc,
    const float* __restrict__ Xin, float* __restrict__ OUT) {
  const int b = blockIdx.z;
  const int m0 = blockIdx.x * 128, n0 = blockIdx.y * 128;
  const bf16* __restrict__ Bb = X2 + (size_t)b * N_ * C_;

  __shared__ bf16 SM[2 * 128 * 64];
  bf16* As = SM;
  bf16* Bs = SM + 8192;

  const int tid = threadIdx.x, wid = tid >> 6, lane = tid & 63;
  const int lc = lane & 15, hi = lane >> 4;
  const int wm = wid >> 1, wn = wid & 1;
  const int swz = lc & 7;

  f32x4 acc[4][4] = {};
  for (int k0 = 0; k0 < C_; k0 += 64) {
#pragma unroll
    for (int it = 0; it < 4; ++it) {
      const int chunk = it * 256 + tid;
      const int row = chunk >> 3;
      const int koff = (((chunk & 7) ^ (row & 7)) << 3);
      const size_t doff = (size_t)(it * 256 + wid * 64) * 8;
      GLDS16(W2H + (size_t)(m0 + row) * C_ + k0 + koff, As + doff);
      GLDS16(Bb + (size_t)(n0 + row) * C_ + k0 + koff, Bs + doff);
    }
    __syncthreads();
#pragma unroll
    for (int ks = 0; ks < 2; ++ks) {
      const int kc = (((ks << 2) + hi) ^ swz) << 3;
      bf16x8 af[4], bg[4];
#pragma unroll
      for (int i = 0; i < 4; ++i)
        af[i] = *reinterpret_cast<const bf16x8*>(As + (wm * 64 + i * 16 + lc) * 64 + kc);
#pragma unroll
      for (int j = 0; j < 4; ++j)
        bg[j] = *reinterpret_cast<const bf16x8*>(Bs + (wn * 64 + j * 16 + lc) * 64 + kc);
#pragma unroll
      for (int i = 0; i < 4; ++i)
#pragma unroll
        for (int j = 0; j < 4; ++j)
          acc[i][j] = __builtin_amdgcn_mfma_f32_16x16x32_bf16(af[i], bg[j], acc[i][j], 0, 0, 0);
    }
    __syncthreads();
  }

  float (*EPF)[132] = reinterpret_cast<float(*)[132]>(SM);
  const int rr = tid >> 3, c4 = (tid & 7) << 2;
#pragma unroll
  for (int i = 0; i < 4; ++i) {
    if (i) __syncthreads();
    const int row0 = m0 + wm * 64 + i * 16 + hi * 4;
    const float4 g4 = *reinterpret_cast<const float4*>(&gc[row0]);
    const float4 o4 = *reinterpret_cast<const float4*>(&oc[row0]);
    const float ga[4] = {g4.x, g4.y, g4.z, g4.w};
    const float oa[4] = {o4.x, o4.y, o4.z, o4.w};
#pragma unroll
    for (int j = 0; j < 4; ++j) {
      const int coll = wn * 64 + j * 16 + lc;
#pragma unroll
      for (int r = 0; r < 4; ++r)
        EPF[wm * 16 + hi * 4 + r][coll] = acc[i][j][r] * ga[r] + oa[r];
    }
    __syncthreads();
    const int m = m0 + (rr >> 4) * 64 + i * 16 + (rr & 15);
#pragma unroll
    for (int rep = 0; rep < 4; ++rep) {
      const int col = rep * 32 + c4;
      const size_t off = ((size_t)b * C_ + m) * N_ + n0 + col;
      const float4 xi = *reinterpret_cast<const float4*>(&Xin[off]);
      float4 ov;
      ov.x = EPF[rr][col + 0] + xi.x;
      ov.y = EPF[rr][col + 1] + xi.y;
      ov.z = EPF[rr][col + 2] + xi.z;
      ov.w = EPF[rr][col + 3] + xi.w;
      *reinterpret_cast<float4*>(&OUT[off]) = ov;
    }
  }
}

// ---------------------------------------------------------------------------
extern "C" void kernel_launch(void* const* d_in, const int* in_sizes, int n_in,
                              void* d_out, int out_size, void* d_ws,
                              size_t ws_size, hipStream_t stream) {
  (void)in_sizes; (void)n_in; (void)out_size; (void)ws_size;
  const float* x     = (const float*)d_in[0];
  const float* w1    = (const float*)d_in[1];
  const float* b1    = (const float*)d_in[2];
  const float* mu0   = (const float*)d_in[3];
  const float* w2    = (const float*)d_in[4];
  const float* gamma = (const float*)d_in[5];
  const float* beta  = (const float*)d_in[6];

  // d_out: xs hi/lo planes live here until conv2_bn overwrites with fp32 out.
  bf16* XSH = (bf16*)d_out;
  bf16* XSL = XSH + (size_t)B_ * N_ * C_;
  float* OUT = (float*)d_out;
  float* MUOUT = OUT + (size_t)B_ * C_ * N_;

  // d_ws layout (identical to round 11)
  bf16* X2b = (bf16*)d_ws;                          // B*N*C
  bf16* ZH  = X2b + (size_t)B_ * N_ * C_;           // B*N*K
  bf16* ZL  = ZH + (size_t)B_ * N_ * K_;
  bf16* W1H = ZL + (size_t)B_ * N_ * K_;
  bf16* W1L = W1H + C_ * C_;
  bf16* W2H = W1L + C_ * C_;
  bf16* W2L = W2H + C_ * C_;
  bf16* MT0H = W2L + C_ * C_;                       // K*C
  bf16* MT0L = MT0H + K_ * C_;
  bf16* MUTH = MT0L + K_ * C_;                      // B*K*C
  bf16* MUTL = MUTH + (size_t)B_ * K_ * C_;
  bf16* MUH  = MUTL + (size_t)B_ * K_ * C_;         // B*C*K
  float* MUACC = (float*)(MUH + (size_t)B_ * C_ * K_);
  float* colsum = MUACC + (size_t)B_ * C_ * K_;     // B*K
  float* gcp = colsum + B_ * K_;                    // C
  float* ocp = gcp + C_;                            // C
  float* psumP = ocp + C_;                          // 1024*C
  float* psqP  = psumP + (size_t)B_ * 64 * C_;      // 1024*C

  const dim3 blk(256);

  cast_w_split<<<dim3(C_ * C_ / 256), blk, 0, stream>>>(w1, W1H, W1L);
  cast_w_split<<<dim3(C_ * C_ / 256), blk, 0, stream>>>(w2, W2H, W2L);
  cast_mu0T_split<<<dim3(K_), blk, 0, stream>>>(mu0, MT0H, MT0L);
  hipMemsetAsync(MUACC, 0, (size_t)B_ * C_ * K_ * sizeof(float), stream);

  // conv1 with fused transpose + register prefetch, all 16 batches
  conv1_fused<<<dim3(N_ / 128, C_ / 128, B_), blk, 0, stream>>>(
      x, W1H, W1L, b1, XSH, XSL);

  // EM: grouped by batches so xs hi/lo (134 MB/group) stays L3-resident
  for (int g = 0; g < B_ / BGRP; ++g) {
    const int boff = g * BGRP;
    for (int it = 0; it < 3; ++it) {
      hipMemsetAsync(colsum + boff * K_, 0, BGRP * K_ * sizeof(float), stream);
      estep_split<<<dim3(N_ / 128, BGRP), blk, 0, stream>>>(
          XSH, XSL, it == 0 ? MT0H : MUTH, it == 0 ? MT0L : MUTL,
          it == 0 ? 0 : (size_t)K_ * C_, ZH, ZL, colsum, boff);
      mstep_split<<<dim3(N_ / MCHUNK, C_ / 128, BGRP), dim3(128), 0, stream>>>(
          XSH, XSL, ZH, ZL, MUACC, boff);
      finalize_mu<<<dim3(BGRP * C_ * K_ / 256), blk, 0, stream>>>(
          MUACC, colsum, MUTH, MUTL, MUH, it == 2 ? MUOUT : nullptr,
          boff * C_ * K_);
    }
  }

  x2_plain<<<dim3(N_ / 128, C_ / 128, B_), blk, 0, stream>>>(ZH, MUH, X2b);
  conv2_stats<<<dim3(C_ / 128, N_ / 128, B_), blk, 0, stream>>>(
      W2H, X2b, psumP, psqP);
  bn_finalize2<<<dim3(C_), blk, 0, stream>>>(psumP, psqP, gamma, beta, gcp, ocp);
  conv2_bn<<<dim3(C_ / 128, N_ / 128, B_), blk, 0, stream>>>(
      W2H, X2b, gcp, ocp, x, OUT);
}

// Round 14
// 1064.341 us; speedup vs baseline: 1.1281x; 1.0404x over previous
//
#include <hip/hip_runtime.h>
#include <math.h>

constexpr int B_ = 16, C_ = 512, K_ = 64, N_ = 8192;
constexpr int BGRP = 8;       // EM batch group size (L3 residency)
constexpr int MCHUNK = 512;   // mstep n-chunk
constexpr int NCHK = N_ / MCHUNK;  // 16 partial slabs

typedef __bf16 bf16;
typedef __bf16 bf16x4 __attribute__((ext_vector_type(4)));
typedef __bf16 bf16x8 __attribute__((ext_vector_type(8)));
typedef float f32x4 __attribute__((ext_vector_type(4)));

#define GLDS16(gp, lp)                                              \
  __builtin_amdgcn_global_load_lds(                                 \
      (const __attribute__((address_space(1))) unsigned int*)(gp),  \
      (__attribute__((address_space(3))) unsigned int*)(lp), 16, 0, 0)

__device__ __forceinline__ bf16 lo_part(float v, bf16 h) {
  return (bf16)(v - (float)h);
}

__global__ void cast_w_split(const float* __restrict__ W, bf16* __restrict__ H,
                             bf16* __restrict__ L) {
  const int i = blockIdx.x * 256 + threadIdx.x;
  const float v = W[i];
  const bf16 h = (bf16)v;
  H[i] = h;
  L[i] = lo_part(v, h);
}

__global__ void cast_mu0T_split(const float* __restrict__ MU0,
                                bf16* __restrict__ H, bf16* __restrict__ L) {
  const int k = blockIdx.x;
  for (int c = threadIdx.x; c < C_; c += 256) {
    const float v = MU0[c * K_ + k];
    const bf16 h = (bf16)v;
    H[k * C_ + c] = h;
    L[k * C_ + c] = lo_part(v, h);
  }
}

// ---------------------------------------------------------------------------
// conv1 FUSED transpose v4: xs_NC = x^T . w1^T + b1, split-bf16 3-pass MFMA.
// A: transposed-gather -> registers issued early (T14); TRUNCATION hi/lo
// split (hi = top16 bits, lo = RNE(v-hi)): 1 fewer VALU op per element,
// combined error ~2^-17. B via GLDS16 + granule swizzle.
// ---------------------------------------------------------------------------
#define LOADREGS(cb32, xr)                                              \
  {                                                                     \
    _Pragma("unroll") for (int g = 0; g < 2; ++g) {                     \
      const int cg = cvg + g * 2;                                       \
      const int cbase = (cb32) + cg * 8;                                \
      _Pragma("unroll") for (int e = 0; e < 8; ++e)                     \
          xr[g * 8 + e] = Xb[(size_t)(cbase + e) * N_ + m0 + cvn];      \
    }                                                                   \
  }

#define STAGEREGS(xr)                                                   \
  {                                                                     \
    _Pragma("unroll") for (int g = 0; g < 2; ++g) {                     \
      const int cg = cvg + g * 2;                                       \
      bf16x8 vh, vl;                                                    \
      _Pragma("unroll") for (int e = 0; e < 8; ++e) {                   \
        const float v = xr[g * 8 + e];                                  \
        const unsigned u = __builtin_bit_cast(unsigned, v);             \
        vh[e] = __builtin_bit_cast(bf16, (unsigned short)(u >> 16));    \
        const float hf = __builtin_bit_cast(float, u & 0xffff0000u);    \
        vl[e] = (bf16)(v - hf);                                         \
      }                                                                 \
      *reinterpret_cast<bf16x8*>(&Ah[cvn][cg * 8]) = vh;                \
      *reinterpret_cast<bf16x8*>(&Al[cvn][cg * 8]) = vl;                \
    }                                                                   \
  }

#define MFMASUB(sub)                                                        \
  {                                                                         \
    bf16x8 ah[4], al4[4], bh[4], bl4[4];                                    \
    const int kc = ((((sub) << 2) + hi) ^ swz) << 3;                        \
    _Pragma("unroll") for (int i = 0; i < 4; ++i) {                         \
      const int arow = wm * 64 + i * 16 + lc;                               \
      ah[i] = *reinterpret_cast<const bf16x8*>(&Ah[arow][hi * 8]);          \
      al4[i] = *reinterpret_cast<const bf16x8*>(&Al[arow][hi * 8]);         \
    }                                                                       \
    _Pragma("unroll") for (int j = 0; j < 4; ++j) {                         \
      bh[j] = *reinterpret_cast<const bf16x8*>(                             \
          Bh + (wn * 64 + j * 16 + lc) * 64 + kc);                          \
      bl4[j] = *reinterpret_cast<const bf16x8*>(                            \
          Bl + (wn * 64 + j * 16 + lc) * 64 + kc);                          \
    }                                                                       \
    _Pragma("unroll") for (int i = 0; i < 4; ++i)                           \
        _Pragma("unroll") for (int j = 0; j < 4; ++j) {                     \
      acc[i][j] =                                                           \
          __builtin_amdgcn_mfma_f32_16x16x32_bf16(al4[i], bh[j], acc[i][j], 0, 0, 0); \
      acc[i][j] =                                                           \
          __builtin_amdgcn_mfma_f32_16x16x32_bf16(ah[i], bl4[j], acc[i][j], 0, 0, 0); \
      acc[i][j] =                                                           \
          __builtin_amdgcn_mfma_f32_16x16x32_bf16(ah[i], bh[j], acc[i][j], 0, 0, 0); \
    }                                                                       \
  }

__global__ __launch_bounds__(256) void conv1_fused(
    const float* __restrict__ X, const bf16* __restrict__ W1H,
    const bf16* __restrict__ W1L, const float* __restrict__ bias,
    bf16* __restrict__ XSH, bf16* __restrict__ XSL) {
  const int bz = blockIdx.z;
  const int m0 = blockIdx.x * 128;  // n rows
  const int n0 = blockIdx.y * 128;  // o cols
  const float* __restrict__ Xb = X + (size_t)bz * C_ * N_;

  __shared__ bf16 Ah[128][40], Al[128][40];  // 10.25 KB each (ld=40: 2-way)
  __shared__ bf16 Bbuf[2 * 128 * 64];        // 32 KB: Bh | Bl ; reused as EP
  bf16* Bh = Bbuf;
  bf16* Bl = Bbuf + 8192;

  const int tid = threadIdx.x, wid = tid >> 6, lane = tid & 63;
  const int lc = lane & 15, hi = lane >> 4;
  const int wm = wid >> 1, wn = wid & 1;
  const int swz = lc & 7;
  const int cvn = tid & 127;   // conversion: n row
  const int cvg = tid >> 7;    // conversion: c-granule base (0..1; +2 via g)

  f32x4 acc[4][4] = {};
  float xa[16], xb[16];

  LOADREGS(0, xa);  // prologue: regs for (k0=0, sub=0)

  for (int k0 = 0; k0 < C_; k0 += 64) {
    // stage B (w1 hi/lo) for this 64-c chunk
#pragma unroll
    for (int it = 0; it < 4; ++it) {
      const int chunk = it * 256 + tid;
      const int row = chunk >> 3;
      const int koff = (((chunk & 7) ^ (row & 7)) << 3);
      const size_t doff = (size_t)(it * 256 + wid * 64) * 8;
      GLDS16(W1H + (size_t)(n0 + row) * C_ + k0 + koff, Bh + doff);
      GLDS16(W1L + (size_t)(n0 + row) * C_ + k0 + koff, Bl + doff);
    }
    // sub 0
    STAGEREGS(xa);
    __syncthreads();           // A(sub0) + B staged
    LOADREGS(k0 + 32, xb);     // issue sub1 loads; latency hides under MFMA
    MFMASUB(0);
    __syncthreads();
    // sub 1
    STAGEREGS(xb);
    __syncthreads();           // A(sub1) staged
    if (k0 < C_ - 64) LOADREGS(k0 + 64, xa);  // prefetch next k0 sub0
    MFMASUB(1);
    __syncthreads();
  }

  // epilogue: EP repack (B region dead), coalesced bf16x8 stores
  bf16 (*EP)[128] = reinterpret_cast<bf16(*)[128]>(Bbuf);
  const int rr = tid >> 4, c8 = (tid & 15) << 3;
#pragma unroll
  for (int plane = 0; plane < 2; ++plane) {
    if (plane) __syncthreads();
#pragma unroll
    for (int j = 0; j < 4; ++j) {
      const int coll = wn * 64 + j * 16 + lc;
      const float bv = bias[n0 + coll];
#pragma unroll
      for (int i = 0; i < 4; ++i) {
        const int rowl = wm * 64 + i * 16 + hi * 4;
#pragma unroll
        for (int r = 0; r < 4; ++r) {
          const float v = acc[i][j][r] + bv;
          const bf16 h = (bf16)v;
          EP[rowl + r][coll] = plane ? lo_part(v, h) : h;
        }
      }
    }
    __syncthreads();
    bf16* DST = plane ? XSL : XSH;
#pragma unroll
    for (int rep = 0; rep < 8; ++rep) {
      const int row = rep * 16 + rr;
      *reinterpret_cast<bf16x8*>(&DST[((size_t)bz * N_ + m0 + row) * C_ + n0 + c8]) =
          *reinterpret_cast<const bf16x8*>(&EP[row][c8]);
    }
  }
}

// ---------------------------------------------------------------------------
// E-step: logits = xs . mu^T (split 3-pass), fp32 softmax over K=64.
// z written as hi/lo bf16 pair (precision-critical: r12 showed hi-only fails).
// ---------------------------------------------------------------------------
__global__ __launch_bounds__(256) void estep_split(
    const bf16* __restrict__ XSH, const bf16* __restrict__ XSL,
    const bf16* __restrict__ MTH, const bf16* __restrict__ MTL,
    size_t mustride, bf16* __restrict__ ZH, bf16* __restrict__ ZL,
    float* __restrict__ colsum, int b_base) {
  const int b = b_base + blockIdx.y;
  const int m0 = blockIdx.x * 128;
  const bf16* __restrict__ AHp = XSH + (size_t)b * N_ * C_;
  const bf16* __restrict__ ALp = XSL + (size_t)b * N_ * C_;
  const bf16* __restrict__ BHp = MTH + (size_t)b * mustride;
  const bf16* __restrict__ BLp = MTL + (size_t)b * mustride;

  __shared__ bf16 Ah[128][64], Al[128][64], Bh[64][64], Bl[64][64];
  __shared__ float cs[64];

  const int tid = threadIdx.x, wid = tid >> 6, lane = tid & 63;
  const int lc = lane & 15, hi = lane >> 4;
  const int swz = lc & 7;
  if (tid < 64) cs[tid] = 0.0f;

  f32x4 acc[2][4] = {};
  for (int k0 = 0; k0 < C_; k0 += 64) {
#pragma unroll
    for (int it = 0; it < 4; ++it) {
      const int chunk = it * 256 + tid;
      const int row = chunk >> 3;
      const int koff = (((chunk & 7) ^ (row & 7)) << 3);
      const size_t doff = (size_t)(it * 256 + wid * 64) * 8;
      GLDS16(AHp + (size_t)(m0 + row) * C_ + k0 + koff, &Ah[0][0] + doff);
      GLDS16(ALp + (size_t)(m0 + row) * C_ + k0 + koff, &Al[0][0] + doff);
    }
#pragma unroll
    for (int it = 0; it < 2; ++it) {
      const int chunk = it * 256 + tid;
      const int row = chunk >> 3;
      const int koff = (((chunk & 7) ^ (row & 7)) << 3);
      const size_t doff = (size_t)(it * 256 + wid * 64) * 8;
      GLDS16(BHp + (size_t)row * C_ + k0 + koff, &Bh[0][0] + doff);
      GLDS16(BLp + (size_t)row * C_ + k0 + koff, &Bl[0][0] + doff);
    }
    __syncthreads();
#pragma unroll
    for (int ks = 0; ks < 2; ++ks) {
      const int kc = (((ks << 2) + hi) ^ swz) << 3;
      bf16x8 ah[2], al4[2], bh[4], bl4[4];
#pragma unroll
      for (int i = 0; i < 2; ++i) {
        ah[i] = *reinterpret_cast<const bf16x8*>(&Ah[wid * 32 + i * 16 + lc][kc]);
        al4[i] = *reinterpret_cast<const bf16x8*>(&Al[wid * 32 + i * 16 + lc][kc]);
      }
#pragma unroll
      for (int j = 0; j < 4; ++j) {
        bh[j] = *reinterpret_cast<const bf16x8*>(&Bh[j * 16 + lc][kc]);
        bl4[j] = *reinterpret_cast<const bf16x8*>(&Bl[j * 16 + lc][kc]);
      }
#pragma unroll
      for (int i = 0; i < 2; ++i)
#pragma unroll
        for (int j = 0; j < 4; ++j) {
          acc[i][j] = __builtin_amdgcn_mfma_f32_16x16x32_bf16(al4[i], bh[j], acc[i][j], 0, 0, 0);
          acc[i][j] = __builtin_amdgcn_mfma_f32_16x16x32_bf16(ah[i], bl4[j], acc[i][j], 0, 0, 0);
          acc[i][j] = __builtin_amdgcn_mfma_f32_16x16x32_bf16(ah[i], bh[j], acc[i][j], 0, 0, 0);
        }
    }
    __syncthreads();
  }

  float cp[4] = {0.f, 0.f, 0.f, 0.f};
#pragma unroll
  for (int i = 0; i < 2; ++i) {
#pragma unroll
    for (int r = 0; r < 4; ++r) {
      float v0 = acc[i][0][r], v1 = acc[i][1][r], v2 = acc[i][2][r], v3 = acc[i][3][r];
      float mx = fmaxf(fmaxf(v0, v1), fmaxf(v2, v3));
#pragma unroll
      for (int off = 1; off < 16; off <<= 1) mx = fmaxf(mx, __shfl_xor(mx, off));
      float p0 = __expf(v0 - mx), p1 = __expf(v1 - mx);
      float p2 = __expf(v2 - mx), p3 = __expf(v3 - mx);
      float s = p0 + p1 + p2 + p3;
#pragma unroll
      for (int off = 1; off < 16; off <<= 1) s += __shfl_xor(s, off);
      const float inv = 1.0f / s;
      p0 *= inv; p1 *= inv; p2 *= inv; p3 *= inv;
      const int n = m0 + wid * 32 + i * 16 + hi * 4 + r;
      bf16* zh = ZH + ((size_t)b * N_ + n) * K_;
      bf16* zl = ZL + ((size_t)b * N_ + n) * K_;
      const float pv[4] = {p0, p1, p2, p3};
#pragma unroll
      for (int j = 0; j < 4; ++j) {
        const bf16 h = (bf16)pv[j];
        zh[j * 16 + lc] = h;
        zl[j * 16 + lc] = lo_part(pv[j], h);
        cp[j] += pv[j];
      }
    }
  }
#pragma unroll
  for (int j = 0; j < 4; ++j) atomicAdd(&cs[j * 16 + lc], cp[j]);
  __syncthreads();
  if (tid < 64) atomicAdd(&colsum[b * K_ + tid], cs[tid]);
}

// ---------------------------------------------------------------------------
// M-step: partials MUACCP[chunk][b][c][k] = sum_n xs[n][c]*z[n][k] over this
// chunk's n-range. Non-atomic stores (chunk owns its slab). Split 3-pass.
// ---------------------------------------------------------------------------
__global__ __launch_bounds__(128) void mstep_split(
    const bf16* __restrict__ XSH, const bf16* __restrict__ XSL,
    const bf16* __restrict__ ZHp, const bf16* __restrict__ ZLp,
    float* __restrict__ MUACCP, int b_base) {
  const int b = b_base + blockIdx.z;
  const int c0 = blockIdx.y * 128;
  const int p = blockIdx.x;
  const int nbase = p * MCHUNK;
  const bf16* __restrict__ XbH = XSH + (size_t)b * N_ * C_;
  const bf16* __restrict__ XbL = XSL + (size_t)b * N_ * C_;
  const bf16* __restrict__ ZbH = ZHp + (size_t)b * N_ * K_;
  const bf16* __restrict__ ZbL = ZLp + (size_t)b * N_ * K_;

  __shared__ bf16 Ah[128][40], Al[128][40], Bh[64][40], Bl[64][40];

  const int tid = threadIdx.x, wid = tid >> 6, lane = tid & 63;
  const int lc = lane & 15, hi = lane >> 4;

  f32x4 acc[4][4] = {};
  for (int n0 = nbase; n0 < nbase + MCHUNK; n0 += 32) {
#pragma unroll
    for (int it = 0; it < 4; ++it) {
      const int chunk = it * 128 + tid;
      const int nn = chunk & 31, c8 = (chunk >> 5) * 8;
      const bf16x8 vh = *reinterpret_cast<const bf16x8*>(
          &XbH[(size_t)(n0 + nn) * C_ + c0 + c8]);
      const bf16x8 vl = *reinterpret_cast<const bf16x8*>(
          &XbL[(size_t)(n0 + nn) * C_ + c0 + c8]);
#pragma unroll
      for (int e = 0; e < 8; ++e) {
        Ah[c8 + e][nn] = vh[e];
        Al[c8 + e][nn] = vl[e];
      }
    }
#pragma unroll
    for (int it = 0; it < 2; ++it) {
      const int chunk = it * 128 + tid;
      const int nn = chunk & 31, k8 = (chunk >> 5) * 8;
      const bf16x8 vh = *reinterpret_cast<const bf16x8*>(
          &ZbH[(size_t)(n0 + nn) * K_ + k8]);
      const bf16x8 vl = *reinterpret_cast<const bf16x8*>(
          &ZbL[(size_t)(n0 + nn) * K_ + k8]);
#pragma unroll
      for (int e = 0; e < 8; ++e) {
        Bh[k8 + e][nn] = vh[e];
        Bl[k8 + e][nn] = vl[e];
      }
    }
    __syncthreads();
    bf16x8 ah[4], al4[4], bh[4], bl4[4];
#pragma unroll
    for (int i = 0; i < 4; ++i) {
      ah[i] = *reinterpret_cast<const bf16x8*>(&Ah[wid * 64 + i * 16 + lc][hi * 8]);
      al4[i] = *reinterpret_cast<const bf16x8*>(&Al[wid * 64 + i * 16 + lc][hi * 8]);
    }
#pragma unroll
    for (int j = 0; j < 4; ++j) {
      bh[j] = *reinterpret_cast<const bf16x8*>(&Bh[j * 16 + lc][hi * 8]);
      bl4[j] = *reinterpret_cast<const bf16x8*>(&Bl[j * 16 + lc][hi * 8]);
    }
#pragma unroll
    for (int i = 0; i < 4; ++i)
#pragma unroll
      for (int j = 0; j < 4; ++j) {
        acc[i][j] = __builtin_amdgcn_mfma_f32_16x16x32_bf16(al4[i], bh[j], acc[i][j], 0, 0, 0);
        acc[i][j] = __builtin_amdgcn_mfma_f32_16x16x32_bf16(ah[i], bl4[j], acc[i][j], 0, 0, 0);
        acc[i][j] = __builtin_amdgcn_mfma_f32_16x16x32_bf16(ah[i], bh[j], acc[i][j], 0, 0, 0);
      }
    __syncthreads();
  }
  float* slab = MUACCP + (((size_t)p * B_ + b) * C_) * K_;
#pragma unroll
  for (int i = 0; i < 4; ++i) {
    const int c = c0 + wid * 64 + i * 16 + hi * 4;
#pragma unroll
    for (int r = 0; r < 4; ++r)
#pragma unroll
      for (int j = 0; j < 4; ++j)
        slab[(size_t)(c + r) * K_ + j * 16 + lc] = acc[i][j][r];
  }
}

// ---------------------------------------------------------------------------
// finalize mu: reduce 16 chunk-partials, scale by 1/(1e-6+colsum).
// ---------------------------------------------------------------------------
__global__ void finalize_mu(const float* __restrict__ MUACCP,
                            const float* __restrict__ colsum,
                            bf16* __restrict__ MUTH, bf16* __restrict__ MUTL,
                            bf16* __restrict__ MUH, float* __restrict__ muout,
                            int idx_base) {
  const int idx = idx_base + blockIdx.x * 256 + threadIdx.x;
  const int k = idx & (K_ - 1);
  const int c = (idx >> 6) & (C_ - 1);
  const int b = idx >> 15;
  float acc = 0.0f;
#pragma unroll
  for (int p = 0; p < NCHK; ++p)
    acc += MUACCP[(size_t)p * B_ * C_ * K_ + idx];
  const float v = acc / (1e-6f + colsum[b * K_ + k]);
  const bf16 h = (bf16)v;
  MUH[idx] = h;
  MUTH[((size_t)b * K_ + k) * C_ + c] = h;
  MUTL[((size_t)b * K_ + k) * C_ + c] = lo_part(v, h);
  if (muout) muout[idx] = v;
}

// ---------------------------------------------------------------------------
// x2_NC = relu(z . mu^T), plain bf16, single K=64 tile. EP repack epilogue.
// ---------------------------------------------------------------------------
__global__ __launch_bounds__(256) void x2_plain(
    const bf16* __restrict__ ZHp, const bf16* __restrict__ MUHp,
    bf16* __restrict__ X2) {
  const int b = blockIdx.z;
  const int m0 = blockIdx.x * 128, n0 = blockIdx.y * 128;
  const bf16* __restrict__ Ab = ZHp + (size_t)b * N_ * K_;
  const bf16* __restrict__ Bb = MUHp + (size_t)b * C_ * K_;

  __shared__ bf16 SM[2 * 128 * 64];
  bf16* As = SM;
  bf16* Bs = SM + 8192;

  const int tid = threadIdx.x, wid = tid >> 6, lane = tid & 63;
  const int lc = lane & 15, hi = lane >> 4;
  const int wm = wid >> 1, wn = wid & 1;
  const int swz = lc & 7;

  f32x4 acc[4][4] = {};
#pragma unroll
  for (int it = 0; it < 4; ++it) {
    const int chunk = it * 256 + tid;
    const int row = chunk >> 3;
    const int koff = (((chunk & 7) ^ (row & 7)) << 3);
    const size_t doff = (size_t)(it * 256 + wid * 64) * 8;
    GLDS16(Ab + (size_t)(m0 + row) * K_ + koff, As + doff);
    GLDS16(Bb + (size_t)(n0 + row) * K_ + koff, Bs + doff);
  }
  __syncthreads();
#pragma unroll
  for (int ks = 0; ks < 2; ++ks) {
    const int kc = (((ks << 2) + hi) ^ swz) << 3;
    bf16x8 af[4], bg[4];
#pragma unroll
    for (int i = 0; i < 4; ++i)
      af[i] = *reinterpret_cast<const bf16x8*>(As + (wm * 64 + i * 16 + lc) * 64 + kc);
#pragma unroll
    for (int j = 0; j < 4; ++j)
      bg[j] = *reinterpret_cast<const bf16x8*>(Bs + (wn * 64 + j * 16 + lc) * 64 + kc);
#pragma unroll
    for (int i = 0; i < 4; ++i)
#pragma unroll
      for (int j = 0; j < 4; ++j)
        acc[i][j] = __builtin_amdgcn_mfma_f32_16x16x32_bf16(af[i], bg[j], acc[i][j], 0, 0, 0);
  }
  __syncthreads();

  bf16 (*EP)[128] = reinterpret_cast<bf16(*)[128]>(SM);
#pragma unroll
  for (int j = 0; j < 4; ++j) {
    const int coll = wn * 64 + j * 16 + lc;
#pragma unroll
    for (int i = 0; i < 4; ++i) {
      const int rowl = wm * 64 + i * 16 + hi * 4;
#pragma unroll
      for (int r = 0; r < 4; ++r)
        EP[rowl + r][coll] = (bf16)fmaxf(acc[i][j][r], 0.0f);
    }
  }
  __syncthreads();
  const int rr = tid >> 4, c8 = (tid & 15) << 3;
#pragma unroll
  for (int rep = 0; rep < 8; ++rep) {
    const int row = rep * 16 + rr;
    *reinterpret_cast<bf16x8*>(&X2[((size_t)b * N_ + m0 + row) * C_ + n0 + c8]) =
        *reinterpret_cast<const bf16x8*>(&EP[row][c8]);
  }
}

// ---------------------------------------------------------------------------
// conv2 pass 1: x3 tiles -> per-channel sum/sumsq non-atomic partials.
// ---------------------------------------------------------------------------
__global__ __launch_bounds__(256) void conv2_stats(
    const bf16* __restrict__ W2H, const bf16* __restrict__ X2,
    float* __restrict__ psumP, float* __restrict__ psqP) {
  const int b = blockIdx.z;
  const int m0 = blockIdx.x * 128, n0 = blockIdx.y * 128;
  const bf16* __restrict__ Bb = X2 + (size_t)b * N_ * C_;

  __shared__ bf16 As[128][64], Bs[128][64];
  __shared__ float s_sum[128], s_sq[128];

  const int tid = threadIdx.x, wid = tid >> 6, lane = tid & 63;
  const int lc = lane & 15, hi = lane >> 4;
  const int wm = wid >> 1, wn = wid & 1;
  const int swz = lc & 7;
  if (tid < 128) { s_sum[tid] = 0.0f; s_sq[tid] = 0.0f; }

  f32x4 acc[4][4] = {};
  for (int k0 = 0; k0 < C_; k0 += 64) {
#pragma unroll
    for (int it = 0; it < 4; ++it) {
      const int chunk = it * 256 + tid;
      const int row = chunk >> 3;
      const int koff = (((chunk & 7) ^ (row & 7)) << 3);
      const size_t doff = (size_t)(it * 256 + wid * 64) * 8;
      GLDS16(W2H + (size_t)(m0 + row) * C_ + k0 + koff, &As[0][0] + doff);
      GLDS16(Bb + (size_t)(n0 + row) * C_ + k0 + koff, &Bs[0][0] + doff);
    }
    __syncthreads();
#pragma unroll
    for (int ks = 0; ks < 2; ++ks) {
      const int kc = (((ks << 2) + hi) ^ swz) << 3;
      bf16x8 af[4], bg[4];
#pragma unroll
      for (int i = 0; i < 4; ++i)
        af[i] = *reinterpret_cast<const bf16x8*>(&As[wm * 64 + i * 16 + lc][kc]);
#pragma unroll
      for (int j = 0; j < 4; ++j)
        bg[j] = *reinterpret_cast<const bf16x8*>(&Bs[wn * 64 + j * 16 + lc][kc]);
#pragma unroll
      for (int i = 0; i < 4; ++i)
#pragma unroll
        for (int j = 0; j < 4; ++j)
          acc[i][j] = __builtin_amdgcn_mfma_f32_16x16x32_bf16(af[i], bg[j], acc[i][j], 0, 0, 0);
    }
    __syncthreads();
  }

  float ps[4][4] = {};
  float pq[4][4] = {};
#pragma unroll
  for (int j = 0; j < 4; ++j)
#pragma unroll
    for (int i = 0; i < 4; ++i)
#pragma unroll
      for (int r = 0; r < 4; ++r) {
        const float v = acc[i][j][r];
        ps[i][r] += v;
        pq[i][r] += v * v;
      }
#pragma unroll
  for (int off = 1; off < 16; off <<= 1)
#pragma unroll
    for (int i = 0; i < 4; ++i)
#pragma unroll
      for (int r = 0; r < 4; ++r) {
        ps[i][r] += __shfl_xor(ps[i][r], off);
        pq[i][r] += __shfl_xor(pq[i][r], off);
      }
  if (lc == 0) {
#pragma unroll
    for (int i = 0; i < 4; ++i) {
      const int chl = wm * 64 + i * 16 + hi * 4;
#pragma unroll
      for (int r = 0; r < 4; ++r) {
        atomicAdd(&s_sum[chl + r], ps[i][r]);
        atomicAdd(&s_sq[chl + r], pq[i][r]);
      }
    }
  }
  __syncthreads();
  const int p = b * 64 + blockIdx.y;
  if (tid < 128) {
    psumP[(size_t)p * C_ + m0 + tid] = s_sum[tid];
    psqP[(size_t)p * C_ + m0 + tid] = s_sq[tid];
  }
}

// ---------------------------------------------------------------------------
__global__ __launch_bounds__(256) void bn_finalize2(
    const float* __restrict__ psumP, const float* __restrict__ psqP,
    const float* __restrict__ gamma, const float* __restrict__ beta,
    float* __restrict__ gc, float* __restrict__ oc) {
  const int c = blockIdx.x;
  const int tid = threadIdx.x;
  float s = 0.0f, q = 0.0f;
  for (int p = tid; p < B_ * 64; p += 256) {
    s += psumP[(size_t)p * C_ + c];
    q += psqP[(size_t)p * C_ + c];
  }
  __shared__ float ls[256], lq[256];
  ls[tid] = s;
  lq[tid] = q;
  __syncthreads();
  for (int off = 128; off > 0; off >>= 1) {
    if (tid < off) { ls[tid] += ls[tid + off]; lq[tid] += lq[tid + off]; }
    __syncthreads();
  }
  if (tid == 0) {
    const float inv = 1.0f / ((float)B_ * N_);
    const float mean = ls[0] * inv;
    const float var = lq[0] * inv - mean * mean;
    const float rstd = rsqrtf(var + 1e-5f);
    const float g = gamma[c] * rstd;
    gc[c] = g;
    oc[c] = beta[c] - mean * g;
  }
}

// ---------------------------------------------------------------------------
// conv2 pass 2: x3 + BN + residual -> OUT fp32 (EPF repack, coalesced).
// ---------------------------------------------------------------------------
__global__ __launch_bounds__(256) void conv2_bn(
    const bf16* __restrict__ W2H, const bf16* __restrict__ X2,
    const float* __restrict__ gc, const float* __restrict__ oc,
    const float* __restrict__ Xin, float* __restrict__ OUT) {
  const int b = blockIdx.z;
  const int m0 = blockIdx.x * 128, n0 = blockIdx.y * 128;
  const bf16* __restrict__ Bb = X2 + (size_t)b * N_ * C_;

  __shared__ bf16 SM[2 * 128 * 64];
  bf16* As = SM;
  bf16* Bs = SM + 8192;

  const int tid = threadIdx.x, wid = tid >> 6, lane = tid & 63;
  const int lc = lane & 15, hi = lane >> 4;
  const int wm = wid >> 1, wn = wid & 1;
  const int swz = lc & 7;

  f32x4 acc[4][4] = {};
  for (int k0 = 0; k0 < C_; k0 += 64) {
#pragma unroll
    for (int it = 0; it < 4; ++it) {
      const int chunk = it * 256 + tid;
      const int row = chunk >> 3;
      const int koff = (((chunk & 7) ^ (row & 7)) << 3);
      const size_t doff = (size_t)(it * 256 + wid * 64) * 8;
      GLDS16(W2H + (size_t)(m0 + row) * C_ + k0 + koff, As + doff);
      GLDS16(Bb + (size_t)(n0 + row) * C_ + k0 + koff, Bs + doff);
    }
    __syncthreads();
#pragma unroll
    for (int ks = 0; ks < 2; ++ks) {
      const int kc = (((ks << 2) + hi) ^ swz) << 3;
      bf16x8 af[4], bg[4];
#pragma unroll
      for (int i = 0; i < 4; ++i)
        af[i] = *reinterpret_cast<const bf16x8*>(As + (wm * 64 + i * 16 + lc) * 64 + kc);
#pragma unroll
      for (int j = 0; j < 4; ++j)
        bg[j] = *reinterpret_cast<const bf16x8*>(Bs + (wn * 64 + j * 16 + lc) * 64 + kc);
#pragma unroll
      for (int i = 0; i < 4; ++i)
#pragma unroll
        for (int j = 0; j < 4; ++j)
          acc[i][j] = __builtin_amdgcn_mfma_f32_16x16x32_bf16(af[i], bg[j], acc[i][j], 0, 0, 0);
    }
    __syncthreads();
  }

  float (*EPF)[132] = reinterpret_cast<float(*)[132]>(SM);
  const int rr = tid >> 3, c4 = (tid & 7) << 2;
#pragma unroll
  for (int i = 0; i < 4; ++i) {
    if (i) __syncthreads();
    const int row0 = m0 + wm * 64 + i * 16 + hi * 4;
    const float4 g4 = *reinterpret_cast<const float4*>(&gc[row0]);
    const float4 o4 = *reinterpret_cast<const float4*>(&oc[row0]);
    const float ga[4] = {g4.x, g4.y, g4.z, g4.w};
    const float oa[4] = {o4.x, o4.y, o4.z, o4.w};
#pragma unroll
    for (int j = 0; j < 4; ++j) {
      const int coll = wn * 64 + j * 16 + lc;
#pragma unroll
      for (int r = 0; r < 4; ++r)
        EPF[wm * 16 + hi * 4 + r][coll] = acc[i][j][r] * ga[r] + oa[r];
    }
    __syncthreads();
    const int m = m0 + (rr >> 4) * 64 + i * 16 + (rr & 15);
#pragma unroll
    for (int rep = 0; rep < 4; ++rep) {
      const int col = rep * 32 + c4;
      const size_t off = ((size_t)b * C_ + m) * N_ + n0 + col;
      const float4 xi = *reinterpret_cast<const float4*>(&Xin[off]);
      float4 ov;
      ov.x = EPF[rr][col + 0] + xi.x;
      ov.y = EPF[rr][col + 1] + xi.y;
      ov.z = EPF[rr][col + 2] + xi.z;
      ov.w = EPF[rr][col + 3] + xi.w;
      *reinterpret_cast<float4*>(&OUT[off]) = ov;
    }
  }
}

// ---------------------------------------------------------------------------
extern "C" void kernel_launch(void* const* d_in, const int* in_sizes, int n_in,
                              void* d_out, int out_size, void* d_ws,
                              size_t ws_size, hipStream_t stream) {
  (void)in_sizes; (void)n_in; (void)out_size; (void)ws_size;
  const float* x     = (const float*)d_in[0];
  const float* w1    = (const float*)d_in[1];
  const float* b1    = (const float*)d_in[2];
  const float* mu0   = (const float*)d_in[3];
  const float* w2    = (const float*)d_in[4];
  const float* gamma = (const float*)d_in[5];
  const float* beta  = (const float*)d_in[6];

  // d_out: xs hi/lo planes live here until conv2_bn overwrites with fp32 out.
  bf16* XSH = (bf16*)d_out;
  bf16* XSL = XSH + (size_t)B_ * N_ * C_;
  float* OUT = (float*)d_out;
  float* MUOUT = OUT + (size_t)B_ * C_ * N_;

  // d_ws layout. MUACCP (16 chunk-partials, 33.6 MB) is EM-phase only;
  // psumP/psqP (conv2 phase) alias the same region (disjoint lifetimes).
  bf16* X2b = (bf16*)d_ws;                          // B*N*C
  bf16* ZH  = X2b + (size_t)B_ * N_ * C_;           // B*N*K
  bf16* ZL  = ZH + (size_t)B_ * N_ * K_;
  bf16* W1H = ZL + (size_t)B_ * N_ * K_;
  bf16* W1L = W1H + C_ * C_;
  bf16* W2H = W1L + C_ * C_;
  bf16* W2L = W2H + C_ * C_;
  bf16* MT0H = W2L + C_ * C_;                       // K*C
  bf16* MT0L = MT0H + K_ * C_;
  bf16* MUTH = MT0L + K_ * C_;                      // B*K*C
  bf16* MUTL = MUTH + (size_t)B_ * K_ * C_;
  bf16* MUH  = MUTL + (size_t)B_ * K_ * C_;         // B*C*K
  float* MUACCP = (float*)(MUH + (size_t)B_ * C_ * K_);  // NCHK*B*C*K (33.6MB)
  float* psumP = MUACCP;                            // alias (conv2 phase)
  float* psqP  = psumP + (size_t)B_ * 64 * C_;      // 1024*C
  float* colsum = MUACCP + (size_t)NCHK * B_ * C_ * K_;  // B*K
  float* gcp = colsum + B_ * K_;                    // C
  float* ocp = gcp + C_;                            // C

  const dim3 blk(256);

  cast_w_split<<<dim3(C_ * C_ / 256), blk, 0, stream>>>(w1, W1H, W1L);
  cast_w_split<<<dim3(C_ * C_ / 256), blk, 0, stream>>>(w2, W2H, W2L);
  cast_mu0T_split<<<dim3(K_), blk, 0, stream>>>(mu0, MT0H, MT0L);

  // conv1 with fused transpose + register prefetch, all 16 batches
  conv1_fused<<<dim3(N_ / 128, C_ / 128, B_), blk, 0, stream>>>(
      x, W1H, W1L, b1, XSH, XSL);

  // EM: grouped by batches so xs hi/lo (134 MB/group) stays L3-resident
  for (int g = 0; g < B_ / BGRP; ++g) {
    const int boff = g * BGRP;
    for (int it = 0; it < 3; ++it) {
      hipMemsetAsync(colsum + boff * K_, 0, BGRP * K_ * sizeof(float), stream);
      estep_split<<<dim3(N_ / 128, BGRP), blk, 0, stream>>>(
          XSH, XSL, it == 0 ? MT0H : MUTH, it == 0 ? MT0L : MUTL,
          it == 0 ? 0 : (size_t)K_ * C_, ZH, ZL, colsum, boff);
      mstep_split<<<dim3(NCHK, C_ / 128, BGRP), dim3(128), 0, stream>>>(
          XSH, XSL, ZH, ZL, MUACCP, boff);
      finalize_mu<<<dim3(BGRP * C_ * K_ / 256), blk, 0, stream>>>(
          MUACCP, colsum, MUTH, MUTL, MUH, it == 2 ? MUOUT : nullptr,
          boff * C_ * K_);
    }
  }

  x2_plain<<<dim3(N_ / 128, C_ / 128, B_), blk, 0, stream>>>(ZH, MUH, X2b);
  conv2_stats<<<dim3(C_ / 128, N_ / 128, B_), blk, 0, stream>>>(
      W2H, X2b, psumP, psqP);
  bn_finalize2<<<dim3(C_), blk, 0, stream>>>(psumP, psqP, gamma, beta, gcp, ocp);
  conv2_bn<<<dim3(C_ / 128, N_ / 128, B_), blk, 0, stream>>>(
      W2H, X2b, gcp, ocp, x, OUT);
}

// Round 16
// 1053.934 us; speedup vs baseline: 1.1393x; 1.0099x over previous
//
#include <hip/hip_runtime.h>
#include <math.h>

constexpr int B_ = 16, C_ = 512, K_ = 64, N_ = 8192;
constexpr int BGRP = 8;       // EM batch group size (L3 residency)
constexpr int MCHUNK = 512;   // mstep n-chunk
constexpr int NCHK = N_ / MCHUNK;  // 16 partial slabs

typedef __bf16 bf16;
typedef __bf16 bf16x4 __attribute__((ext_vector_type(4)));
typedef __bf16 bf16x8 __attribute__((ext_vector_type(8)));
typedef float f32x4 __attribute__((ext_vector_type(4)));

#define GLDS16(gp, lp)                                              \
  __builtin_amdgcn_global_load_lds(                                 \
      (const __attribute__((address_space(1))) unsigned int*)(gp),  \
      (__attribute__((address_space(3))) unsigned int*)(lp), 16, 0, 0)

__device__ __forceinline__ bf16 lo_part(float v, bf16 h) {
  return (bf16)(v - (float)h);
}

__global__ void cast_w_split(const float* __restrict__ W, bf16* __restrict__ H,
                             bf16* __restrict__ L) {
  const int i = blockIdx.x * 256 + threadIdx.x;
  const float v = W[i];
  const bf16 h = (bf16)v;
  H[i] = h;
  L[i] = lo_part(v, h);
}

__global__ void cast_mu0T_split(const float* __restrict__ MU0,
                                bf16* __restrict__ H, bf16* __restrict__ L) {
  const int k = blockIdx.x;
  for (int c = threadIdx.x; c < C_; c += 256) {
    const float v = MU0[c * K_ + k];
    const bf16 h = (bf16)v;
    H[k * C_ + c] = h;
    L[k * C_ + c] = lo_part(v, h);
  }
}

// ---------------------------------------------------------------------------
// conv1 FUSED transpose v4: xs_NC = x^T . w1^T + b1, split-bf16 3-pass MFMA.
// A: transposed-gather -> registers issued early (T14); truncation hi/lo
// split. B via GLDS16 + granule swizzle.
// ---------------------------------------------------------------------------
#define LOADREGS(cb32, xr)                                              \
  {                                                                     \
    _Pragma("unroll") for (int g = 0; g < 2; ++g) {                     \
      const int cg = cvg + g * 2;                                       \
      const int cbase = (cb32) + cg * 8;                                \
      _Pragma("unroll") for (int e = 0; e < 8; ++e)                     \
          xr[g * 8 + e] = Xb[(size_t)(cbase + e) * N_ + m0 + cvn];      \
    }                                                                   \
  }

#define STAGEREGS(xr)                                                   \
  {                                                                     \
    _Pragma("unroll") for (int g = 0; g < 2; ++g) {                     \
      const int cg = cvg + g * 2;                                       \
      bf16x8 vh, vl;                                                    \
      _Pragma("unroll") for (int e = 0; e < 8; ++e) {                   \
        const float v = xr[g * 8 + e];                                  \
        const unsigned u = __builtin_bit_cast(unsigned, v);             \
        vh[e] = __builtin_bit_cast(bf16, (unsigned short)(u >> 16));    \
        const float hf = __builtin_bit_cast(float, u & 0xffff0000u);    \
        vl[e] = (bf16)(v - hf);                                         \
      }                                                                 \
      *reinterpret_cast<bf16x8*>(&Ah[cvn][cg * 8]) = vh;                \
      *reinterpret_cast<bf16x8*>(&Al[cvn][cg * 8]) = vl;                \
    }                                                                   \
  }

#define MFMASUB(sub)                                                        \
  {                                                                         \
    bf16x8 ah[4], al4[4], bh[4], bl4[4];                                    \
    const int kc = ((((sub) << 2) + hi) ^ swz) << 3;                        \
    _Pragma("unroll") for (int i = 0; i < 4; ++i) {                         \
      const int arow = wm * 64 + i * 16 + lc;                               \
      ah[i] = *reinterpret_cast<const bf16x8*>(&Ah[arow][hi * 8]);          \
      al4[i] = *reinterpret_cast<const bf16x8*>(&Al[arow][hi * 8]);         \
    }                                                                       \
    _Pragma("unroll") for (int j = 0; j < 4; ++j) {                         \
      bh[j] = *reinterpret_cast<const bf16x8*>(                             \
          Bh + (wn * 64 + j * 16 + lc) * 64 + kc);                          \
      bl4[j] = *reinterpret_cast<const bf16x8*>(                            \
          Bl + (wn * 64 + j * 16 + lc) * 64 + kc);                          \
    }                                                                       \
    _Pragma("unroll") for (int i = 0; i < 4; ++i)                           \
        _Pragma("unroll") for (int j = 0; j < 4; ++j) {                     \
      acc[i][j] =                                                           \
          __builtin_amdgcn_mfma_f32_16x16x32_bf16(al4[i], bh[j], acc[i][j], 0, 0, 0); \
      acc[i][j] =                                                           \
          __builtin_amdgcn_mfma_f32_16x16x32_bf16(ah[i], bl4[j], acc[i][j], 0, 0, 0); \
      acc[i][j] =                                                           \
          __builtin_amdgcn_mfma_f32_16x16x32_bf16(ah[i], bh[j], acc[i][j], 0, 0, 0); \
    }                                                                       \
  }

__global__ __launch_bounds__(256) void conv1_fused(
    const float* __restrict__ X, const bf16* __restrict__ W1H,
    const bf16* __restrict__ W1L, const float* __restrict__ bias,
    bf16* __restrict__ XSH, bf16* __restrict__ XSL) {
  const int bz = blockIdx.z;
  const int m0 = blockIdx.x * 128;  // n rows
  const int n0 = blockIdx.y * 128;  // o cols
  const float* __restrict__ Xb = X + (size_t)bz * C_ * N_;

  __shared__ bf16 Ah[128][40], Al[128][40];  // 10.25 KB each (ld=40: 2-way)
  __shared__ bf16 Bbuf[2 * 128 * 64];        // 32 KB: Bh | Bl ; reused as EP
  bf16* Bh = Bbuf;
  bf16* Bl = Bbuf + 8192;

  const int tid = threadIdx.x, wid = tid >> 6, lane = tid & 63;
  const int lc = lane & 15, hi = lane >> 4;
  const int wm = wid >> 1, wn = wid & 1;
  const int swz = lc & 7;
  const int cvn = tid & 127;   // conversion: n row
  const int cvg = tid >> 7;    // conversion: c-granule base (0..1; +2 via g)

  f32x4 acc[4][4] = {};
  float xa[16], xb[16];

  LOADREGS(0, xa);  // prologue: regs for (k0=0, sub=0)

  for (int k0 = 0; k0 < C_; k0 += 64) {
    // stage B (w1 hi/lo) for this 64-c chunk
#pragma unroll
    for (int it = 0; it < 4; ++it) {
      const int chunk = it * 256 + tid;
      const int row = chunk >> 3;
      const int koff = (((chunk & 7) ^ (row & 7)) << 3);
      const size_t doff = (size_t)(it * 256 + wid * 64) * 8;
      GLDS16(W1H + (size_t)(n0 + row) * C_ + k0 + koff, Bh + doff);
      GLDS16(W1L + (size_t)(n0 + row) * C_ + k0 + koff, Bl + doff);
    }
    // sub 0
    STAGEREGS(xa);
    __syncthreads();           // A(sub0) + B staged
    LOADREGS(k0 + 32, xb);     // issue sub1 loads; latency hides under MFMA
    MFMASUB(0);
    __syncthreads();
    // sub 1
    STAGEREGS(xb);
    __syncthreads();           // A(sub1) staged
    if (k0 < C_ - 64) LOADREGS(k0 + 64, xa);  // prefetch next k0 sub0
    MFMASUB(1);
    __syncthreads();
  }

  // epilogue: EP repack (B region dead), coalesced bf16x8 stores
  bf16 (*EP)[128] = reinterpret_cast<bf16(*)[128]>(Bbuf);
  const int rr = tid >> 4, c8 = (tid & 15) << 3;
#pragma unroll
  for (int plane = 0; plane < 2; ++plane) {
    if (plane) __syncthreads();
#pragma unroll
    for (int j = 0; j < 4; ++j) {
      const int coll = wn * 64 + j * 16 + lc;
      const float bv = bias[n0 + coll];
#pragma unroll
      for (int i = 0; i < 4; ++i) {
        const int rowl = wm * 64 + i * 16 + hi * 4;
#pragma unroll
        for (int r = 0; r < 4; ++r) {
          const float v = acc[i][j][r] + bv;
          const bf16 h = (bf16)v;
          EP[rowl + r][coll] = plane ? lo_part(v, h) : h;
        }
      }
    }
    __syncthreads();
    bf16* DST = plane ? XSL : XSH;
#pragma unroll
    for (int rep = 0; rep < 8; ++rep) {
      const int row = rep * 16 + rr;
      *reinterpret_cast<bf16x8*>(&DST[((size_t)bz * N_ + m0 + row) * C_ + n0 + c8]) =
          *reinterpret_cast<const bf16x8*>(&EP[row][c8]);
    }
  }
}

// ---------------------------------------------------------------------------
// E-step: logits = xs . mu^T (split 3-pass), fp32 softmax over K=64.
// ---------------------------------------------------------------------------
__global__ __launch_bounds__(256) void estep_split(
    const bf16* __restrict__ XSH, const bf16* __restrict__ XSL,
    const bf16* __restrict__ MTH, const bf16* __restrict__ MTL,
    size_t mustride, bf16* __restrict__ ZH, bf16* __restrict__ ZL,
    float* __restrict__ colsum, int b_base) {
  const int b = b_base + blockIdx.y;
  const int m0 = blockIdx.x * 128;
  const bf16* __restrict__ AHp = XSH + (size_t)b * N_ * C_;
  const bf16* __restrict__ ALp = XSL + (size_t)b * N_ * C_;
  const bf16* __restrict__ BHp = MTH + (size_t)b * mustride;
  const bf16* __restrict__ BLp = MTL + (size_t)b * mustride;

  __shared__ bf16 Ah[128][64], Al[128][64], Bh[64][64], Bl[64][64];
  __shared__ float cs[64];

  const int tid = threadIdx.x, wid = tid >> 6, lane = tid & 63;
  const int lc = lane & 15, hi = lane >> 4;
  const int swz = lc & 7;
  if (tid < 64) cs[tid] = 0.0f;

  f32x4 acc[2][4] = {};
  for (int k0 = 0; k0 < C_; k0 += 64) {
#pragma unroll
    for (int it = 0; it < 4; ++it) {
      const int chunk = it * 256 + tid;
      const int row = chunk >> 3;
      const int koff = (((chunk & 7) ^ (row & 7)) << 3);
      const size_t doff = (size_t)(it * 256 + wid * 64) * 8;
      GLDS16(AHp + (size_t)(m0 + row) * C_ + k0 + koff, &Ah[0][0] + doff);
      GLDS16(ALp + (size_t)(m0 + row) * C_ + k0 + koff, &Al[0][0] + doff);
    }
#pragma unroll
    for (int it = 0; it < 2; ++it) {
      const int chunk = it * 256 + tid;
      const int row = chunk >> 3;
      const int koff = (((chunk & 7) ^ (row & 7)) << 3);
      const size_t doff = (size_t)(it * 256 + wid * 64) * 8;
      GLDS16(BHp + (size_t)row * C_ + k0 + koff, &Bh[0][0] + doff);
      GLDS16(BLp + (size_t)row * C_ + k0 + koff, &Bl[0][0] + doff);
    }
    __syncthreads();
#pragma unroll
    for (int ks = 0; ks < 2; ++ks) {
      const int kc = (((ks << 2) + hi) ^ swz) << 3;
      bf16x8 ah[2], al4[2], bh[4], bl4[4];
#pragma unroll
      for (int i = 0; i < 2; ++i) {
        ah[i] = *reinterpret_cast<const bf16x8*>(&Ah[wid * 32 + i * 16 + lc][kc]);
        al4[i] = *reinterpret_cast<const bf16x8*>(&Al[wid * 32 + i * 16 + lc][kc]);
      }
#pragma unroll
      for (int j = 0; j < 4; ++j) {
        bh[j] = *reinterpret_cast<const bf16x8*>(&Bh[j * 16 + lc][kc]);
        bl4[j] = *reinterpret_cast<const bf16x8*>(&Bl[j * 16 + lc][kc]);
      }
#pragma unroll
      for (int i = 0; i < 2; ++i)
#pragma unroll
        for (int j = 0; j < 4; ++j) {
          acc[i][j] = __builtin_amdgcn_mfma_f32_16x16x32_bf16(al4[i], bh[j], acc[i][j], 0, 0, 0);
          acc[i][j] = __builtin_amdgcn_mfma_f32_16x16x32_bf16(ah[i], bl4[j], acc[i][j], 0, 0, 0);
          acc[i][j] = __builtin_amdgcn_mfma_f32_16x16x32_bf16(ah[i], bh[j], acc[i][j], 0, 0, 0);
        }
    }
    __syncthreads();
  }

  float cp[4] = {0.f, 0.f, 0.f, 0.f};
#pragma unroll
  for (int i = 0; i < 2; ++i) {
#pragma unroll
    for (int r = 0; r < 4; ++r) {
      float v0 = acc[i][0][r], v1 = acc[i][1][r], v2 = acc[i][2][r], v3 = acc[i][3][r];
      float mx = fmaxf(fmaxf(v0, v1), fmaxf(v2, v3));
#pragma unroll
      for (int off = 1; off < 16; off <<= 1) mx = fmaxf(mx, __shfl_xor(mx, off));
      float p0 = __expf(v0 - mx), p1 = __expf(v1 - mx);
      float p2 = __expf(v2 - mx), p3 = __expf(v3 - mx);
      float s = p0 + p1 + p2 + p3;
#pragma unroll
      for (int off = 1; off < 16; off <<= 1) s += __shfl_xor(s, off);
      const float inv = 1.0f / s;
      p0 *= inv; p1 *= inv; p2 *= inv; p3 *= inv;
      const int n = m0 + wid * 32 + i * 16 + hi * 4 + r;
      bf16* zh = ZH + ((size_t)b * N_ + n) * K_;
      bf16* zl = ZL + ((size_t)b * N_ + n) * K_;
      const float pv[4] = {p0, p1, p2, p3};
#pragma unroll
      for (int j = 0; j < 4; ++j) {
        const bf16 h = (bf16)pv[j];
        zh[j * 16 + lc] = h;
        zl[j * 16 + lc] = lo_part(pv[j], h);
        cp[j] += pv[j];
      }
    }
  }
#pragma unroll
  for (int j = 0; j < 4; ++j) atomicAdd(&cs[j * 16 + lc], cp[j]);
  __syncthreads();
  if (tid < 64) atomicAdd(&colsum[b * K_ + tid], cs[tid]);
}

// ---------------------------------------------------------------------------
// M-step v3: partials MUACCP[chunk][b][c][k], FULL 3-pass (xs hi/lo + z hi/lo;
// r15 proved xs-lo is precision-critical too), 256 threads (4 waves x 32 c).
// ---------------------------------------------------------------------------
__global__ __launch_bounds__(256) void mstep_split(
    const bf16* __restrict__ XSH, const bf16* __restrict__ XSL,
    const bf16* __restrict__ ZHp, const bf16* __restrict__ ZLp,
    float* __restrict__ MUACCP, int b_base) {
  const int b = b_base + blockIdx.z;
  const int c0 = blockIdx.y * 128;
  const int p = blockIdx.x;
  const int nbase = p * MCHUNK;
  const bf16* __restrict__ XbH = XSH + (size_t)b * N_ * C_;
  const bf16* __restrict__ XbL = XSL + (size_t)b * N_ * C_;
  const bf16* __restrict__ ZbH = ZHp + (size_t)b * N_ * K_;
  const bf16* __restrict__ ZbL = ZLp + (size_t)b * N_ * K_;

  __shared__ bf16 Ah[128][40], Al[128][40], Bh[64][40], Bl[64][40];

  const int tid = threadIdx.x, wid = tid >> 6, lane = tid & 63;
  const int lc = lane & 15, hi = lane >> 4;

  f32x4 acc[2][4] = {};
  for (int n0 = nbase; n0 < nbase + MCHUNK; n0 += 32) {
    // A (xs hi+lo): 128 c x 32 n = 512 chunks of 8; 256 threads x 2 its/plane
#pragma unroll
    for (int it = 0; it < 2; ++it) {
      const int chunk = it * 256 + tid;
      const int nn = chunk & 31, c8 = (chunk >> 5) * 8;
      const bf16x8 vh = *reinterpret_cast<const bf16x8*>(
          &XbH[(size_t)(n0 + nn) * C_ + c0 + c8]);
      const bf16x8 vl = *reinterpret_cast<const bf16x8*>(
          &XbL[(size_t)(n0 + nn) * C_ + c0 + c8]);
#pragma unroll
      for (int e = 0; e < 8; ++e) {
        Ah[c8 + e][nn] = vh[e];
        Al[c8 + e][nn] = vl[e];
      }
    }
    // B (z hi/lo): 64 k x 32 n = 256 chunks; 1 it, both planes
    {
      const int nn = tid & 31, k8 = (tid >> 5) * 8;
      const bf16x8 vh = *reinterpret_cast<const bf16x8*>(
          &ZbH[(size_t)(n0 + nn) * K_ + k8]);
      const bf16x8 vl = *reinterpret_cast<const bf16x8*>(
          &ZbL[(size_t)(n0 + nn) * K_ + k8]);
#pragma unroll
      for (int e = 0; e < 8; ++e) {
        Bh[k8 + e][nn] = vh[e];
        Bl[k8 + e][nn] = vl[e];
      }
    }
    __syncthreads();
    bf16x8 ah[2], al4[2], bh[4], bl4[4];
#pragma unroll
    for (int i = 0; i < 2; ++i) {
      ah[i] = *reinterpret_cast<const bf16x8*>(&Ah[wid * 32 + i * 16 + lc][hi * 8]);
      al4[i] = *reinterpret_cast<const bf16x8*>(&Al[wid * 32 + i * 16 + lc][hi * 8]);
    }
#pragma unroll
    for (int j = 0; j < 4; ++j) {
      bh[j] = *reinterpret_cast<const bf16x8*>(&Bh[j * 16 + lc][hi * 8]);
      bl4[j] = *reinterpret_cast<const bf16x8*>(&Bl[j * 16 + lc][hi * 8]);
    }
#pragma unroll
    for (int i = 0; i < 2; ++i)
#pragma unroll
      for (int j = 0; j < 4; ++j) {
        acc[i][j] = __builtin_amdgcn_mfma_f32_16x16x32_bf16(al4[i], bh[j], acc[i][j], 0, 0, 0);
        acc[i][j] = __builtin_amdgcn_mfma_f32_16x16x32_bf16(ah[i], bl4[j], acc[i][j], 0, 0, 0);
        acc[i][j] = __builtin_amdgcn_mfma_f32_16x16x32_bf16(ah[i], bh[j], acc[i][j], 0, 0, 0);
      }
    __syncthreads();
  }
  float* slab = MUACCP + (((size_t)p * B_ + b) * C_) * K_;
#pragma unroll
  for (int i = 0; i < 2; ++i) {
    const int c = c0 + wid * 32 + i * 16 + hi * 4;
#pragma unroll
    for (int r = 0; r < 4; ++r)
#pragma unroll
      for (int j = 0; j < 4; ++j)
        slab[(size_t)(c + r) * K_ + j * 16 + lc] = acc[i][j][r];
  }
}

// ---------------------------------------------------------------------------
// finalize mu: reduce 16 chunk-partials, scale by 1/(1e-6+colsum).
// ---------------------------------------------------------------------------
__global__ void finalize_mu(const float* __restrict__ MUACCP,
                            const float* __restrict__ colsum,
                            bf16* __restrict__ MUTH, bf16* __restrict__ MUTL,
                            bf16* __restrict__ MUH, float* __restrict__ muout,
                            int idx_base) {
  const int idx = idx_base + blockIdx.x * 256 + threadIdx.x;
  const int k = idx & (K_ - 1);
  const int c = (idx >> 6) & (C_ - 1);
  const int b = idx >> 15;
  float acc = 0.0f;
#pragma unroll
  for (int p = 0; p < NCHK; ++p)
    acc += MUACCP[(size_t)p * B_ * C_ * K_ + idx];
  const float v = acc / (1e-6f + colsum[b * K_ + k]);
  const bf16 h = (bf16)v;
  MUH[idx] = h;
  MUTH[((size_t)b * K_ + k) * C_ + c] = h;
  MUTL[((size_t)b * K_ + k) * C_ + c] = lo_part(v, h);
  if (muout) muout[idx] = v;
}

// ---------------------------------------------------------------------------
// x2_NC = relu(z . mu^T), plain bf16, single K=64 tile. EP repack epilogue.
// ---------------------------------------------------------------------------
__global__ __launch_bounds__(256) void x2_plain(
    const bf16* __restrict__ ZHp, const bf16* __restrict__ MUHp,
    bf16* __restrict__ X2) {
  const int b = blockIdx.z;
  const int m0 = blockIdx.x * 128, n0 = blockIdx.y * 128;
  const bf16* __restrict__ Ab = ZHp + (size_t)b * N_ * K_;
  const bf16* __restrict__ Bb = MUHp + (size_t)b * C_ * K_;

  __shared__ bf16 SM[2 * 128 * 64];
  bf16* As = SM;
  bf16* Bs = SM + 8192;

  const int tid = threadIdx.x, wid = tid >> 6, lane = tid & 63;
  const int lc = lane & 15, hi = lane >> 4;
  const int wm = wid >> 1, wn = wid & 1;
  const int swz = lc & 7;

  f32x4 acc[4][4] = {};
#pragma unroll
  for (int it = 0; it < 4; ++it) {
    const int chunk = it * 256 + tid;
    const int row = chunk >> 3;
    const int koff = (((chunk & 7) ^ (row & 7)) << 3);
    const size_t doff = (size_t)(it * 256 + wid * 64) * 8;
    GLDS16(Ab + (size_t)(m0 + row) * K_ + koff, As + doff);
    GLDS16(Bb + (size_t)(n0 + row) * K_ + koff, Bs + doff);
  }
  __syncthreads();
#pragma unroll
  for (int ks = 0; ks < 2; ++ks) {
    const int kc = (((ks << 2) + hi) ^ swz) << 3;
    bf16x8 af[4], bg[4];
#pragma unroll
    for (int i = 0; i < 4; ++i)
      af[i] = *reinterpret_cast<const bf16x8*>(As + (wm * 64 + i * 16 + lc) * 64 + kc);
#pragma unroll
    for (int j = 0; j < 4; ++j)
      bg[j] = *reinterpret_cast<const bf16x8*>(Bs + (wn * 64 + j * 16 + lc) * 64 + kc);
#pragma unroll
    for (int i = 0; i < 4; ++i)
#pragma unroll
      for (int j = 0; j < 4; ++j)
        acc[i][j] = __builtin_amdgcn_mfma_f32_16x16x32_bf16(af[i], bg[j], acc[i][j], 0, 0, 0);
  }
  __syncthreads();

  bf16 (*EP)[128] = reinterpret_cast<bf16(*)[128]>(SM);
#pragma unroll
  for (int j = 0; j < 4; ++j) {
    const int coll = wn * 64 + j * 16 + lc;
#pragma unroll
    for (int i = 0; i < 4; ++i) {
      const int rowl = wm * 64 + i * 16 + hi * 4;
#pragma unroll
      for (int r = 0; r < 4; ++r)
        EP[rowl + r][coll] = (bf16)fmaxf(acc[i][j][r], 0.0f);
    }
  }
  __syncthreads();
  const int rr = tid >> 4, c8 = (tid & 15) << 3;
#pragma unroll
  for (int rep = 0; rep < 8; ++rep) {
    const int row = rep * 16 + rr;
    *reinterpret_cast<bf16x8*>(&X2[((size_t)b * N_ + m0 + row) * C_ + n0 + c8]) =
        *reinterpret_cast<const bf16x8*>(&EP[row][c8]);
  }
}

// ---------------------------------------------------------------------------
// conv2 pass 1: x3 tiles -> per-channel sum/sumsq non-atomic partials.
// ---------------------------------------------------------------------------
__global__ __launch_bounds__(256) void conv2_stats(
    const bf16* __restrict__ W2H, const bf16* __restrict__ X2,
    float* __restrict__ psumP, float* __restrict__ psqP) {
  const int b = blockIdx.z;
  const int m0 = blockIdx.x * 128, n0 = blockIdx.y * 128;
  const bf16* __restrict__ Bb = X2 + (size_t)b * N_ * C_;

  __shared__ bf16 As[128][64], Bs[128][64];
  __shared__ float s_sum[128], s_sq[128];

  const int tid = threadIdx.x, wid = tid >> 6, lane = tid & 63;
  const int lc = lane & 15, hi = lane >> 4;
  const int wm = wid >> 1, wn = wid & 1;
  const int swz = lc & 7;
  if (tid < 128) { s_sum[tid] = 0.0f; s_sq[tid] = 0.0f; }

  f32x4 acc[4][4] = {};
  for (int k0 = 0; k0 < C_; k0 += 64) {
#pragma unroll
    for (int it = 0; it < 4; ++it) {
      const int chunk = it * 256 + tid;
      const int row = chunk >> 3;
      const int koff = (((chunk & 7) ^ (row & 7)) << 3);
      const size_t doff = (size_t)(it * 256 + wid * 64) * 8;
      GLDS16(W2H + (size_t)(m0 + row) * C_ + k0 + koff, &As[0][0] + doff);
      GLDS16(Bb + (size_t)(n0 + row) * C_ + k0 + koff, &Bs[0][0] + doff);
    }
    __syncthreads();
#pragma unroll
    for (int ks = 0; ks < 2; ++ks) {
      const int kc = (((ks << 2) + hi) ^ swz) << 3;
      bf16x8 af[4], bg[4];
#pragma unroll
      for (int i = 0; i < 4; ++i)
        af[i] = *reinterpret_cast<const bf16x8*>(&As[wm * 64 + i * 16 + lc][kc]);
#pragma unroll
      for (int j = 0; j < 4; ++j)
        bg[j] = *reinterpret_cast<const bf16x8*>(&Bs[wn * 64 + j * 16 + lc][kc]);
#pragma unroll
      for (int i = 0; i < 4; ++i)
#pragma unroll
        for (int j = 0; j < 4; ++j)
          acc[i][j] = __builtin_amdgcn_mfma_f32_16x16x32_bf16(af[i], bg[j], acc[i][j], 0, 0, 0);
    }
    __syncthreads();
  }

  float ps[4][4] = {};
  float pq[4][4] = {};
#pragma unroll
  for (int j = 0; j < 4; ++j)
#pragma unroll
    for (int i = 0; i < 4; ++i)
#pragma unroll
      for (int r = 0; r < 4; ++r) {
        const float v = acc[i][j][r];
        ps[i][r] += v;
        pq[i][r] += v * v;
      }
#pragma unroll
  for (int off = 1; off < 16; off <<= 1)
#pragma unroll
    for (int i = 0; i < 4; ++i)
#pragma unroll
      for (int r = 0; r < 4; ++r) {
        ps[i][r] += __shfl_xor(ps[i][r], off);
        pq[i][r] += __shfl_xor(pq[i][r], off);
      }
  if (lc == 0) {
#pragma unroll
    for (int i = 0; i < 4; ++i) {
      const int chl = wm * 64 + i * 16 + hi * 4;
#pragma unroll
      for (int r = 0; r < 4; ++r) {
        atomicAdd(&s_sum[chl + r], ps[i][r]);
        atomicAdd(&s_sq[chl + r], pq[i][r]);
      }
    }
  }
  __syncthreads();
  const int p = b * 64 + blockIdx.y;
  if (tid < 128) {
    psumP[(size_t)p * C_ + m0 + tid] = s_sum[tid];
    psqP[(size_t)p * C_ + m0 + tid] = s_sq[tid];
  }
}

// ---------------------------------------------------------------------------
__global__ __launch_bounds__(256) void bn_finalize2(
    const float* __restrict__ psumP, const float* __restrict__ psqP,
    const float* __restrict__ gamma, const float* __restrict__ beta,
    float* __restrict__ gc, float* __restrict__ oc) {
  const int c = blockIdx.x;
  const int tid = threadIdx.x;
  float s = 0.0f, q = 0.0f;
  for (int p = tid; p < B_ * 64; p += 256) {
    s += psumP[(size_t)p * C_ + c];
    q += psqP[(size_t)p * C_ + c];
  }
  __shared__ float ls[256], lq[256];
  ls[tid] = s;
  lq[tid] = q;
  __syncthreads();
  for (int off = 128; off > 0; off >>= 1) {
    if (tid < off) { ls[tid] += ls[tid + off]; lq[tid] += lq[tid + off]; }
    __syncthreads();
  }
  if (tid == 0) {
    const float inv = 1.0f / ((float)B_ * N_);
    const float mean = ls[0] * inv;
    const float var = lq[0] * inv - mean * mean;
    const float rstd = rsqrtf(var + 1e-5f);
    const float g = gamma[c] * rstd;
    gc[c] = g;
    oc[c] = beta[c] - mean * g;
  }
}

// ---------------------------------------------------------------------------
// conv2 pass 2: x3 + BN + residual -> OUT fp32 (EPF repack, coalesced).
// ---------------------------------------------------------------------------
__global__ __launch_bounds__(256) void conv2_bn(
    const bf16* __restrict__ W2H, const bf16* __restrict__ X2,
    const float* __restrict__ gc, const float* __restrict__ oc,
    const float* __restrict__ Xin, float* __restrict__ OUT) {
  const int b = blockIdx.z;
  const int m0 = blockIdx.x * 128, n0 = blockIdx.y * 128;
  const bf16* __restrict__ Bb = X2 + (size_t)b * N_ * C_;

  __shared__ bf16 SM[2 * 128 * 64];
  bf16* As = SM;
  bf16* Bs = SM + 8192;

  const int tid = threadIdx.x, wid = tid >> 6, lane = tid & 63;
  const int lc = lane & 15, hi = lane >> 4;
  const int wm = wid >> 1, wn = wid & 1;
  const int swz = lc & 7;

  f32x4 acc[4][4] = {};
  for (int k0 = 0; k0 < C_; k0 += 64) {
#pragma unroll
    for (int it = 0; it < 4; ++it) {
      const int chunk = it * 256 + tid;
      const int row = chunk >> 3;
      const int koff = (((chunk & 7) ^ (row & 7)) << 3);
      const size_t doff = (size_t)(it * 256 + wid * 64) * 8;
      GLDS16(W2H + (size_t)(m0 + row) * C_ + k0 + koff, As + doff);
      GLDS16(Bb + (size_t)(n0 + row) * C_ + k0 + koff, Bs + doff);
    }
    __syncthreads();
#pragma unroll
    for (int ks = 0; ks < 2; ++ks) {
      const int kc = (((ks << 2) + hi) ^ swz) << 3;
      bf16x8 af[4], bg[4];
#pragma unroll
      for (int i = 0; i < 4; ++i)
        af[i] = *reinterpret_cast<const bf16x8*>(As + (wm * 64 + i * 16 + lc) * 64 + kc);
#pragma unroll
      for (int j = 0; j < 4; ++j)
        bg[j] = *reinterpret_cast<const bf16x8*>(Bs + (wn * 64 + j * 16 + lc) * 64 + kc);
#pragma unroll
      for (int i = 0; i < 4; ++i)
#pragma unroll
        for (int j = 0; j < 4; ++j)
          acc[i][j] = __builtin_amdgcn_mfma_f32_16x16x32_bf16(af[i], bg[j], acc[i][j], 0, 0, 0);
    }
    __syncthreads();
  }

  float (*EPF)[132] = reinterpret_cast<float(*)[132]>(SM);
  const int rr = tid >> 3, c4 = (tid & 7) << 2;
#pragma unroll
  for (int i = 0; i < 4; ++i) {
    if (i) __syncthreads();
    const int row0 = m0 + wm * 64 + i * 16 + hi * 4;
    const float4 g4 = *reinterpret_cast<const float4*>(&gc[row0]);
    const float4 o4 = *reinterpret_cast<const float4*>(&oc[row0]);
    const float ga[4] = {g4.x, g4.y, g4.z, g4.w};
    const float oa[4] = {o4.x, o4.y, o4.z, o4.w};
#pragma unroll
    for (int j = 0; j < 4; ++j) {
      const int coll = wn * 64 + j * 16 + lc;
#pragma unroll
      for (int r = 0; r < 4; ++r)
        EPF[wm * 16 + hi * 4 + r][coll] = acc[i][j][r] * ga[r] + oa[r];
    }
    __syncthreads();
    const int m = m0 + (rr >> 4) * 64 + i * 16 + (rr & 15);
#pragma unroll
    for (int rep = 0; rep < 4; ++rep) {
      const int col = rep * 32 + c4;
      const size_t off = ((size_t)b * C_ + m) * N_ + n0 + col;
      const float4 xi = *reinterpret_cast<const float4*>(&Xin[off]);
      float4 ov;
      ov.x = EPF[rr][col + 0] + xi.x;
      ov.y = EPF[rr][col + 1] + xi.y;
      ov.z = EPF[rr][col + 2] + xi.z;
      ov.w = EPF[rr][col + 3] + xi.w;
      *reinterpret_cast<float4*>(&OUT[off]) = ov;
    }
  }
}

// ---------------------------------------------------------------------------
extern "C" void kernel_launch(void* const* d_in, const int* in_sizes, int n_in,
                              void* d_out, int out_size, void* d_ws,
                              size_t ws_size, hipStream_t stream) {
  (void)in_sizes; (void)n_in; (void)out_size; (void)ws_size;
  const float* x     = (const float*)d_in[0];
  const float* w1    = (const float*)d_in[1];
  const float* b1    = (const float*)d_in[2];
  const float* mu0   = (const float*)d_in[3];
  const float* w2    = (const float*)d_in[4];
  const float* gamma = (const float*)d_in[5];
  const float* beta  = (const float*)d_in[6];

  // d_out: xs hi/lo planes live here until conv2_bn overwrites with fp32 out.
  bf16* XSH = (bf16*)d_out;
  bf16* XSL = XSH + (size_t)B_ * N_ * C_;
  float* OUT = (float*)d_out;
  float* MUOUT = OUT + (size_t)B_ * C_ * N_;

  // d_ws layout. MUACCP (16 chunk-partials, 33.6 MB) is EM-phase only;
  // psumP/psqP (conv2 phase) alias the same region (disjoint lifetimes).
  bf16* X2b = (bf16*)d_ws;                          // B*N*C
  bf16* ZH  = X2b + (size_t)B_ * N_ * C_;           // B*N*K
  bf16* ZL  = ZH + (size_t)B_ * N_ * K_;
  bf16* W1H = ZL + (size_t)B_ * N_ * K_;
  bf16* W1L = W1H + C_ * C_;
  bf16* W2H = W1L + C_ * C_;
  bf16* W2L = W2H + C_ * C_;
  bf16* MT0H = W2L + C_ * C_;                       // K*C
  bf16* MT0L = MT0H + K_ * C_;
  bf16* MUTH = MT0L + K_ * C_;                      // B*K*C
  bf16* MUTL = MUTH + (size_t)B_ * K_ * C_;
  bf16* MUH  = MUTL + (size_t)B_ * K_ * C_;         // B*C*K
  float* MUACCP = (float*)(MUH + (size_t)B_ * C_ * K_);  // NCHK*B*C*K (33.6MB)
  float* psumP = MUACCP;                            // alias (conv2 phase)
  float* psqP  = psumP + (size_t)B_ * 64 * C_;      // 1024*C
  float* colsum = MUACCP + (size_t)NCHK * B_ * C_ * K_;  // B*K
  float* gcp = colsum + B_ * K_;                    // C
  float* ocp = gcp + C_;                            // C

  const dim3 blk(256);

  cast_w_split<<<dim3(C_ * C_ / 256), blk, 0, stream>>>(w1, W1H, W1L);
  cast_w_split<<<dim3(C_ * C_ / 256), blk, 0, stream>>>(w2, W2H, W2L);
  cast_mu0T_split<<<dim3(K_), blk, 0, stream>>>(mu0, MT0H, MT0L);

  // conv1 with fused transpose + register prefetch, all 16 batches
  conv1_fused<<<dim3(N_ / 128, C_ / 128, B_), blk, 0, stream>>>(
      x, W1H, W1L, b1, XSH, XSL);

  // EM: grouped by batches so xs hi/lo (134 MB/group) stays L3-resident
  for (int g = 0; g < B_ / BGRP; ++g) {
    const int boff = g * BGRP;
    for (int it = 0; it < 3; ++it) {
      hipMemsetAsync(colsum + boff * K_, 0, BGRP * K_ * sizeof(float), stream);
      estep_split<<<dim3(N_ / 128, BGRP), blk, 0, stream>>>(
          XSH, XSL, it == 0 ? MT0H : MUTH, it == 0 ? MT0L : MUTL,
          it == 0 ? 0 : (size_t)K_ * C_, ZH, ZL, colsum, boff);
      mstep_split<<<dim3(NCHK, C_ / 128, BGRP), blk, 0, stream>>>(
          XSH, XSL, ZH, ZL, MUACCP, boff);
      finalize_mu<<<dim3(BGRP * C_ * K_ / 256), blk, 0, stream>>>(
          MUACCP, colsum, MUTH, MUTL, MUH, it == 2 ? MUOUT : nullptr,
          boff * C_ * K_);
    }
  }

  x2_plain<<<dim3(N_ / 128, C_ / 128, B_), blk, 0, stream>>>(ZH, MUH, X2b);
  conv2_stats<<<dim3(C_ / 128, N_ / 128, B_), blk, 0, stream>>>(
      W2H, X2b, psumP, psqP);
  bn_finalize2<<<dim3(C_), blk, 0, stream>>>(psumP, psqP, gamma, beta, gcp, ocp);
  conv2_bn<<<dim3(C_ / 128, N_ / 128, B_), blk, 0, stream>>>(
      W2H, X2b, gcp, ocp, x, OUT);
}